// Round 7
// baseline (1540.716 us; speedup 1.0000x reference)
//
#include <hip/hip_runtime.h>
#include <hip/hip_bf16.h>

typedef unsigned short ushort_t;
typedef unsigned int   uint_t;
typedef __attribute__((ext_vector_type(8))) _Float16 half8;   // MFMA f16 A/B frag
typedef __attribute__((ext_vector_type(2))) _Float16 half2v;  // packed f16 pair
typedef __attribute__((ext_vector_type(4))) float    floatx4; // MFMA acc

#define B_    2
#define R_    8192
#define HW_   256
#define S_    64
#define NRAYS (B_*R_)
#define PLANE_ELEMS ((size_t)64*HW_*HW_)
#define TRP_ELEMS   ((size_t)HW_*HW_*64)
#define WS_PLANES_BYTES (6ull*B_*TRP_ELEMS*2)   /* 100,663,296 */
#define NW_US 10240    /* weight f16s: 8192 mlp + 2048 head */
#define WV 4           /* waves (rays) per block */

__device__ __forceinline__ float sp(float x){ return fmaxf(x, 0.f) + __logf(1.f + __expf(-fabsf(x))); }
__device__ __forceinline__ ushort_t f2h(float f){
    union{_Float16 h; ushort_t u;} v; v.h = (_Float16)f; return v.u;
}

// ---------------- Kernel A: transpose planes [C,H,W]f32 -> [H,W,C]f16 ----------------
__global__ __launch_bounds__(256) void tr_planes(
    const float* __restrict__ p0, const float* __restrict__ p1, const float* __restrict__ p2,
    const float* __restrict__ p3, const float* __restrict__ p4, const float* __restrict__ p5,
    ushort_t* __restrict__ outp)
{
    const int blk = blockIdx.x;
    const int y = blk & 255, b = (blk >> 8) & 1, p = blk >> 9;
    const float* src = (p==0)?p0:(p==1)?p1:(p==2)?p2:(p==3)?p3:(p==4)?p4:p5;
    src += (size_t)b*PLANE_ELEMS + (size_t)y*HW_ + threadIdx.x;
    ushort_t* dst = outp + (size_t)(p*2+b)*TRP_ELEMS + ((size_t)y*HW_ + threadIdx.x)*64;

    __attribute__((aligned(16))) ushort_t tmp[64];
#pragma unroll
    for (int c = 0; c < 64; ++c)
        tmp[c] = f2h(src[(size_t)c*HW_*HW_]);
#pragma unroll
    for (int k = 0; k < 8; ++k)
        reinterpret_cast<uint4*>(dst)[k] = reinterpret_cast<const uint4*>(tmp)[k];
}

// ---------------- Kernel A2: weights -> f16, transposed for B-fragments ----------------
// dst layout (f16): [0,8192): Wt[l][o][c];  [8192,10240): head[n][c]:
//   n<16: w_col col n;  n==16: w_opacity;  n in 17..31: 0
__global__ __launch_bounds__(256) void prep_weights(
    const float* __restrict__ mlp_w, const float* __restrict__ w_op,
    const float* __restrict__ w_col, ushort_t* __restrict__ dst)
{
    int i = blockIdx.x*256 + threadIdx.x;
    if (i >= NW_US) return;
    float v;
    if (i < 8192) {
        int l = i >> 12, o = (i >> 6) & 63, c = i & 63;
        v = mlp_w[l*4096 + c*64 + o];
    } else {
        int j = i - 8192, n = j >> 6, c = j & 63;
        v = (n < 16) ? w_col[c*16 + n] : (n == 16 ? w_op[c] : 0.f);
    }
    dst[i] = f2h(v);
}

// ---------------- Kernel B: render (1 wave = 1 ray; MFMA f16 MLP) ----------------
// R6: f16 everywhere in the feature path. Gather accumulates in half2
// (v_pk_fma_f16): acc 64->32 VGPRs, per-corner VALU halved, no repack
// epilogue. R5's f32 acc pushed VGPR to 256 -> 2 waves/SIMD, latency-bound.
// (256,3) caps at 168 VGPR; predicted live set ~130 -> no spill (watch WRITE_SIZE).
__global__ __launch_bounds__(256, 3) void render(
    const float* __restrict__ rays, const float* __restrict__ centers,
    const float* __restrict__ enc,  const float* __restrict__ nearp, const float* __restrict__ farp,
    const float* __restrict__ mlp_b, const float* __restrict__ b_op,
    const float* __restrict__ b_col, const float* __restrict__ bgc,
    const ushort_t* __restrict__ trp, const ushort_t* __restrict__ wq,
    float* __restrict__ out)
{
    __shared__ ushort_t A_lds[WV][4096];     // 64 rows x 128B (64 f16), XOR-swizzled 16B slots
    __shared__ float    sd_lds[WV][64];
    __shared__ float    w_lds [WV][64];

    const int wv = threadIdx.x >> 6, lane = threadIdx.x & 63;
    const int gray = blockIdx.x*WV + wv;
    const int b = gray >> 13;
    ushort_t* A = &A_lds[wv][0];

    const float nr = nearp[gray], fr = farp[gray];
    const float rdx = rays[gray*3+0], rdy = rays[gray*3+1], rdz = rays[gray*3+2];
    const float rox = centers[gray*3+0], roy = centers[gray*3+1], roz = centers[gray*3+2];
    const float delta = (fr - nr) * (1.f/S_);
    const float t  = nr + (fr - nr) * ((lane + 0.5f) * (1.f/S_));
    const float px = rox + t*rdx, py = roy + t*rdy, pz = roz + t*rdz;

    // bilinear prep (shared by density & color planes: same pts)
    int pos[3]; float a00[3], a01[3], a10[3], a11[3];
    {
        float us[3] = {px, py, pz};
        float vs[3] = {py, pz, px};
#pragma unroll
        for (int p = 0; p < 3; ++p) {
            float x = (fminf(fmaxf(us[p],-1.f),1.f) + 1.f) * 127.5f;
            float y = (fminf(fmaxf(vs[p],-1.f),1.f) + 1.f) * 127.5f;
            int x0 = (int)floorf(x); x0 = x0 < 0 ? 0 : (x0 > 254 ? 254 : x0);
            int y0 = (int)floorf(y); y0 = y0 < 0 ? 0 : (y0 > 254 ? 254 : y0);
            float wx = x - (float)x0, wy = y - (float)y0;
            pos[p] = y0*HW_ + x0;
            a00[p] = (1.f-wx)*(1.f-wy); a01[p] = wx*(1.f-wy);
            a10[p] = (1.f-wx)*wy;       a11[p] = wx*wy;
        }
    }

    // gather 3 planes into this lane's A row (m = lane), f16, swizzled.
    // Per (plane,corner): one full 128 B line load -> 32 pk-FMA -> next corner.
    auto gather3 = [&](int pbase, const float* encrow) {
        half2v acc[32];
        if (encrow) {
#pragma unroll
            for (int i = 0; i < 16; ++i) {
                float4 e = *reinterpret_cast<const float4*>(encrow + i*4);
                acc[2*i+0] = half2v{(_Float16)e.x, (_Float16)e.y};
                acc[2*i+1] = half2v{(_Float16)e.z, (_Float16)e.w};
            }
        } else {
#pragma unroll
            for (int i = 0; i < 32; ++i) acc[i] = half2v{(_Float16)0.f, (_Float16)0.f};
        }
#pragma unroll
        for (int p = 0; p < 3; ++p) {
            const ushort_t* base = trp + (size_t)((pbase+p)*2 + b)*TRP_ELEMS + (size_t)pos[p]*64;
#pragma unroll
            for (int corner = 0; corner < 4; ++corner) {
                const ushort_t* cp = base + ((corner & 1) ? 64 : 0) + ((corner & 2) ? 64*HW_ : 0);
                const float w = (corner==0)?a00[p]:(corner==1)?a01[p]:(corner==2)?a10[p]:a11[p];
                const _Float16 wh = (_Float16)w;
                const half2v w2 = half2v{wh, wh};
                union { uint4 v[8]; half2v h[32]; } q;
#pragma unroll
                for (int k = 0; k < 8; ++k) q.v[k] = reinterpret_cast<const uint4*>(cp)[k];
#pragma unroll
                for (int j = 0; j < 32; ++j)
                    acc[j] += w2 * q.h[j];       // v_pk_fma_f16
            }
        }
#pragma unroll
        for (int c8 = 0; c8 < 8; ++c8) {
            union { half2v h[4]; uint4 v; } pk;
#pragma unroll
            for (int j = 0; j < 4; ++j) pk.h[j] = acc[c8*4 + j];
            *reinterpret_cast<uint4*>(reinterpret_cast<char*>(A) + lane*128 + ((c8*16) ^ ((lane&7)<<4)))
                = pk.v;
        }
    };

    // A-fragment load: lane holds row (lane&15) of tile mi, k = kt*32 + (lane>>4)*8 + j
    auto ldfrag = [&](int mi, int kt) -> half8 {
        int m  = mi*16 + (lane&15);
        int cb = (kt*64 + ((lane>>4)*16)) ^ ((m&7)<<4);
        return *reinterpret_cast<const half8*>(reinterpret_cast<const char*>(A) + m*128 + cb);
    };
    // B-fragment: lane holds col (lane&15) of tile nt, k = kt*32 + (lane>>4)*8 + j
    auto ldbfrag = [&](const ushort_t* wrow, int nt, int kt) -> half8 {
        return *reinterpret_cast<const half8*>(wrow + (nt*16 + (lane&15))*64 + kt*32 + (lane>>4)*8);
    };
    // write H value (f16) at [m][n], swizzled
    auto stH = [&](int m, int n, float v) {
        A[(m*128 + ((n*2) ^ ((m&7)<<4))) >> 1] = f2h(v);
    };

    // one MLP layer: A(f16 in LDS) @ Wt -> softplus -> back into A.
    // af[8] preload is a CORRECTNESS requirement: all reads of A must complete
    // before the nt-loop's stH writes overwrite A in place (R3 lesson).
    auto mlp_layer = [&](const ushort_t* wrow, const float* bias) {
        half8 af[8];
#pragma unroll
        for (int mi = 0; mi < 4; ++mi)
#pragma unroll
            for (int kt = 0; kt < 2; ++kt) af[mi*2+kt] = ldfrag(mi, kt);
#pragma unroll
        for (int nt = 0; nt < 4; ++nt) {
            half8 b0 = ldbfrag(wrow, nt, 0);
            half8 b1 = ldbfrag(wrow, nt, 1);
            floatx4 acc[4];
#pragma unroll
            for (int mi = 0; mi < 4; ++mi) {
                acc[mi] = (floatx4){0.f,0.f,0.f,0.f};
                acc[mi] = __builtin_amdgcn_mfma_f32_16x16x32_f16(af[mi*2+0], b0, acc[mi], 0, 0, 0);
                acc[mi] = __builtin_amdgcn_mfma_f32_16x16x32_f16(af[mi*2+1], b1, acc[mi], 0, 0, 0);
            }
            const int n = nt*16 + (lane&15);
            const float bc = bias[n];
#pragma unroll
            for (int mi = 0; mi < 4; ++mi)
#pragma unroll
                for (int r = 0; r < 4; ++r) {
                    int m = mi*16 + (lane>>4)*4 + r;
                    stH(m, n, sp(acc[mi][r] + bc));
                }
        }
    };

    // ---- pipeline ----
    gather3(0, nullptr);                 // density features -> A
    mlp_layer(wq,        mlp_b);         // layer 1
    mlp_layer(wq + 4096, mlp_b + 64);    // layer 2  (A now holds h)

    const ushort_t* whead = wq + 8192;

    // sigma head: h @ [w_op | 0...]  (nt=1 tile of head region; col 16 = w_op)
    {
        half8 b0 = ldbfrag(whead, 1, 0);
        half8 b1 = ldbfrag(whead, 1, 1);
        floatx4 accS[4];
#pragma unroll
        for (int mi = 0; mi < 4; ++mi) {
            accS[mi] = (floatx4){0.f,0.f,0.f,0.f};
            accS[mi] = __builtin_amdgcn_mfma_f32_16x16x32_f16(ldfrag(mi,0), b0, accS[mi], 0, 0, 0);
            accS[mi] = __builtin_amdgcn_mfma_f32_16x16x32_f16(ldfrag(mi,1), b1, accS[mi], 0, 0, 0);
        }
        if ((lane & 15) == 0) {
            const float bop = b_op[0];
#pragma unroll
            for (int mi = 0; mi < 4; ++mi)
#pragma unroll
                for (int r = 0; r < 4; ++r) {
                    int m = mi*16 + (lane>>4)*4 + r;
                    sd_lds[wv][m] = sp(accS[mi][r] + bop) * delta;
                }
        }
    }   // accS dead here — only accC (below) lives across the color gather

    // color head: (h) @ Wc, then (+fc+enc) @ Wc accumulated
    floatx4 accC[4];
#pragma unroll
    for (int mi = 0; mi < 4; ++mi) accC[mi] = (floatx4){0.f,0.f,0.f,0.f};
    {
        half8 b0 = ldbfrag(whead, 0, 0);
        half8 b1 = ldbfrag(whead, 0, 1);
#pragma unroll
        for (int mi = 0; mi < 4; ++mi) {
            accC[mi] = __builtin_amdgcn_mfma_f32_16x16x32_f16(ldfrag(mi,0), b0, accC[mi], 0, 0, 0);
            accC[mi] = __builtin_amdgcn_mfma_f32_16x16x32_f16(ldfrag(mi,1), b1, accC[mi], 0, 0, 0);
        }
    }

    gather3(3, enc + (size_t)gray*64);   // color features + rays_encoding -> A
    {
        half8 b0 = ldbfrag(whead, 0, 0);
        half8 b1 = ldbfrag(whead, 0, 1);
#pragma unroll
        for (int mi = 0; mi < 4; ++mi) {
            accC[mi] = __builtin_amdgcn_mfma_f32_16x16x32_f16(ldfrag(mi,0), b0, accC[mi], 0, 0, 0);
            accC[mi] = __builtin_amdgcn_mfma_f32_16x16x32_f16(ldfrag(mi,1), b1, accC[mi], 0, 0, 0);
        }
    }

    // ---- composite: lane = sample ----
    const float sdv = sd_lds[wv][lane];
    float csd = sdv;
#pragma unroll
    for (int off = 1; off < 64; off <<= 1) {
        float nn = __shfl_up(csd, off, 64);
        if (lane >= off) csd += nn;
    }
    const float nlt = __shfl(csd, 63, 64);
    const float Tw  = __expf(sdv - csd) * (1.f - __expf(-sdv));
    const float em  = __expf(-nlt);
    w_lds[wv][lane] = Tw;

    float rl = Tw * t;
#pragma unroll
    for (int off = 32; off > 0; off >>= 1) rl += __shfl_xor(rl, off, 64);

    // feat[k] = sum_m w_m * (color[m][k] + b_col[k]);  k = lane&15
    const float bcn = b_col[lane & 15];
    float pf = 0.f;
#pragma unroll
    for (int mi = 0; mi < 4; ++mi)
#pragma unroll
        for (int r = 0; r < 4; ++r) {
            int m = mi*16 + (lane>>4)*4 + r;
            pf += w_lds[wv][m] * (accC[mi][r] + bcn);
        }
    pf += __shfl_xor(pf, 16, 64);
    pf += __shfl_xor(pf, 32, 64);

    if (lane < 16)
        out[(size_t)gray*16 + lane] = pf + em * bgc[lane];
    if (lane == 0) {
        out[(size_t)NRAYS*16 + gray] = 1.f - em;   // mask
        out[(size_t)NRAYS*17 + gray] = rl;         // ray_len
    }
}

extern "C" void kernel_launch(void* const* d_in, const int* in_sizes, int n_in,
                              void* d_out, int out_size, void* d_ws, size_t ws_size,
                              hipStream_t stream)
{
    const float* rays    = (const float*)d_in[0];
    const float* centers = (const float*)d_in[1];
    const float* enc     = (const float*)d_in[2];
    const float* nearp   = (const float*)d_in[3];
    const float* farp    = (const float*)d_in[4];
    const float* xy      = (const float*)d_in[5];
    const float* yz      = (const float*)d_in[6];
    const float* zx      = (const float*)d_in[7];
    const float* xyc     = (const float*)d_in[8];
    const float* yzc     = (const float*)d_in[9];
    const float* zxc     = (const float*)d_in[10];
    const float* mlp_w   = (const float*)d_in[11];
    const float* mlp_b   = (const float*)d_in[12];
    const float* w_op    = (const float*)d_in[13];
    const float* b_op    = (const float*)d_in[14];
    const float* w_col   = (const float*)d_in[15];
    const float* b_col   = (const float*)d_in[16];
    const float* bg      = (const float*)d_in[17];
    float* out = (float*)d_out;

    ushort_t* trp = (ushort_t*)d_ws;
    ushort_t* wq  = (ushort_t*)((char*)d_ws + WS_PLANES_BYTES);

    tr_planes<<<6*2*HW_, 256, 0, stream>>>(xy, yz, zx, xyc, yzc, zxc, trp);
    prep_weights<<<(NW_US + 255)/256, 256, 0, stream>>>(mlp_w, w_op, w_col, wq);
    render<<<NRAYS/WV, WV*64, 0, stream>>>(
        rays, centers, enc, nearp, farp, mlp_b, b_op, b_col, bg, trp, wq, out);
}

// Round 8
// 991.016 us; speedup vs baseline: 1.5547x; 1.5547x over previous
//
#include <hip/hip_runtime.h>
#include <hip/hip_bf16.h>

typedef unsigned short ushort_t;
typedef unsigned int   uint_t;
typedef __attribute__((ext_vector_type(8))) _Float16 half8;   // MFMA f16 A/B frag
typedef __attribute__((ext_vector_type(2))) _Float16 half2v;  // packed f16 pair
typedef __attribute__((ext_vector_type(4))) float    floatx4; // MFMA acc

#define B_    2
#define R_    8192
#define HW_   256
#define S_    64
#define NRAYS (B_*R_)
#define PLANE_ELEMS ((size_t)64*HW_*HW_)
#define TRP_ELEMS   ((size_t)HW_*HW_*64)
#define WS_PLANES_BYTES (6ull*B_*TRP_ELEMS*2)   /* 100,663,296 */
#define NW_US 10240    /* weight f16s: 8192 mlp + 2048 head */
#define WV 4           /* waves (rays) per block */

__device__ __forceinline__ float sp(float x){ return fmaxf(x, 0.f) + __logf(1.f + __expf(-fabsf(x))); }
__device__ __forceinline__ ushort_t f2h(float f){
    union{_Float16 h; ushort_t u;} v; v.h = (_Float16)f; return v.u;
}

// ---------------- Kernel A: transpose planes [C,H,W]f32 -> [H,W,C]f16 ----------------
__global__ __launch_bounds__(256) void tr_planes(
    const float* __restrict__ p0, const float* __restrict__ p1, const float* __restrict__ p2,
    const float* __restrict__ p3, const float* __restrict__ p4, const float* __restrict__ p5,
    ushort_t* __restrict__ outp)
{
    const int blk = blockIdx.x;
    const int y = blk & 255, b = (blk >> 8) & 1, p = blk >> 9;
    const float* src = (p==0)?p0:(p==1)?p1:(p==2)?p2:(p==3)?p3:(p==4)?p4:p5;
    src += (size_t)b*PLANE_ELEMS + (size_t)y*HW_ + threadIdx.x;
    ushort_t* dst = outp + (size_t)(p*2+b)*TRP_ELEMS + ((size_t)y*HW_ + threadIdx.x)*64;

    __attribute__((aligned(16))) ushort_t tmp[64];
#pragma unroll
    for (int c = 0; c < 64; ++c)
        tmp[c] = f2h(src[(size_t)c*HW_*HW_]);
#pragma unroll
    for (int k = 0; k < 8; ++k)
        reinterpret_cast<uint4*>(dst)[k] = reinterpret_cast<const uint4*>(tmp)[k];
}

// ---------------- Kernel A2: weights -> f16, transposed for B-fragments ----------------
// dst layout (f16): [0,8192): Wt[l][o][c];  [8192,10240): head[n][c]:
//   n<16: w_col col n;  n==16: w_opacity;  n in 17..31: 0
__global__ __launch_bounds__(256) void prep_weights(
    const float* __restrict__ mlp_w, const float* __restrict__ w_op,
    const float* __restrict__ w_col, ushort_t* __restrict__ dst)
{
    int i = blockIdx.x*256 + threadIdx.x;
    if (i >= NW_US) return;
    float v;
    if (i < 8192) {
        int l = i >> 12, o = (i >> 6) & 63, c = i & 63;
        v = mlp_w[l*4096 + c*64 + o];
    } else {
        int j = i - 8192, n = j >> 6, c = j & 63;
        v = (n < 16) ? w_col[c*16 + n] : (n == 16 ? w_op[c] : 0.f);
    }
    dst[i] = f2h(v);
}

// ---------------- Kernel B: render (1 wave = 1 ray; MFMA f16 MLP) ----------------
// R7: f16 path (R6) + PLAIN __launch_bounds__(256) (R5's allocation regime).
// RULE (hit twice, R2+R6): min-waves >= 2 hints make the allocator squeeze
// (84 VGPR) and spill 38-510 MB of scratch. Let it breathe; f16's smaller
// live set (acc 32 vs 64 VGPRs) should land near the 170-VGPR/3-wave step.
__global__ __launch_bounds__(256) void render(
    const float* __restrict__ rays, const float* __restrict__ centers,
    const float* __restrict__ enc,  const float* __restrict__ nearp, const float* __restrict__ farp,
    const float* __restrict__ mlp_b, const float* __restrict__ b_op,
    const float* __restrict__ b_col, const float* __restrict__ bgc,
    const ushort_t* __restrict__ trp, const ushort_t* __restrict__ wq,
    float* __restrict__ out)
{
    __shared__ ushort_t A_lds[WV][4096];     // 64 rows x 128B (64 f16), XOR-swizzled 16B slots
    __shared__ float    sd_lds[WV][64];
    __shared__ float    w_lds [WV][64];

    const int wv = threadIdx.x >> 6, lane = threadIdx.x & 63;
    const int gray = blockIdx.x*WV + wv;
    const int b = gray >> 13;
    ushort_t* A = &A_lds[wv][0];

    const float nr = nearp[gray], fr = farp[gray];
    const float rdx = rays[gray*3+0], rdy = rays[gray*3+1], rdz = rays[gray*3+2];
    const float rox = centers[gray*3+0], roy = centers[gray*3+1], roz = centers[gray*3+2];
    const float delta = (fr - nr) * (1.f/S_);
    const float t  = nr + (fr - nr) * ((lane + 0.5f) * (1.f/S_));
    const float px = rox + t*rdx, py = roy + t*rdy, pz = roz + t*rdz;

    // bilinear prep (shared by density & color planes: same pts)
    int pos[3]; float a00[3], a01[3], a10[3], a11[3];
    {
        float us[3] = {px, py, pz};
        float vs[3] = {py, pz, px};
#pragma unroll
        for (int p = 0; p < 3; ++p) {
            float x = (fminf(fmaxf(us[p],-1.f),1.f) + 1.f) * 127.5f;
            float y = (fminf(fmaxf(vs[p],-1.f),1.f) + 1.f) * 127.5f;
            int x0 = (int)floorf(x); x0 = x0 < 0 ? 0 : (x0 > 254 ? 254 : x0);
            int y0 = (int)floorf(y); y0 = y0 < 0 ? 0 : (y0 > 254 ? 254 : y0);
            float wx = x - (float)x0, wy = y - (float)y0;
            pos[p] = y0*HW_ + x0;
            a00[p] = (1.f-wx)*(1.f-wy); a01[p] = wx*(1.f-wy);
            a10[p] = (1.f-wx)*wy;       a11[p] = wx*wy;
        }
    }

    // gather 3 planes into this lane's A row (m = lane), f16, swizzled.
    // Per (plane,corner): one full 128 B line load -> 32 pk-FMA -> next corner.
    auto gather3 = [&](int pbase, const float* encrow) {
        half2v acc[32];
        if (encrow) {
#pragma unroll
            for (int i = 0; i < 16; ++i) {
                float4 e = *reinterpret_cast<const float4*>(encrow + i*4);
                acc[2*i+0] = half2v{(_Float16)e.x, (_Float16)e.y};
                acc[2*i+1] = half2v{(_Float16)e.z, (_Float16)e.w};
            }
        } else {
#pragma unroll
            for (int i = 0; i < 32; ++i) acc[i] = half2v{(_Float16)0.f, (_Float16)0.f};
        }
#pragma unroll
        for (int p = 0; p < 3; ++p) {
            const ushort_t* base = trp + (size_t)((pbase+p)*2 + b)*TRP_ELEMS + (size_t)pos[p]*64;
#pragma unroll
            for (int corner = 0; corner < 4; ++corner) {
                const ushort_t* cp = base + ((corner & 1) ? 64 : 0) + ((corner & 2) ? 64*HW_ : 0);
                const float w = (corner==0)?a00[p]:(corner==1)?a01[p]:(corner==2)?a10[p]:a11[p];
                const _Float16 wh = (_Float16)w;
                const half2v w2 = half2v{wh, wh};
                union { uint4 v[8]; half2v h[32]; } q;
#pragma unroll
                for (int k = 0; k < 8; ++k) q.v[k] = reinterpret_cast<const uint4*>(cp)[k];
#pragma unroll
                for (int j = 0; j < 32; ++j)
                    acc[j] += w2 * q.h[j];       // v_pk_fma_f16
            }
        }
#pragma unroll
        for (int c8 = 0; c8 < 8; ++c8) {
            union { half2v h[4]; uint4 v; } pk;
#pragma unroll
            for (int j = 0; j < 4; ++j) pk.h[j] = acc[c8*4 + j];
            *reinterpret_cast<uint4*>(reinterpret_cast<char*>(A) + lane*128 + ((c8*16) ^ ((lane&7)<<4)))
                = pk.v;
        }
    };

    // A-fragment load: lane holds row (lane&15) of tile mi, k = kt*32 + (lane>>4)*8 + j
    auto ldfrag = [&](int mi, int kt) -> half8 {
        int m  = mi*16 + (lane&15);
        int cb = (kt*64 + ((lane>>4)*16)) ^ ((m&7)<<4);
        return *reinterpret_cast<const half8*>(reinterpret_cast<const char*>(A) + m*128 + cb);
    };
    // B-fragment: lane holds col (lane&15) of tile nt, k = kt*32 + (lane>>4)*8 + j
    auto ldbfrag = [&](const ushort_t* wrow, int nt, int kt) -> half8 {
        return *reinterpret_cast<const half8*>(wrow + (nt*16 + (lane&15))*64 + kt*32 + (lane>>4)*8);
    };
    // write H value (f16) at [m][n], swizzled
    auto stH = [&](int m, int n, float v) {
        A[(m*128 + ((n*2) ^ ((m&7)<<4))) >> 1] = f2h(v);
    };

    // one MLP layer: A(f16 in LDS) @ Wt -> softplus -> back into A.
    // af[8] preload is a CORRECTNESS requirement: all reads of A must complete
    // before the nt-loop's stH writes overwrite A in place (R3 lesson).
    auto mlp_layer = [&](const ushort_t* wrow, const float* bias) {
        half8 af[8];
#pragma unroll
        for (int mi = 0; mi < 4; ++mi)
#pragma unroll
            for (int kt = 0; kt < 2; ++kt) af[mi*2+kt] = ldfrag(mi, kt);
#pragma unroll
        for (int nt = 0; nt < 4; ++nt) {
            half8 b0 = ldbfrag(wrow, nt, 0);
            half8 b1 = ldbfrag(wrow, nt, 1);
            floatx4 acc[4];
#pragma unroll
            for (int mi = 0; mi < 4; ++mi) {
                acc[mi] = (floatx4){0.f,0.f,0.f,0.f};
                acc[mi] = __builtin_amdgcn_mfma_f32_16x16x32_f16(af[mi*2+0], b0, acc[mi], 0, 0, 0);
                acc[mi] = __builtin_amdgcn_mfma_f32_16x16x32_f16(af[mi*2+1], b1, acc[mi], 0, 0, 0);
            }
            const int n = nt*16 + (lane&15);
            const float bc = bias[n];
#pragma unroll
            for (int mi = 0; mi < 4; ++mi)
#pragma unroll
                for (int r = 0; r < 4; ++r) {
                    int m = mi*16 + (lane>>4)*4 + r;
                    stH(m, n, sp(acc[mi][r] + bc));
                }
        }
    };

    // ---- pipeline ----
    gather3(0, nullptr);                 // density features -> A
    mlp_layer(wq,        mlp_b);         // layer 1
    mlp_layer(wq + 4096, mlp_b + 64);    // layer 2  (A now holds h)

    const ushort_t* whead = wq + 8192;

    // sigma head: h @ [w_op | 0...]  (nt=1 tile of head region; col 16 = w_op)
    {
        half8 b0 = ldbfrag(whead, 1, 0);
        half8 b1 = ldbfrag(whead, 1, 1);
        floatx4 accS[4];
#pragma unroll
        for (int mi = 0; mi < 4; ++mi) {
            accS[mi] = (floatx4){0.f,0.f,0.f,0.f};
            accS[mi] = __builtin_amdgcn_mfma_f32_16x16x32_f16(ldfrag(mi,0), b0, accS[mi], 0, 0, 0);
            accS[mi] = __builtin_amdgcn_mfma_f32_16x16x32_f16(ldfrag(mi,1), b1, accS[mi], 0, 0, 0);
        }
        if ((lane & 15) == 0) {
            const float bop = b_op[0];
#pragma unroll
            for (int mi = 0; mi < 4; ++mi)
#pragma unroll
                for (int r = 0; r < 4; ++r) {
                    int m = mi*16 + (lane>>4)*4 + r;
                    sd_lds[wv][m] = sp(accS[mi][r] + bop) * delta;
                }
        }
    }   // accS dead here — only accC (below) lives across the color gather

    // color head: (h) @ Wc, then (+fc+enc) @ Wc accumulated
    floatx4 accC[4];
#pragma unroll
    for (int mi = 0; mi < 4; ++mi) accC[mi] = (floatx4){0.f,0.f,0.f,0.f};
    {
        half8 b0 = ldbfrag(whead, 0, 0);
        half8 b1 = ldbfrag(whead, 0, 1);
#pragma unroll
        for (int mi = 0; mi < 4; ++mi) {
            accC[mi] = __builtin_amdgcn_mfma_f32_16x16x32_f16(ldfrag(mi,0), b0, accC[mi], 0, 0, 0);
            accC[mi] = __builtin_amdgcn_mfma_f32_16x16x32_f16(ldfrag(mi,1), b1, accC[mi], 0, 0, 0);
        }
    }

    gather3(3, enc + (size_t)gray*64);   // color features + rays_encoding -> A
    {
        half8 b0 = ldbfrag(whead, 0, 0);
        half8 b1 = ldbfrag(whead, 0, 1);
#pragma unroll
        for (int mi = 0; mi < 4; ++mi) {
            accC[mi] = __builtin_amdgcn_mfma_f32_16x16x32_f16(ldfrag(mi,0), b0, accC[mi], 0, 0, 0);
            accC[mi] = __builtin_amdgcn_mfma_f32_16x16x32_f16(ldfrag(mi,1), b1, accC[mi], 0, 0, 0);
        }
    }

    // ---- composite: lane = sample ----
    const float sdv = sd_lds[wv][lane];
    float csd = sdv;
#pragma unroll
    for (int off = 1; off < 64; off <<= 1) {
        float nn = __shfl_up(csd, off, 64);
        if (lane >= off) csd += nn;
    }
    const float nlt = __shfl(csd, 63, 64);
    const float Tw  = __expf(sdv - csd) * (1.f - __expf(-sdv));
    const float em  = __expf(-nlt);
    w_lds[wv][lane] = Tw;

    float rl = Tw * t;
#pragma unroll
    for (int off = 32; off > 0; off >>= 1) rl += __shfl_xor(rl, off, 64);

    // feat[k] = sum_m w_m * (color[m][k] + b_col[k]);  k = lane&15
    const float bcn = b_col[lane & 15];
    float pf = 0.f;
#pragma unroll
    for (int mi = 0; mi < 4; ++mi)
#pragma unroll
        for (int r = 0; r < 4; ++r) {
            int m = mi*16 + (lane>>4)*4 + r;
            pf += w_lds[wv][m] * (accC[mi][r] + bcn);
        }
    pf += __shfl_xor(pf, 16, 64);
    pf += __shfl_xor(pf, 32, 64);

    if (lane < 16)
        out[(size_t)gray*16 + lane] = pf + em * bgc[lane];
    if (lane == 0) {
        out[(size_t)NRAYS*16 + gray] = 1.f - em;   // mask
        out[(size_t)NRAYS*17 + gray] = rl;         // ray_len
    }
}

extern "C" void kernel_launch(void* const* d_in, const int* in_sizes, int n_in,
                              void* d_out, int out_size, void* d_ws, size_t ws_size,
                              hipStream_t stream)
{
    const float* rays    = (const float*)d_in[0];
    const float* centers = (const float*)d_in[1];
    const float* enc     = (const float*)d_in[2];
    const float* nearp   = (const float*)d_in[3];
    const float* farp    = (const float*)d_in[4];
    const float* xy      = (const float*)d_in[5];
    const float* yz      = (const float*)d_in[6];
    const float* zx      = (const float*)d_in[7];
    const float* xyc     = (const float*)d_in[8];
    const float* yzc     = (const float*)d_in[9];
    const float* zxc     = (const float*)d_in[10];
    const float* mlp_w   = (const float*)d_in[11];
    const float* mlp_b   = (const float*)d_in[12];
    const float* w_op    = (const float*)d_in[13];
    const float* b_op    = (const float*)d_in[14];
    const float* w_col   = (const float*)d_in[15];
    const float* b_col   = (const float*)d_in[16];
    const float* bg      = (const float*)d_in[17];
    float* out = (float*)d_out;

    ushort_t* trp = (ushort_t*)d_ws;
    ushort_t* wq  = (ushort_t*)((char*)d_ws + WS_PLANES_BYTES);

    tr_planes<<<6*2*HW_, 256, 0, stream>>>(xy, yz, zx, xyc, yzc, zxc, trp);
    prep_weights<<<(NW_US + 255)/256, 256, 0, stream>>>(mlp_w, w_op, w_col, wq);
    render<<<NRAYS/WV, WV*64, 0, stream>>>(
        rays, centers, enc, nearp, farp, mlp_b, b_op, b_col, bg, trp, wq, out);
}

// Round 9
// 757.018 us; speedup vs baseline: 2.0352x; 1.3091x over previous
//
#include <hip/hip_runtime.h>
#include <hip/hip_bf16.h>

typedef unsigned short ushort_t;
typedef unsigned int   uint_t;
typedef __attribute__((ext_vector_type(8))) _Float16 half8;   // MFMA f16 A/B frag
typedef __attribute__((ext_vector_type(2))) _Float16 half2v;  // packed f16 pair
typedef __attribute__((ext_vector_type(4))) float    floatx4; // MFMA acc

#define B_    2
#define R_    8192
#define HW_   256
#define S_    64
#define NRAYS (B_*R_)
#define PLANE_ELEMS ((size_t)64*HW_*HW_)
#define TRP_ELEMS   ((size_t)HW_*HW_*64)
#define WS_PLANES_BYTES (6ull*B_*TRP_ELEMS*2)   /* 100,663,296 */
#define NW_US 10240    /* weight f16s: 8192 mlp + 2048 head */
#define WV 4           /* waves (rays) per block */
#define NWG (NRAYS/WV) /* 4096 render blocks */
#define NBINS 1024

/* ws layout (bytes):
   [0, WS_PLANES_BYTES)                     : transposed f16 planes
   [WS_PLANES_BYTES, +NW_US*2)              : f16 weights
   then (4B-aligned): keys[NRAYS], perm[NRAYS], hist[NBINS], offs[NBINS] */
#define WS_WQ_OFF   WS_PLANES_BYTES
#define WS_KEYS_OFF (WS_WQ_OFF + NW_US*2)
#define WS_PERM_OFF (WS_KEYS_OFF + NRAYS*4)
#define WS_HIST_OFF (WS_PERM_OFF + NRAYS*4)
#define WS_OFFS_OFF (WS_HIST_OFF + NBINS*4)

__device__ __forceinline__ float sp(float x){ return fmaxf(x, 0.f) + __logf(1.f + __expf(-fabsf(x))); }
__device__ __forceinline__ ushort_t f2h(float f){
    union{_Float16 h; ushort_t u;} v; v.h = (_Float16)f; return v.u;
}

// ---------------- Kernel A: transpose planes [C,H,W]f32 -> [H,W,C]f16 ----------------
__global__ __launch_bounds__(256) void tr_planes(
    const float* __restrict__ p0, const float* __restrict__ p1, const float* __restrict__ p2,
    const float* __restrict__ p3, const float* __restrict__ p4, const float* __restrict__ p5,
    ushort_t* __restrict__ outp)
{
    const int blk = blockIdx.x;
    const int y = blk & 255, b = (blk >> 8) & 1, p = blk >> 9;
    const float* src = (p==0)?p0:(p==1)?p1:(p==2)?p2:(p==3)?p3:(p==4)?p4:p5;
    src += (size_t)b*PLANE_ELEMS + (size_t)y*HW_ + threadIdx.x;
    ushort_t* dst = outp + (size_t)(p*2+b)*TRP_ELEMS + ((size_t)y*HW_ + threadIdx.x)*64;

    __attribute__((aligned(16))) ushort_t tmp[64];
#pragma unroll
    for (int c = 0; c < 64; ++c)
        tmp[c] = f2h(src[(size_t)c*HW_*HW_]);
#pragma unroll
    for (int k = 0; k < 8; ++k)
        reinterpret_cast<uint4*>(dst)[k] = reinterpret_cast<const uint4*>(tmp)[k];
}

// ---------------- Kernel A2: weights -> f16, transposed for B-fragments ----------------
__global__ __launch_bounds__(256) void prep_weights(
    const float* __restrict__ mlp_w, const float* __restrict__ w_op,
    const float* __restrict__ w_col, ushort_t* __restrict__ dst)
{
    int i = blockIdx.x*256 + threadIdx.x;
    if (i >= NW_US) return;
    float v;
    if (i < 8192) {
        int l = i >> 12, o = (i >> 6) & 63, c = i & 63;
        v = mlp_w[l*4096 + c*64 + o];
    } else {
        int j = i - 8192, n = j >> 6, c = j & 63;
        v = (n < 16) ? w_col[c*16 + n] : (n == 16 ? w_op[c] : 0.f);
    }
    dst[i] = f2h(v);
}

// ---------------- Sort kernels: spatial counting sort of rays ----------------
// Key = batch(1b) + 8x8x8 cell of clamped ray midpoint. Groups rays whose tap
// footprints overlap so co-resident blocks hit the same L2 lines.
__global__ __launch_bounds__(256) void ray_keys(
    const float* __restrict__ rays, const float* __restrict__ centers,
    const float* __restrict__ nearp, const float* __restrict__ farp,
    uint_t* __restrict__ keys, uint_t* __restrict__ hist)
{
    int rid = blockIdx.x*256 + threadIdx.x;
    if (rid >= NRAYS) return;
    const float t = 0.5f*(nearp[rid] + farp[rid]);
    float c[3];
#pragma unroll
    for (int a = 0; a < 3; ++a) {
        float p = centers[rid*3+a] + t*rays[rid*3+a];
        p = fminf(fmaxf(p, -1.f), 1.f);
        int ci = (int)((p + 1.f)*4.f);           // 0..8
        c[a] = (float)(ci > 7 ? 7 : ci);
    }
    uint_t key = (uint_t)(rid >> 13)*512 + (uint_t)c[2]*64 + (uint_t)c[1]*8 + (uint_t)c[0];
    keys[rid] = key;
    atomicAdd(&hist[key], 1u);
}

__global__ __launch_bounds__(NBINS) void scan_hist(
    const uint_t* __restrict__ hist, uint_t* __restrict__ offs)
{
    __shared__ uint_t tmp[NBINS];
    const int tid = threadIdx.x;
    const uint_t own = hist[tid];
    tmp[tid] = own;
    __syncthreads();
#pragma unroll
    for (int off = 1; off < NBINS; off <<= 1) {
        uint_t v = (tid >= off) ? tmp[tid - off] : 0u;
        __syncthreads();
        tmp[tid] += v;
        __syncthreads();
    }
    offs[tid] = tmp[tid] - own;    // exclusive
}

__global__ __launch_bounds__(256) void scatter_perm(
    const uint_t* __restrict__ keys, uint_t* __restrict__ offs, uint_t* __restrict__ perm)
{
    int rid = blockIdx.x*256 + threadIdx.x;
    if (rid >= NRAYS) return;
    uint_t pos = atomicAdd(&offs[keys[rid]], 1u);
    perm[pos] = (uint_t)rid;
}

// ---------------- Kernel B: render (1 wave = 1 ray; MFMA f16 MLP) ----------------
// R8: ray order = spatial sort (perm) + bijective XCD-chunk swizzle so each
// XCD's co-resident blocks process spatially adjacent rays -> tap L2 reuse.
// Body identical to R7 (f16, plain launch_bounds; R2/R6 rule: no min-waves hint).
__global__ __launch_bounds__(256) void render(
    const float* __restrict__ rays, const float* __restrict__ centers,
    const float* __restrict__ enc,  const float* __restrict__ nearp, const float* __restrict__ farp,
    const float* __restrict__ mlp_b, const float* __restrict__ b_op,
    const float* __restrict__ b_col, const float* __restrict__ bgc,
    const ushort_t* __restrict__ trp, const ushort_t* __restrict__ wq,
    const uint_t* __restrict__ perm, float* __restrict__ out)
{
    __shared__ ushort_t A_lds[WV][4096];     // 64 rows x 128B (64 f16), XOR-swizzled 16B slots
    __shared__ float    sd_lds[WV][64];
    __shared__ float    w_lds [WV][64];

    const int wv = threadIdx.x >> 6, lane = threadIdx.x & 63;
    const int sb  = (blockIdx.x & 7)*(NWG/8) + (blockIdx.x >> 3);  // XCD-chunk swizzle
    const int rid = (int)perm[sb*WV + wv];
    const int b = rid >> 13;
    ushort_t* A = &A_lds[wv][0];

    const float nr = nearp[rid], fr = farp[rid];
    const float rdx = rays[rid*3+0], rdy = rays[rid*3+1], rdz = rays[rid*3+2];
    const float rox = centers[rid*3+0], roy = centers[rid*3+1], roz = centers[rid*3+2];
    const float delta = (fr - nr) * (1.f/S_);
    const float t  = nr + (fr - nr) * ((lane + 0.5f) * (1.f/S_));
    const float px = rox + t*rdx, py = roy + t*rdy, pz = roz + t*rdz;

    // bilinear prep (shared by density & color planes: same pts)
    int pos[3]; float a00[3], a01[3], a10[3], a11[3];
    {
        float us[3] = {px, py, pz};
        float vs[3] = {py, pz, px};
#pragma unroll
        for (int p = 0; p < 3; ++p) {
            float x = (fminf(fmaxf(us[p],-1.f),1.f) + 1.f) * 127.5f;
            float y = (fminf(fmaxf(vs[p],-1.f),1.f) + 1.f) * 127.5f;
            int x0 = (int)floorf(x); x0 = x0 < 0 ? 0 : (x0 > 254 ? 254 : x0);
            int y0 = (int)floorf(y); y0 = y0 < 0 ? 0 : (y0 > 254 ? 254 : y0);
            float wx = x - (float)x0, wy = y - (float)y0;
            pos[p] = y0*HW_ + x0;
            a00[p] = (1.f-wx)*(1.f-wy); a01[p] = wx*(1.f-wy);
            a10[p] = (1.f-wx)*wy;       a11[p] = wx*wy;
        }
    }

    // gather 3 planes into this lane's A row (m = lane), f16, swizzled.
    auto gather3 = [&](int pbase, const float* encrow) {
        half2v acc[32];
        if (encrow) {
#pragma unroll
            for (int i = 0; i < 16; ++i) {
                float4 e = *reinterpret_cast<const float4*>(encrow + i*4);
                acc[2*i+0] = half2v{(_Float16)e.x, (_Float16)e.y};
                acc[2*i+1] = half2v{(_Float16)e.z, (_Float16)e.w};
            }
        } else {
#pragma unroll
            for (int i = 0; i < 32; ++i) acc[i] = half2v{(_Float16)0.f, (_Float16)0.f};
        }
#pragma unroll
        for (int p = 0; p < 3; ++p) {
            const ushort_t* base = trp + (size_t)((pbase+p)*2 + b)*TRP_ELEMS + (size_t)pos[p]*64;
#pragma unroll
            for (int corner = 0; corner < 4; ++corner) {
                const ushort_t* cp = base + ((corner & 1) ? 64 : 0) + ((corner & 2) ? 64*HW_ : 0);
                const float w = (corner==0)?a00[p]:(corner==1)?a01[p]:(corner==2)?a10[p]:a11[p];
                const _Float16 wh = (_Float16)w;
                const half2v w2 = half2v{wh, wh};
                union { uint4 v[8]; half2v h[32]; } q;
#pragma unroll
                for (int k = 0; k < 8; ++k) q.v[k] = reinterpret_cast<const uint4*>(cp)[k];
#pragma unroll
                for (int j = 0; j < 32; ++j)
                    acc[j] += w2 * q.h[j];       // v_pk_fma_f16
            }
        }
#pragma unroll
        for (int c8 = 0; c8 < 8; ++c8) {
            union { half2v h[4]; uint4 v; } pk;
#pragma unroll
            for (int j = 0; j < 4; ++j) pk.h[j] = acc[c8*4 + j];
            *reinterpret_cast<uint4*>(reinterpret_cast<char*>(A) + lane*128 + ((c8*16) ^ ((lane&7)<<4)))
                = pk.v;
        }
    };

    // A-fragment load: lane holds row (lane&15) of tile mi, k = kt*32 + (lane>>4)*8 + j
    auto ldfrag = [&](int mi, int kt) -> half8 {
        int m  = mi*16 + (lane&15);
        int cb = (kt*64 + ((lane>>4)*16)) ^ ((m&7)<<4);
        return *reinterpret_cast<const half8*>(reinterpret_cast<const char*>(A) + m*128 + cb);
    };
    auto ldbfrag = [&](const ushort_t* wrow, int nt, int kt) -> half8 {
        return *reinterpret_cast<const half8*>(wrow + (nt*16 + (lane&15))*64 + kt*32 + (lane>>4)*8);
    };
    auto stH = [&](int m, int n, float v) {
        A[(m*128 + ((n*2) ^ ((m&7)<<4))) >> 1] = f2h(v);
    };

    // one MLP layer; af[8] preload is a CORRECTNESS requirement (R3 lesson).
    auto mlp_layer = [&](const ushort_t* wrow, const float* bias) {
        half8 af[8];
#pragma unroll
        for (int mi = 0; mi < 4; ++mi)
#pragma unroll
            for (int kt = 0; kt < 2; ++kt) af[mi*2+kt] = ldfrag(mi, kt);
#pragma unroll
        for (int nt = 0; nt < 4; ++nt) {
            half8 b0 = ldbfrag(wrow, nt, 0);
            half8 b1 = ldbfrag(wrow, nt, 1);
            floatx4 acc[4];
#pragma unroll
            for (int mi = 0; mi < 4; ++mi) {
                acc[mi] = (floatx4){0.f,0.f,0.f,0.f};
                acc[mi] = __builtin_amdgcn_mfma_f32_16x16x32_f16(af[mi*2+0], b0, acc[mi], 0, 0, 0);
                acc[mi] = __builtin_amdgcn_mfma_f32_16x16x32_f16(af[mi*2+1], b1, acc[mi], 0, 0, 0);
            }
            const int n = nt*16 + (lane&15);
            const float bc = bias[n];
#pragma unroll
            for (int mi = 0; mi < 4; ++mi)
#pragma unroll
                for (int r = 0; r < 4; ++r) {
                    int m = mi*16 + (lane>>4)*4 + r;
                    stH(m, n, sp(acc[mi][r] + bc));
                }
        }
    };

    // ---- pipeline ----
    gather3(0, nullptr);                 // density features -> A
    mlp_layer(wq,        mlp_b);         // layer 1
    mlp_layer(wq + 4096, mlp_b + 64);    // layer 2  (A now holds h)

    const ushort_t* whead = wq + 8192;

    // sigma head: h @ [w_op | 0...]  (col 16 of head region = w_op)
    {
        half8 b0 = ldbfrag(whead, 1, 0);
        half8 b1 = ldbfrag(whead, 1, 1);
        floatx4 accS[4];
#pragma unroll
        for (int mi = 0; mi < 4; ++mi) {
            accS[mi] = (floatx4){0.f,0.f,0.f,0.f};
            accS[mi] = __builtin_amdgcn_mfma_f32_16x16x32_f16(ldfrag(mi,0), b0, accS[mi], 0, 0, 0);
            accS[mi] = __builtin_amdgcn_mfma_f32_16x16x32_f16(ldfrag(mi,1), b1, accS[mi], 0, 0, 0);
        }
        if ((lane & 15) == 0) {
            const float bop = b_op[0];
#pragma unroll
            for (int mi = 0; mi < 4; ++mi)
#pragma unroll
                for (int r = 0; r < 4; ++r) {
                    int m = mi*16 + (lane>>4)*4 + r;
                    sd_lds[wv][m] = sp(accS[mi][r] + bop) * delta;
                }
        }
    }

    // color head: (h) @ Wc, then (+fc+enc) @ Wc accumulated
    floatx4 accC[4];
#pragma unroll
    for (int mi = 0; mi < 4; ++mi) accC[mi] = (floatx4){0.f,0.f,0.f,0.f};
    {
        half8 b0 = ldbfrag(whead, 0, 0);
        half8 b1 = ldbfrag(whead, 0, 1);
#pragma unroll
        for (int mi = 0; mi < 4; ++mi) {
            accC[mi] = __builtin_amdgcn_mfma_f32_16x16x32_f16(ldfrag(mi,0), b0, accC[mi], 0, 0, 0);
            accC[mi] = __builtin_amdgcn_mfma_f32_16x16x32_f16(ldfrag(mi,1), b1, accC[mi], 0, 0, 0);
        }
    }

    gather3(3, enc + (size_t)rid*64);    // color features + rays_encoding -> A
    {
        half8 b0 = ldbfrag(whead, 0, 0);
        half8 b1 = ldbfrag(whead, 0, 1);
#pragma unroll
        for (int mi = 0; mi < 4; ++mi) {
            accC[mi] = __builtin_amdgcn_mfma_f32_16x16x32_f16(ldfrag(mi,0), b0, accC[mi], 0, 0, 0);
            accC[mi] = __builtin_amdgcn_mfma_f32_16x16x32_f16(ldfrag(mi,1), b1, accC[mi], 0, 0, 0);
        }
    }

    // ---- composite: lane = sample ----
    const float sdv = sd_lds[wv][lane];
    float csd = sdv;
#pragma unroll
    for (int off = 1; off < 64; off <<= 1) {
        float nn = __shfl_up(csd, off, 64);
        if (lane >= off) csd += nn;
    }
    const float nlt = __shfl(csd, 63, 64);
    const float Tw  = __expf(sdv - csd) * (1.f - __expf(-sdv));
    const float em  = __expf(-nlt);
    w_lds[wv][lane] = Tw;

    float rl = Tw * t;
#pragma unroll
    for (int off = 32; off > 0; off >>= 1) rl += __shfl_xor(rl, off, 64);

    // feat[k] = sum_m w_m * (color[m][k] + b_col[k]);  k = lane&15
    const float bcn = b_col[lane & 15];
    float pf = 0.f;
#pragma unroll
    for (int mi = 0; mi < 4; ++mi)
#pragma unroll
        for (int r = 0; r < 4; ++r) {
            int m = mi*16 + (lane>>4)*4 + r;
            pf += w_lds[wv][m] * (accC[mi][r] + bcn);
        }
    pf += __shfl_xor(pf, 16, 64);
    pf += __shfl_xor(pf, 32, 64);

    if (lane < 16)
        out[(size_t)rid*16 + lane] = pf + em * bgc[lane];
    if (lane == 0) {
        out[(size_t)NRAYS*16 + rid] = 1.f - em;   // mask
        out[(size_t)NRAYS*17 + rid] = rl;         // ray_len
    }
}

extern "C" void kernel_launch(void* const* d_in, const int* in_sizes, int n_in,
                              void* d_out, int out_size, void* d_ws, size_t ws_size,
                              hipStream_t stream)
{
    const float* rays    = (const float*)d_in[0];
    const float* centers = (const float*)d_in[1];
    const float* enc     = (const float*)d_in[2];
    const float* nearp   = (const float*)d_in[3];
    const float* farp    = (const float*)d_in[4];
    const float* xy      = (const float*)d_in[5];
    const float* yz      = (const float*)d_in[6];
    const float* zx      = (const float*)d_in[7];
    const float* xyc     = (const float*)d_in[8];
    const float* yzc     = (const float*)d_in[9];
    const float* zxc     = (const float*)d_in[10];
    const float* mlp_w   = (const float*)d_in[11];
    const float* mlp_b   = (const float*)d_in[12];
    const float* w_op    = (const float*)d_in[13];
    const float* b_op    = (const float*)d_in[14];
    const float* w_col   = (const float*)d_in[15];
    const float* b_col   = (const float*)d_in[16];
    const float* bg      = (const float*)d_in[17];
    float* out = (float*)d_out;

    char* ws = (char*)d_ws;
    ushort_t* trp  = (ushort_t*)ws;
    ushort_t* wq   = (ushort_t*)(ws + WS_WQ_OFF);
    uint_t*   keys = (uint_t*)(ws + WS_KEYS_OFF);
    uint_t*   perm = (uint_t*)(ws + WS_PERM_OFF);
    uint_t*   hist = (uint_t*)(ws + WS_HIST_OFF);
    uint_t*   offs = (uint_t*)(ws + WS_OFFS_OFF);

    tr_planes<<<6*2*HW_, 256, 0, stream>>>(xy, yz, zx, xyc, yzc, zxc, trp);
    prep_weights<<<(NW_US + 255)/256, 256, 0, stream>>>(mlp_w, w_op, w_col, wq);

    hipMemsetAsync(hist, 0, NBINS*sizeof(uint_t), stream);
    ray_keys<<<NRAYS/256, 256, 0, stream>>>(rays, centers, nearp, farp, keys, hist);
    scan_hist<<<1, NBINS, 0, stream>>>(hist, offs);
    scatter_perm<<<NRAYS/256, 256, 0, stream>>>(keys, offs, perm);

    render<<<NWG, WV*64, 0, stream>>>(
        rays, centers, enc, nearp, farp, mlp_b, b_op, b_col, bg, trp, wq, perm, out);
}

// Round 10
// 679.897 us; speedup vs baseline: 2.2661x; 1.1134x over previous
//
#include <hip/hip_runtime.h>
#include <hip/hip_bf16.h>

typedef unsigned short ushort_t;
typedef unsigned int   uint_t;
typedef __attribute__((ext_vector_type(8))) _Float16 half8;   // MFMA f16 A/B frag
typedef __attribute__((ext_vector_type(2))) _Float16 half2v;  // packed f16 pair
typedef __attribute__((ext_vector_type(4))) float    floatx4; // MFMA acc

#define B_    2
#define R_    8192
#define HW_   256
#define S_    64
#define NRAYS (B_*R_)
#define PLANE_ELEMS ((size_t)64*HW_*HW_)
#define TRP_ELEMS   ((size_t)HW_*HW_*64)
#define WS_PLANES_BYTES (6ull*B_*TRP_ELEMS*2)   /* 100,663,296 */
#define NW_US 10240    /* weight f16s: 8192 mlp + 2048 head */
#define WV 4           /* waves (rays) per block */
#define NWG (NRAYS/WV) /* 4096 render blocks */
#define NBINS 1024

#define WS_WQ_OFF   WS_PLANES_BYTES
#define WS_KEYS_OFF (WS_WQ_OFF + NW_US*2)
#define WS_PERM_OFF (WS_KEYS_OFF + NRAYS*4)
#define WS_HIST_OFF (WS_PERM_OFF + NRAYS*4)
#define WS_OFFS_OFF (WS_HIST_OFF + NBINS*4)

__device__ __forceinline__ float sp(float x){ return fmaxf(x, 0.f) + __logf(1.f + __expf(-fabsf(x))); }
__device__ __forceinline__ ushort_t f2h(float f){
    union{_Float16 h; ushort_t u;} v; v.h = (_Float16)f; return v.u;
}

// ---------------- Kernel A: transpose planes [C,H,W]f32 -> [H,W,C]f16 ----------------
__global__ __launch_bounds__(256) void tr_planes(
    const float* __restrict__ p0, const float* __restrict__ p1, const float* __restrict__ p2,
    const float* __restrict__ p3, const float* __restrict__ p4, const float* __restrict__ p5,
    ushort_t* __restrict__ outp)
{
    const int blk = blockIdx.x;
    const int y = blk & 255, b = (blk >> 8) & 1, p = blk >> 9;
    const float* src = (p==0)?p0:(p==1)?p1:(p==2)?p2:(p==3)?p3:(p==4)?p4:p5;
    src += (size_t)b*PLANE_ELEMS + (size_t)y*HW_ + threadIdx.x;
    ushort_t* dst = outp + (size_t)(p*2+b)*TRP_ELEMS + ((size_t)y*HW_ + threadIdx.x)*64;

    __attribute__((aligned(16))) ushort_t tmp[64];
#pragma unroll
    for (int c = 0; c < 64; ++c)
        tmp[c] = f2h(src[(size_t)c*HW_*HW_]);
#pragma unroll
    for (int k = 0; k < 8; ++k)
        reinterpret_cast<uint4*>(dst)[k] = reinterpret_cast<const uint4*>(tmp)[k];
}

// ---------------- Kernel A2: weights -> f16, transposed for B-fragments ----------------
__global__ __launch_bounds__(256) void prep_weights(
    const float* __restrict__ mlp_w, const float* __restrict__ w_op,
    const float* __restrict__ w_col, ushort_t* __restrict__ dst)
{
    int i = blockIdx.x*256 + threadIdx.x;
    if (i >= NW_US) return;
    float v;
    if (i < 8192) {
        int l = i >> 12, o = (i >> 6) & 63, c = i & 63;
        v = mlp_w[l*4096 + c*64 + o];
    } else {
        int j = i - 8192, n = j >> 6, c = j & 63;
        v = (n < 16) ? w_col[c*16 + n] : (n == 16 ? w_op[c] : 0.f);
    }
    dst[i] = f2h(v);
}

// ---------------- Sort kernels: spatial counting sort of rays (R8) ----------------
__global__ __launch_bounds__(256) void ray_keys(
    const float* __restrict__ rays, const float* __restrict__ centers,
    const float* __restrict__ nearp, const float* __restrict__ farp,
    uint_t* __restrict__ keys, uint_t* __restrict__ hist)
{
    int rid = blockIdx.x*256 + threadIdx.x;
    if (rid >= NRAYS) return;
    const float t = 0.5f*(nearp[rid] + farp[rid]);
    float c[3];
#pragma unroll
    for (int a = 0; a < 3; ++a) {
        float p = centers[rid*3+a] + t*rays[rid*3+a];
        p = fminf(fmaxf(p, -1.f), 1.f);
        int ci = (int)((p + 1.f)*4.f);
        c[a] = (float)(ci > 7 ? 7 : ci);
    }
    uint_t key = (uint_t)(rid >> 13)*512 + (uint_t)c[2]*64 + (uint_t)c[1]*8 + (uint_t)c[0];
    keys[rid] = key;
    atomicAdd(&hist[key], 1u);
}

__global__ __launch_bounds__(NBINS) void scan_hist(
    const uint_t* __restrict__ hist, uint_t* __restrict__ offs)
{
    __shared__ uint_t tmp[NBINS];
    const int tid = threadIdx.x;
    const uint_t own = hist[tid];
    tmp[tid] = own;
    __syncthreads();
#pragma unroll
    for (int off = 1; off < NBINS; off <<= 1) {
        uint_t v = (tid >= off) ? tmp[tid - off] : 0u;
        __syncthreads();
        tmp[tid] += v;
        __syncthreads();
    }
    offs[tid] = tmp[tid] - own;    // exclusive
}

__global__ __launch_bounds__(256) void scatter_perm(
    const uint_t* __restrict__ keys, uint_t* __restrict__ offs, uint_t* __restrict__ perm)
{
    int rid = blockIdx.x*256 + threadIdx.x;
    if (rid >= NRAYS) return;
    uint_t pos = atomicAdd(&offs[keys[rid]], 1u);
    perm[pos] = (uint_t)rid;
}

// ---------------- Kernel B: render (1 wave = 1 ray; MFMA f16 MLP) ----------------
// R9: MERGED gather — density AND color tap loads issue in one front phase
// (same pos[]). accC (color features + enc) lives in 32 VGPRs across the MLP
// and is written to A only after the heads consume h. Removes the post-MLP
// latency block; doubles in-flight loads during the gather phase.
__global__ __launch_bounds__(256) void render(
    const float* __restrict__ rays, const float* __restrict__ centers,
    const float* __restrict__ enc,  const float* __restrict__ nearp, const float* __restrict__ farp,
    const float* __restrict__ mlp_b, const float* __restrict__ b_op,
    const float* __restrict__ b_col, const float* __restrict__ bgc,
    const ushort_t* __restrict__ trp, const ushort_t* __restrict__ wq,
    const uint_t* __restrict__ perm, float* __restrict__ out)
{
    __shared__ ushort_t A_lds[WV][4096];     // 64 rows x 128B (64 f16), XOR-swizzled 16B slots
    __shared__ float    sd_lds[WV][64];
    __shared__ float    w_lds [WV][64];

    const int wv = threadIdx.x >> 6, lane = threadIdx.x & 63;
    const int sb  = (blockIdx.x & 7)*(NWG/8) + (blockIdx.x >> 3);  // XCD-chunk swizzle
    const int rid = (int)perm[sb*WV + wv];
    const int b = rid >> 13;
    ushort_t* A = &A_lds[wv][0];

    const float nr = nearp[rid], fr = farp[rid];
    const float rdx = rays[rid*3+0], rdy = rays[rid*3+1], rdz = rays[rid*3+2];
    const float rox = centers[rid*3+0], roy = centers[rid*3+1], roz = centers[rid*3+2];
    const float delta = (fr - nr) * (1.f/S_);
    const float t  = nr + (fr - nr) * ((lane + 0.5f) * (1.f/S_));
    const float px = rox + t*rdx, py = roy + t*rdy, pz = roz + t*rdz;

    // bilinear prep (shared by density & color planes: same pts)
    int pos[3]; float a00[3], a01[3], a10[3], a11[3];
    {
        float us[3] = {px, py, pz};
        float vs[3] = {py, pz, px};
#pragma unroll
        for (int p = 0; p < 3; ++p) {
            float x = (fminf(fmaxf(us[p],-1.f),1.f) + 1.f) * 127.5f;
            float y = (fminf(fmaxf(vs[p],-1.f),1.f) + 1.f) * 127.5f;
            int x0 = (int)floorf(x); x0 = x0 < 0 ? 0 : (x0 > 254 ? 254 : x0);
            int y0 = (int)floorf(y); y0 = y0 < 0 ? 0 : (y0 > 254 ? 254 : y0);
            float wx = x - (float)x0, wy = y - (float)y0;
            pos[p] = y0*HW_ + x0;
            a00[p] = (1.f-wx)*(1.f-wy); a01[p] = wx*(1.f-wy);
            a10[p] = (1.f-wx)*wy;       a11[p] = wx*wy;
        }
    }

    // accumulate one plane-triple's taps into acc[32] (half2 packed)
    auto gather_regs = [&](int pbase, half2v* acc) {
#pragma unroll
        for (int p = 0; p < 3; ++p) {
            const ushort_t* base = trp + (size_t)((pbase+p)*2 + b)*TRP_ELEMS + (size_t)pos[p]*64;
#pragma unroll
            for (int corner = 0; corner < 4; ++corner) {
                const ushort_t* cp = base + ((corner & 1) ? 64 : 0) + ((corner & 2) ? 64*HW_ : 0);
                const float w = (corner==0)?a00[p]:(corner==1)?a01[p]:(corner==2)?a10[p]:a11[p];
                const _Float16 wh = (_Float16)w;
                const half2v w2 = half2v{wh, wh};
                union { uint4 v[8]; half2v h[32]; } q;
#pragma unroll
                for (int k = 0; k < 8; ++k) q.v[k] = reinterpret_cast<const uint4*>(cp)[k];
#pragma unroll
                for (int j = 0; j < 32; ++j)
                    acc[j] += w2 * q.h[j];       // v_pk_fma_f16
            }
        }
    };
    // write packed acc[32] into this lane's A row (m = lane), swizzled
    auto writeA = [&](const half2v* acc) {
#pragma unroll
        for (int c8 = 0; c8 < 8; ++c8) {
            union { half2v h[4]; uint4 v; } pk;
#pragma unroll
            for (int j = 0; j < 4; ++j) pk.h[j] = acc[c8*4 + j];
            *reinterpret_cast<uint4*>(reinterpret_cast<char*>(A) + lane*128 + ((c8*16) ^ ((lane&7)<<4)))
                = pk.v;
        }
    };

    // A-fragment load: lane holds row (lane&15) of tile mi, k = kt*32 + (lane>>4)*8 + j
    auto ldfrag = [&](int mi, int kt) -> half8 {
        int m  = mi*16 + (lane&15);
        int cb = (kt*64 + ((lane>>4)*16)) ^ ((m&7)<<4);
        return *reinterpret_cast<const half8*>(reinterpret_cast<const char*>(A) + m*128 + cb);
    };
    auto ldbfrag = [&](const ushort_t* wrow, int nt, int kt) -> half8 {
        return *reinterpret_cast<const half8*>(wrow + (nt*16 + (lane&15))*64 + kt*32 + (lane>>4)*8);
    };
    auto stH = [&](int m, int n, float v) {
        A[(m*128 + ((n*2) ^ ((m&7)<<4))) >> 1] = f2h(v);
    };

    // one MLP layer; af[8] preload is a CORRECTNESS requirement (R3 lesson).
    auto mlp_layer = [&](const ushort_t* wrow, const float* bias) {
        half8 af[8];
#pragma unroll
        for (int mi = 0; mi < 4; ++mi)
#pragma unroll
            for (int kt = 0; kt < 2; ++kt) af[mi*2+kt] = ldfrag(mi, kt);
#pragma unroll
        for (int nt = 0; nt < 4; ++nt) {
            half8 b0 = ldbfrag(wrow, nt, 0);
            half8 b1 = ldbfrag(wrow, nt, 1);
            floatx4 acc[4];
#pragma unroll
            for (int mi = 0; mi < 4; ++mi) {
                acc[mi] = (floatx4){0.f,0.f,0.f,0.f};
                acc[mi] = __builtin_amdgcn_mfma_f32_16x16x32_f16(af[mi*2+0], b0, acc[mi], 0, 0, 0);
                acc[mi] = __builtin_amdgcn_mfma_f32_16x16x32_f16(af[mi*2+1], b1, acc[mi], 0, 0, 0);
            }
            const int n = nt*16 + (lane&15);
            const float bc = bias[n];
#pragma unroll
            for (int mi = 0; mi < 4; ++mi)
#pragma unroll
                for (int r = 0; r < 4; ++r) {
                    int m = mi*16 + (lane>>4)*4 + r;
                    stH(m, n, sp(acc[mi][r] + bc));
                }
        }
    };

    // ---- merged gather phase: all 24 tap lines issue here ----
    half2v accD[32], accC[32];
#pragma unroll
    for (int i = 0; i < 32; ++i) accD[i] = half2v{(_Float16)0.f, (_Float16)0.f};
    {
        const float* er = enc + (size_t)rid*64;
#pragma unroll
        for (int i = 0; i < 16; ++i) {
            float4 e = *reinterpret_cast<const float4*>(er + i*4);
            accC[2*i+0] = half2v{(_Float16)e.x, (_Float16)e.y};
            accC[2*i+1] = half2v{(_Float16)e.z, (_Float16)e.w};
        }
    }
    gather_regs(0, accD);
    gather_regs(3, accC);
    writeA(accD);                        // density features -> A (accD dies)

    // ---- MLP (accC stays resident in VGPRs) ----
    mlp_layer(wq,        mlp_b);         // layer 1
    mlp_layer(wq + 4096, mlp_b + 64);    // layer 2  (A now holds h)

    const ushort_t* whead = wq + 8192;

    // preload h fragments ONCE for both heads
    half8 af[8];
#pragma unroll
    for (int mi = 0; mi < 4; ++mi)
#pragma unroll
        for (int kt = 0; kt < 2; ++kt) af[mi*2+kt] = ldfrag(mi, kt);

    // sigma head: h @ [w_op | 0...]  (col 16 of head region = w_op)
    {
        half8 b0 = ldbfrag(whead, 1, 0);
        half8 b1 = ldbfrag(whead, 1, 1);
        floatx4 accS[4];
#pragma unroll
        for (int mi = 0; mi < 4; ++mi) {
            accS[mi] = (floatx4){0.f,0.f,0.f,0.f};
            accS[mi] = __builtin_amdgcn_mfma_f32_16x16x32_f16(af[mi*2+0], b0, accS[mi], 0, 0, 0);
            accS[mi] = __builtin_amdgcn_mfma_f32_16x16x32_f16(af[mi*2+1], b1, accS[mi], 0, 0, 0);
        }
        if ((lane & 15) == 0) {
            const float bop = b_op[0];
#pragma unroll
            for (int mi = 0; mi < 4; ++mi)
#pragma unroll
                for (int r = 0; r < 4; ++r) {
                    int m = mi*16 + (lane>>4)*4 + r;
                    sd_lds[wv][m] = sp(accS[mi][r] + bop) * delta;
                }
        }
    }

    // color head: h @ Wc (from af), then (fc+enc) @ Wc accumulated
    floatx4 accH[4];
#pragma unroll
    for (int mi = 0; mi < 4; ++mi) accH[mi] = (floatx4){0.f,0.f,0.f,0.f};
    {
        half8 b0 = ldbfrag(whead, 0, 0);
        half8 b1 = ldbfrag(whead, 0, 1);
#pragma unroll
        for (int mi = 0; mi < 4; ++mi) {
            accH[mi] = __builtin_amdgcn_mfma_f32_16x16x32_f16(af[mi*2+0], b0, accH[mi], 0, 0, 0);
            accH[mi] = __builtin_amdgcn_mfma_f32_16x16x32_f16(af[mi*2+1], b1, accH[mi], 0, 0, 0);
        }
        writeA(accC);                    // now safe: heads consumed h from af
#pragma unroll
        for (int mi = 0; mi < 4; ++mi) {
            accH[mi] = __builtin_amdgcn_mfma_f32_16x16x32_f16(ldfrag(mi,0), b0, accH[mi], 0, 0, 0);
            accH[mi] = __builtin_amdgcn_mfma_f32_16x16x32_f16(ldfrag(mi,1), b1, accH[mi], 0, 0, 0);
        }
    }

    // ---- composite: lane = sample ----
    const float sdv = sd_lds[wv][lane];
    float csd = sdv;
#pragma unroll
    for (int off = 1; off < 64; off <<= 1) {
        float nn = __shfl_up(csd, off, 64);
        if (lane >= off) csd += nn;
    }
    const float nlt = __shfl(csd, 63, 64);
    const float Tw  = __expf(sdv - csd) * (1.f - __expf(-sdv));
    const float em  = __expf(-nlt);
    w_lds[wv][lane] = Tw;

    float rl = Tw * t;
#pragma unroll
    for (int off = 32; off > 0; off >>= 1) rl += __shfl_xor(rl, off, 64);

    // feat[k] = sum_m w_m * (color[m][k] + b_col[k]);  k = lane&15
    const float bcn = b_col[lane & 15];
    float pf = 0.f;
#pragma unroll
    for (int mi = 0; mi < 4; ++mi)
#pragma unroll
        for (int r = 0; r < 4; ++r) {
            int m = mi*16 + (lane>>4)*4 + r;
            pf += w_lds[wv][m] * (accH[mi][r] + bcn);
        }
    pf += __shfl_xor(pf, 16, 64);
    pf += __shfl_xor(pf, 32, 64);

    if (lane < 16)
        out[(size_t)rid*16 + lane] = pf + em * bgc[lane];
    if (lane == 0) {
        out[(size_t)NRAYS*16 + rid] = 1.f - em;   // mask
        out[(size_t)NRAYS*17 + rid] = rl;         // ray_len
    }
}

extern "C" void kernel_launch(void* const* d_in, const int* in_sizes, int n_in,
                              void* d_out, int out_size, void* d_ws, size_t ws_size,
                              hipStream_t stream)
{
    const float* rays    = (const float*)d_in[0];
    const float* centers = (const float*)d_in[1];
    const float* enc     = (const float*)d_in[2];
    const float* nearp   = (const float*)d_in[3];
    const float* farp    = (const float*)d_in[4];
    const float* xy      = (const float*)d_in[5];
    const float* yz      = (const float*)d_in[6];
    const float* zx      = (const float*)d_in[7];
    const float* xyc     = (const float*)d_in[8];
    const float* yzc     = (const float*)d_in[9];
    const float* zxc     = (const float*)d_in[10];
    const float* mlp_w   = (const float*)d_in[11];
    const float* mlp_b   = (const float*)d_in[12];
    const float* w_op    = (const float*)d_in[13];
    const float* b_op    = (const float*)d_in[14];
    const float* w_col   = (const float*)d_in[15];
    const float* b_col   = (const float*)d_in[16];
    const float* bg      = (const float*)d_in[17];
    float* out = (float*)d_out;

    char* ws = (char*)d_ws;
    ushort_t* trp  = (ushort_t*)ws;
    ushort_t* wq   = (ushort_t*)(ws + WS_WQ_OFF);
    uint_t*   keys = (uint_t*)(ws + WS_KEYS_OFF);
    uint_t*   perm = (uint_t*)(ws + WS_PERM_OFF);
    uint_t*   hist = (uint_t*)(ws + WS_HIST_OFF);
    uint_t*   offs = (uint_t*)(ws + WS_OFFS_OFF);

    tr_planes<<<6*2*HW_, 256, 0, stream>>>(xy, yz, zx, xyc, yzc, zxc, trp);
    prep_weights<<<(NW_US + 255)/256, 256, 0, stream>>>(mlp_w, w_op, w_col, wq);

    hipMemsetAsync(hist, 0, NBINS*sizeof(uint_t), stream);
    ray_keys<<<NRAYS/256, 256, 0, stream>>>(rays, centers, nearp, farp, keys, hist);
    scan_hist<<<1, NBINS, 0, stream>>>(hist, offs);
    scatter_perm<<<NRAYS/256, 256, 0, stream>>>(keys, offs, perm);

    render<<<NWG, WV*64, 0, stream>>>(
        rays, centers, enc, nearp, farp, mlp_b, b_op, b_col, bg, trp, wq, perm, out);
}

// Round 11
// 656.111 us; speedup vs baseline: 2.3483x; 1.0363x over previous
//
#include <hip/hip_runtime.h>
#include <hip/hip_bf16.h>

typedef unsigned short ushort_t;
typedef unsigned int   uint_t;
typedef __attribute__((ext_vector_type(8))) _Float16 half8;   // MFMA f16 A/B frag
typedef __attribute__((ext_vector_type(2))) _Float16 half2v;  // packed f16 pair
typedef __attribute__((ext_vector_type(4))) float    floatx4; // MFMA acc

#define B_    2
#define R_    8192
#define HW_   256
#define S_    64
#define NRAYS (B_*R_)
#define PLANE_ELEMS ((size_t)64*HW_*HW_)
#define TRP_ELEMS   ((size_t)HW_*HW_*64)
#define WS_PLANES_BYTES (6ull*B_*TRP_ELEMS*2)   /* 100,663,296 */
#define NW_US 10240    /* weight f16s: 8192 mlp + 2048 head */
#define WV 4           /* waves (rays) per block */
#define NWG (NRAYS/WV) /* 4096 render blocks */
#define NBINS 1024

#define WS_WQ_OFF   WS_PLANES_BYTES
#define WS_KEYS_OFF (WS_WQ_OFF + NW_US*2)
#define WS_PERM_OFF (WS_KEYS_OFF + NRAYS*4)
#define WS_HIST_OFF (WS_PERM_OFF + NRAYS*4)
#define WS_OFFS_OFF (WS_HIST_OFF + NBINS*4)

__device__ __forceinline__ float sp(float x){ return fmaxf(x, 0.f) + __logf(1.f + __expf(-fabsf(x))); }
__device__ __forceinline__ ushort_t f2h(float f){
    union{_Float16 h; ushort_t u;} v; v.h = (_Float16)f; return v.u;
}

// ---------------- Kernel A: transpose planes [C,H,W]f32 -> [H,W,C]f16 ----------------
__global__ __launch_bounds__(256) void tr_planes(
    const float* __restrict__ p0, const float* __restrict__ p1, const float* __restrict__ p2,
    const float* __restrict__ p3, const float* __restrict__ p4, const float* __restrict__ p5,
    ushort_t* __restrict__ outp)
{
    const int blk = blockIdx.x;
    const int y = blk & 255, b = (blk >> 8) & 1, p = blk >> 9;
    const float* src = (p==0)?p0:(p==1)?p1:(p==2)?p2:(p==3)?p3:(p==4)?p4:p5;
    src += (size_t)b*PLANE_ELEMS + (size_t)y*HW_ + threadIdx.x;
    ushort_t* dst = outp + (size_t)(p*2+b)*TRP_ELEMS + ((size_t)y*HW_ + threadIdx.x)*64;

    __attribute__((aligned(16))) ushort_t tmp[64];
#pragma unroll
    for (int c = 0; c < 64; ++c)
        tmp[c] = f2h(src[(size_t)c*HW_*HW_]);
#pragma unroll
    for (int k = 0; k < 8; ++k)
        reinterpret_cast<uint4*>(dst)[k] = reinterpret_cast<const uint4*>(tmp)[k];
}

// ---------------- Kernel A2: weights -> f16, transposed for B-fragments ----------------
__global__ __launch_bounds__(256) void prep_weights(
    const float* __restrict__ mlp_w, const float* __restrict__ w_op,
    const float* __restrict__ w_col, ushort_t* __restrict__ dst)
{
    int i = blockIdx.x*256 + threadIdx.x;
    if (i >= NW_US) return;
    float v;
    if (i < 8192) {
        int l = i >> 12, o = (i >> 6) & 63, c = i & 63;
        v = mlp_w[l*4096 + c*64 + o];
    } else {
        int j = i - 8192, n = j >> 6, c = j & 63;
        v = (n < 16) ? w_col[c*16 + n] : (n == 16 ? w_op[c] : 0.f);
    }
    dst[i] = f2h(v);
}

// ---------------- Sort kernels: spatial counting sort of rays (R8) ----------------
__global__ __launch_bounds__(256) void ray_keys(
    const float* __restrict__ rays, const float* __restrict__ centers,
    const float* __restrict__ nearp, const float* __restrict__ farp,
    uint_t* __restrict__ keys, uint_t* __restrict__ hist)
{
    int rid = blockIdx.x*256 + threadIdx.x;
    if (rid >= NRAYS) return;
    const float t = 0.5f*(nearp[rid] + farp[rid]);
    float c[3];
#pragma unroll
    for (int a = 0; a < 3; ++a) {
        float p = centers[rid*3+a] + t*rays[rid*3+a];
        p = fminf(fmaxf(p, -1.f), 1.f);
        int ci = (int)((p + 1.f)*4.f);
        c[a] = (float)(ci > 7 ? 7 : ci);
    }
    uint_t key = (uint_t)(rid >> 13)*512 + (uint_t)c[2]*64 + (uint_t)c[1]*8 + (uint_t)c[0];
    keys[rid] = key;
    atomicAdd(&hist[key], 1u);
}

__global__ __launch_bounds__(NBINS) void scan_hist(
    const uint_t* __restrict__ hist, uint_t* __restrict__ offs)
{
    __shared__ uint_t tmp[NBINS];
    const int tid = threadIdx.x;
    const uint_t own = hist[tid];
    tmp[tid] = own;
    __syncthreads();
#pragma unroll
    for (int off = 1; off < NBINS; off <<= 1) {
        uint_t v = (tid >= off) ? tmp[tid - off] : 0u;
        __syncthreads();
        tmp[tid] += v;
        __syncthreads();
    }
    offs[tid] = tmp[tid] - own;    // exclusive
}

__global__ __launch_bounds__(256) void scatter_perm(
    const uint_t* __restrict__ keys, uint_t* __restrict__ offs, uint_t* __restrict__ perm)
{
    int rid = blockIdx.x*256 + threadIdx.x;
    if (rid >= NRAYS) return;
    uint_t pos = atomicAdd(&offs[keys[rid]], 1u);
    perm[pos] = (uint_t)rid;
}

// ---------------- Kernel B: render (1 wave = 1 ray; MFMA f16 MLP) ----------------
// R10: merged gather kept, but the (fc+enc)@Wc GEMM is hoisted BEFORE the MLP
// (color = h@Wc + (fc+enc)@Wc). accC + line buffers die before the MLP; the
// only cross-phase state is accH (16 f32 regs). R9 held accC(32 f16 regs)
// across the MLP and hit the 256-VGPR ceiling: 157 MB scratch spill.
__global__ __launch_bounds__(256) void render(
    const float* __restrict__ rays, const float* __restrict__ centers,
    const float* __restrict__ enc,  const float* __restrict__ nearp, const float* __restrict__ farp,
    const float* __restrict__ mlp_b, const float* __restrict__ b_op,
    const float* __restrict__ b_col, const float* __restrict__ bgc,
    const ushort_t* __restrict__ trp, const ushort_t* __restrict__ wq,
    const uint_t* __restrict__ perm, float* __restrict__ out)
{
    __shared__ ushort_t A_lds[WV][4096];     // 64 rows x 128B (64 f16), XOR-swizzled 16B slots
    __shared__ float    sd_lds[WV][64];
    __shared__ float    w_lds [WV][64];

    const int wv = threadIdx.x >> 6, lane = threadIdx.x & 63;
    const int sb  = (blockIdx.x & 7)*(NWG/8) + (blockIdx.x >> 3);  // XCD-chunk swizzle
    const int rid = (int)perm[sb*WV + wv];
    const int b = rid >> 13;
    ushort_t* A = &A_lds[wv][0];

    const float nr = nearp[rid], fr = farp[rid];
    const float rdx = rays[rid*3+0], rdy = rays[rid*3+1], rdz = rays[rid*3+2];
    const float rox = centers[rid*3+0], roy = centers[rid*3+1], roz = centers[rid*3+2];
    const float delta = (fr - nr) * (1.f/S_);
    const float t  = nr + (fr - nr) * ((lane + 0.5f) * (1.f/S_));
    const float px = rox + t*rdx, py = roy + t*rdy, pz = roz + t*rdz;

    // bilinear prep (shared by density & color planes: same pts)
    int pos[3]; float a00[3], a01[3], a10[3], a11[3];
    {
        float us[3] = {px, py, pz};
        float vs[3] = {py, pz, px};
#pragma unroll
        for (int p = 0; p < 3; ++p) {
            float x = (fminf(fmaxf(us[p],-1.f),1.f) + 1.f) * 127.5f;
            float y = (fminf(fmaxf(vs[p],-1.f),1.f) + 1.f) * 127.5f;
            int x0 = (int)floorf(x); x0 = x0 < 0 ? 0 : (x0 > 254 ? 254 : x0);
            int y0 = (int)floorf(y); y0 = y0 < 0 ? 0 : (y0 > 254 ? 254 : y0);
            float wx = x - (float)x0, wy = y - (float)y0;
            pos[p] = y0*HW_ + x0;
            a00[p] = (1.f-wx)*(1.f-wy); a01[p] = wx*(1.f-wy);
            a10[p] = (1.f-wx)*wy;       a11[p] = wx*wy;
        }
    }

    // accumulate one plane-triple's taps into acc[32] (half2 packed)
    auto gather_regs = [&](int pbase, half2v* acc) {
#pragma unroll
        for (int p = 0; p < 3; ++p) {
            const ushort_t* base = trp + (size_t)((pbase+p)*2 + b)*TRP_ELEMS + (size_t)pos[p]*64;
#pragma unroll
            for (int corner = 0; corner < 4; ++corner) {
                const ushort_t* cp = base + ((corner & 1) ? 64 : 0) + ((corner & 2) ? 64*HW_ : 0);
                const float w = (corner==0)?a00[p]:(corner==1)?a01[p]:(corner==2)?a10[p]:a11[p];
                const _Float16 wh = (_Float16)w;
                const half2v w2 = half2v{wh, wh};
                union { uint4 v[8]; half2v h[32]; } q;
#pragma unroll
                for (int k = 0; k < 8; ++k) q.v[k] = reinterpret_cast<const uint4*>(cp)[k];
#pragma unroll
                for (int j = 0; j < 32; ++j)
                    acc[j] += w2 * q.h[j];       // v_pk_fma_f16
            }
        }
    };
    // write packed acc[32] into this lane's A row (m = lane), swizzled
    auto writeA = [&](const half2v* acc) {
#pragma unroll
        for (int c8 = 0; c8 < 8; ++c8) {
            union { half2v h[4]; uint4 v; } pk;
#pragma unroll
            for (int j = 0; j < 4; ++j) pk.h[j] = acc[c8*4 + j];
            *reinterpret_cast<uint4*>(reinterpret_cast<char*>(A) + lane*128 + ((c8*16) ^ ((lane&7)<<4)))
                = pk.v;
        }
    };

    // A-fragment load: lane holds row (lane&15) of tile mi, k = kt*32 + (lane>>4)*8 + j
    auto ldfrag = [&](int mi, int kt) -> half8 {
        int m  = mi*16 + (lane&15);
        int cb = (kt*64 + ((lane>>4)*16)) ^ ((m&7)<<4);
        return *reinterpret_cast<const half8*>(reinterpret_cast<const char*>(A) + m*128 + cb);
    };
    auto ldbfrag = [&](const ushort_t* wrow, int nt, int kt) -> half8 {
        return *reinterpret_cast<const half8*>(wrow + (nt*16 + (lane&15))*64 + kt*32 + (lane>>4)*8);
    };
    auto stH = [&](int m, int n, float v) {
        A[(m*128 + ((n*2) ^ ((m&7)<<4))) >> 1] = f2h(v);
    };

    // one MLP layer; af[8] preload is a CORRECTNESS requirement (R3 lesson).
    auto mlp_layer = [&](const ushort_t* wrow, const float* bias) {
        half8 af[8];
#pragma unroll
        for (int mi = 0; mi < 4; ++mi)
#pragma unroll
            for (int kt = 0; kt < 2; ++kt) af[mi*2+kt] = ldfrag(mi, kt);
#pragma unroll
        for (int nt = 0; nt < 4; ++nt) {
            half8 b0 = ldbfrag(wrow, nt, 0);
            half8 b1 = ldbfrag(wrow, nt, 1);
            floatx4 acc[4];
#pragma unroll
            for (int mi = 0; mi < 4; ++mi) {
                acc[mi] = (floatx4){0.f,0.f,0.f,0.f};
                acc[mi] = __builtin_amdgcn_mfma_f32_16x16x32_f16(af[mi*2+0], b0, acc[mi], 0, 0, 0);
                acc[mi] = __builtin_amdgcn_mfma_f32_16x16x32_f16(af[mi*2+1], b1, acc[mi], 0, 0, 0);
            }
            const int n = nt*16 + (lane&15);
            const float bc = bias[n];
#pragma unroll
            for (int mi = 0; mi < 4; ++mi)
#pragma unroll
                for (int r = 0; r < 4; ++r) {
                    int m = mi*16 + (lane>>4)*4 + r;
                    stH(m, n, sp(acc[mi][r] + bc));
                }
        }
    };

    const ushort_t* whead = wq + 8192;

    // ---- merged gather phase: all 24 tap lines issue here ----
    half2v accD[32], accC[32];
#pragma unroll
    for (int i = 0; i < 32; ++i) accD[i] = half2v{(_Float16)0.f, (_Float16)0.f};
    {
        const float* er = enc + (size_t)rid*64;
#pragma unroll
        for (int i = 0; i < 16; ++i) {
            float4 e = *reinterpret_cast<const float4*>(er + i*4);
            accC[2*i+0] = half2v{(_Float16)e.x, (_Float16)e.y};
            accC[2*i+1] = half2v{(_Float16)e.z, (_Float16)e.w};
        }
    }
    gather_regs(0, accD);
    gather_regs(3, accC);

    // ---- early color GEMM: accH = (fc + enc) @ Wc  (independent of MLP) ----
    floatx4 accH[4];
#pragma unroll
    for (int mi = 0; mi < 4; ++mi) accH[mi] = (floatx4){0.f,0.f,0.f,0.f};
    {
        writeA(accC);                    // accC dies here
        half8 b0 = ldbfrag(whead, 0, 0);
        half8 b1 = ldbfrag(whead, 0, 1);
#pragma unroll
        for (int mi = 0; mi < 4; ++mi) {
            accH[mi] = __builtin_amdgcn_mfma_f32_16x16x32_f16(ldfrag(mi,0), b0, accH[mi], 0, 0, 0);
            accH[mi] = __builtin_amdgcn_mfma_f32_16x16x32_f16(ldfrag(mi,1), b1, accH[mi], 0, 0, 0);
        }
    }
    // DS ops are in-order per wave and alias on A: the frag reads above
    // complete before this overwrite.
    writeA(accD);                        // density features -> A (accD dies)

    // ---- MLP (only accH: 16 f32 regs live across) ----
    mlp_layer(wq,        mlp_b);         // layer 1
    mlp_layer(wq + 4096, mlp_b + 64);    // layer 2  (A now holds h)

    // preload h fragments ONCE for both heads
    half8 af[8];
#pragma unroll
    for (int mi = 0; mi < 4; ++mi)
#pragma unroll
        for (int kt = 0; kt < 2; ++kt) af[mi*2+kt] = ldfrag(mi, kt);

    // sigma head: h @ [w_op | 0...]  (col 16 of head region = w_op)
    {
        half8 b0 = ldbfrag(whead, 1, 0);
        half8 b1 = ldbfrag(whead, 1, 1);
        floatx4 accS[4];
#pragma unroll
        for (int mi = 0; mi < 4; ++mi) {
            accS[mi] = (floatx4){0.f,0.f,0.f,0.f};
            accS[mi] = __builtin_amdgcn_mfma_f32_16x16x32_f16(af[mi*2+0], b0, accS[mi], 0, 0, 0);
            accS[mi] = __builtin_amdgcn_mfma_f32_16x16x32_f16(af[mi*2+1], b1, accS[mi], 0, 0, 0);
        }
        if ((lane & 15) == 0) {
            const float bop = b_op[0];
#pragma unroll
            for (int mi = 0; mi < 4; ++mi)
#pragma unroll
                for (int r = 0; r < 4; ++r) {
                    int m = mi*16 + (lane>>4)*4 + r;
                    sd_lds[wv][m] = sp(accS[mi][r] + bop) * delta;
                }
        }
    }

    // color head part 2: accH += h @ Wc
    {
        half8 b0 = ldbfrag(whead, 0, 0);
        half8 b1 = ldbfrag(whead, 0, 1);
#pragma unroll
        for (int mi = 0; mi < 4; ++mi) {
            accH[mi] = __builtin_amdgcn_mfma_f32_16x16x32_f16(af[mi*2+0], b0, accH[mi], 0, 0, 0);
            accH[mi] = __builtin_amdgcn_mfma_f32_16x16x32_f16(af[mi*2+1], b1, accH[mi], 0, 0, 0);
        }
    }

    // ---- composite: lane = sample ----
    const float sdv = sd_lds[wv][lane];
    float csd = sdv;
#pragma unroll
    for (int off = 1; off < 64; off <<= 1) {
        float nn = __shfl_up(csd, off, 64);
        if (lane >= off) csd += nn;
    }
    const float nlt = __shfl(csd, 63, 64);
    const float Tw  = __expf(sdv - csd) * (1.f - __expf(-sdv));
    const float em  = __expf(-nlt);
    w_lds[wv][lane] = Tw;

    float rl = Tw * t;
#pragma unroll
    for (int off = 32; off > 0; off >>= 1) rl += __shfl_xor(rl, off, 64);

    // feat[k] = sum_m w_m * (color[m][k] + b_col[k]);  k = lane&15
    const float bcn = b_col[lane & 15];
    float pf = 0.f;
#pragma unroll
    for (int mi = 0; mi < 4; ++mi)
#pragma unroll
        for (int r = 0; r < 4; ++r) {
            int m = mi*16 + (lane>>4)*4 + r;
            pf += w_lds[wv][m] * (accH[mi][r] + bcn);
        }
    pf += __shfl_xor(pf, 16, 64);
    pf += __shfl_xor(pf, 32, 64);

    if (lane < 16)
        out[(size_t)rid*16 + lane] = pf + em * bgc[lane];
    if (lane == 0) {
        out[(size_t)NRAYS*16 + rid] = 1.f - em;   // mask
        out[(size_t)NRAYS*17 + rid] = rl;         // ray_len
    }
}

extern "C" void kernel_launch(void* const* d_in, const int* in_sizes, int n_in,
                              void* d_out, int out_size, void* d_ws, size_t ws_size,
                              hipStream_t stream)
{
    const float* rays    = (const float*)d_in[0];
    const float* centers = (const float*)d_in[1];
    const float* enc     = (const float*)d_in[2];
    const float* nearp   = (const float*)d_in[3];
    const float* farp    = (const float*)d_in[4];
    const float* xy      = (const float*)d_in[5];
    const float* yz      = (const float*)d_in[6];
    const float* zx      = (const float*)d_in[7];
    const float* xyc     = (const float*)d_in[8];
    const float* yzc     = (const float*)d_in[9];
    const float* zxc     = (const float*)d_in[10];
    const float* mlp_w   = (const float*)d_in[11];
    const float* mlp_b   = (const float*)d_in[12];
    const float* w_op    = (const float*)d_in[13];
    const float* b_op    = (const float*)d_in[14];
    const float* w_col   = (const float*)d_in[15];
    const float* b_col   = (const float*)d_in[16];
    const float* bg      = (const float*)d_in[17];
    float* out = (float*)d_out;

    char* ws = (char*)d_ws;
    ushort_t* trp  = (ushort_t*)ws;
    ushort_t* wq   = (ushort_t*)(ws + WS_WQ_OFF);
    uint_t*   keys = (uint_t*)(ws + WS_KEYS_OFF);
    uint_t*   perm = (uint_t*)(ws + WS_PERM_OFF);
    uint_t*   hist = (uint_t*)(ws + WS_HIST_OFF);
    uint_t*   offs = (uint_t*)(ws + WS_OFFS_OFF);

    tr_planes<<<6*2*HW_, 256, 0, stream>>>(xy, yz, zx, xyc, yzc, zxc, trp);
    prep_weights<<<(NW_US + 255)/256, 256, 0, stream>>>(mlp_w, w_op, w_col, wq);

    hipMemsetAsync(hist, 0, NBINS*sizeof(uint_t), stream);
    ray_keys<<<NRAYS/256, 256, 0, stream>>>(rays, centers, nearp, farp, keys, hist);
    scan_hist<<<1, NBINS, 0, stream>>>(hist, offs);
    scatter_perm<<<NRAYS/256, 256, 0, stream>>>(keys, offs, perm);

    render<<<NWG, WV*64, 0, stream>>>(
        rays, centers, enc, nearp, farp, mlp_b, b_op, b_col, bg, trp, wq, perm, out);
}

// Round 12
// 559.504 us; speedup vs baseline: 2.7537x; 1.1727x over previous
//
#include <hip/hip_runtime.h>
#include <hip/hip_bf16.h>

typedef unsigned short ushort_t;
typedef unsigned int   uint_t;
typedef __attribute__((ext_vector_type(8))) _Float16 half8;   // MFMA f16 A/B frag
typedef __attribute__((ext_vector_type(2))) _Float16 half2v;  // packed f16 pair
typedef __attribute__((ext_vector_type(4))) float    floatx4; // MFMA acc

#define B_    2
#define R_    8192
#define HW_   256
#define S_    64
#define NRAYS (B_*R_)
#define PLANE_ELEMS ((size_t)64*HW_*HW_)
#define TRP_ELEMS   ((size_t)HW_*HW_*64)
#define WS_PLANES_BYTES (6ull*B_*TRP_ELEMS*2)   /* 100,663,296 */
#define NW_US 10240    /* weight f16s: 8192 mlp + 2048 head */
#define WV 4           /* waves (rays) per block */
#define NWG (NRAYS/WV) /* 4096 render blocks */
#define NBINS 1024

#define WS_WQ_OFF   WS_PLANES_BYTES
#define WS_KEYS_OFF (WS_WQ_OFF + NW_US*2)
#define WS_PERM_OFF (WS_KEYS_OFF + NRAYS*4)
#define WS_HIST_OFF (WS_PERM_OFF + NRAYS*4)
#define WS_OFFS_OFF (WS_HIST_OFF + NBINS*4)

__device__ __forceinline__ float sp(float x){ return fmaxf(x, 0.f) + __logf(1.f + __expf(-fabsf(x))); }
__device__ __forceinline__ ushort_t f2h(float f){
    union{_Float16 h; ushort_t u;} v; v.h = (_Float16)f; return v.u;
}

// ---------------- Kernel A: transpose planes [C,H,W]f32 -> [H,W,C]f16 ----------------
__global__ __launch_bounds__(256) void tr_planes(
    const float* __restrict__ p0, const float* __restrict__ p1, const float* __restrict__ p2,
    const float* __restrict__ p3, const float* __restrict__ p4, const float* __restrict__ p5,
    ushort_t* __restrict__ outp)
{
    const int blk = blockIdx.x;
    const int y = blk & 255, b = (blk >> 8) & 1, p = blk >> 9;
    const float* src = (p==0)?p0:(p==1)?p1:(p==2)?p2:(p==3)?p3:(p==4)?p4:p5;
    src += (size_t)b*PLANE_ELEMS + (size_t)y*HW_ + threadIdx.x;
    ushort_t* dst = outp + (size_t)(p*2+b)*TRP_ELEMS + ((size_t)y*HW_ + threadIdx.x)*64;

    __attribute__((aligned(16))) ushort_t tmp[64];
#pragma unroll
    for (int c = 0; c < 64; ++c)
        tmp[c] = f2h(src[(size_t)c*HW_*HW_]);
#pragma unroll
    for (int k = 0; k < 8; ++k)
        reinterpret_cast<uint4*>(dst)[k] = reinterpret_cast<const uint4*>(tmp)[k];
}

// ---------------- Kernel A2: weights -> f16, transposed for B-fragments ----------------
__global__ __launch_bounds__(256) void prep_weights(
    const float* __restrict__ mlp_w, const float* __restrict__ w_op,
    const float* __restrict__ w_col, ushort_t* __restrict__ dst)
{
    int i = blockIdx.x*256 + threadIdx.x;
    if (i >= NW_US) return;
    float v;
    if (i < 8192) {
        int l = i >> 12, o = (i >> 6) & 63, c = i & 63;
        v = mlp_w[l*4096 + c*64 + o];
    } else {
        int j = i - 8192, n = j >> 6, c = j & 63;
        v = (n < 16) ? w_col[c*16 + n] : (n == 16 ? w_op[c] : 0.f);
    }
    dst[i] = f2h(v);
}

// ---------------- Sort kernels: spatial counting sort of rays (R8) ----------------
__global__ __launch_bounds__(256) void ray_keys(
    const float* __restrict__ rays, const float* __restrict__ centers,
    const float* __restrict__ nearp, const float* __restrict__ farp,
    uint_t* __restrict__ keys, uint_t* __restrict__ hist)
{
    int rid = blockIdx.x*256 + threadIdx.x;
    if (rid >= NRAYS) return;
    const float t = 0.5f*(nearp[rid] + farp[rid]);
    float c[3];
#pragma unroll
    for (int a = 0; a < 3; ++a) {
        float p = centers[rid*3+a] + t*rays[rid*3+a];
        p = fminf(fmaxf(p, -1.f), 1.f);
        int ci = (int)((p + 1.f)*4.f);
        c[a] = (float)(ci > 7 ? 7 : ci);
    }
    uint_t key = (uint_t)(rid >> 13)*512 + (uint_t)c[2]*64 + (uint_t)c[1]*8 + (uint_t)c[0];
    keys[rid] = key;
    atomicAdd(&hist[key], 1u);
}

__global__ __launch_bounds__(NBINS) void scan_hist(
    const uint_t* __restrict__ hist, uint_t* __restrict__ offs)
{
    __shared__ uint_t tmp[NBINS];
    const int tid = threadIdx.x;
    const uint_t own = hist[tid];
    tmp[tid] = own;
    __syncthreads();
#pragma unroll
    for (int off = 1; off < NBINS; off <<= 1) {
        uint_t v = (tid >= off) ? tmp[tid - off] : 0u;
        __syncthreads();
        tmp[tid] += v;
        __syncthreads();
    }
    offs[tid] = tmp[tid] - own;    // exclusive
}

__global__ __launch_bounds__(256) void scatter_perm(
    const uint_t* __restrict__ keys, uint_t* __restrict__ offs, uint_t* __restrict__ perm)
{
    int rid = blockIdx.x*256 + threadIdx.x;
    if (rid >= NRAYS) return;
    uint_t pos = atomicAdd(&offs[keys[rid]], 1u);
    perm[pos] = (uint_t)rid;
}

// ---------------- Kernel B: render (1 wave = 1 ray; MFMA f16 MLP) ----------------
// R11: split gathers so only ONE 32-reg accumulator is live at a time.
// Goal: VGPR <= 128 — HW allocates wave VGPRs in 64/128/256 steps (m68/m69);
// R10's 132 VGPR occupied a 256-slot -> 2 waves/SIMD, occupancy pinned ~11%.
// Order: gather color -> writeA -> (fc+enc)@Wc GEMM -> gather density ->
// writeA -> MLP -> heads. No launch-bounds hints (R2/R6 spill rule).
__global__ __launch_bounds__(256) void render(
    const float* __restrict__ rays, const float* __restrict__ centers,
    const float* __restrict__ enc,  const float* __restrict__ nearp, const float* __restrict__ farp,
    const float* __restrict__ mlp_b, const float* __restrict__ b_op,
    const float* __restrict__ b_col, const float* __restrict__ bgc,
    const ushort_t* __restrict__ trp, const ushort_t* __restrict__ wq,
    const uint_t* __restrict__ perm, float* __restrict__ out)
{
    __shared__ ushort_t A_lds[WV][4096];     // 64 rows x 128B (64 f16), XOR-swizzled 16B slots
    __shared__ float    sd_lds[WV][64];
    __shared__ float    w_lds [WV][64];

    const int wv = threadIdx.x >> 6, lane = threadIdx.x & 63;
    const int sb  = (blockIdx.x & 7)*(NWG/8) + (blockIdx.x >> 3);  // XCD-chunk swizzle
    const int rid = (int)perm[sb*WV + wv];
    const int b = rid >> 13;
    ushort_t* A = &A_lds[wv][0];

    const float nr = nearp[rid], fr = farp[rid];
    const float rdx = rays[rid*3+0], rdy = rays[rid*3+1], rdz = rays[rid*3+2];
    const float rox = centers[rid*3+0], roy = centers[rid*3+1], roz = centers[rid*3+2];
    const float delta = (fr - nr) * (1.f/S_);
    const float t  = nr + (fr - nr) * ((lane + 0.5f) * (1.f/S_));
    const float px = rox + t*rdx, py = roy + t*rdy, pz = roz + t*rdz;

    // bilinear prep (shared by density & color planes: same pts)
    int pos[3]; float a00[3], a01[3], a10[3], a11[3];
    {
        float us[3] = {px, py, pz};
        float vs[3] = {py, pz, px};
#pragma unroll
        for (int p = 0; p < 3; ++p) {
            float x = (fminf(fmaxf(us[p],-1.f),1.f) + 1.f) * 127.5f;
            float y = (fminf(fmaxf(vs[p],-1.f),1.f) + 1.f) * 127.5f;
            int x0 = (int)floorf(x); x0 = x0 < 0 ? 0 : (x0 > 254 ? 254 : x0);
            int y0 = (int)floorf(y); y0 = y0 < 0 ? 0 : (y0 > 254 ? 254 : y0);
            float wx = x - (float)x0, wy = y - (float)y0;
            pos[p] = y0*HW_ + x0;
            a00[p] = (1.f-wx)*(1.f-wy); a01[p] = wx*(1.f-wy);
            a10[p] = (1.f-wx)*wy;       a11[p] = wx*wy;
        }
    }

    // accumulate one plane-triple's taps into acc[32] (half2 packed)
    auto gather_regs = [&](int pbase, half2v* acc) {
#pragma unroll
        for (int p = 0; p < 3; ++p) {
            const ushort_t* base = trp + (size_t)((pbase+p)*2 + b)*TRP_ELEMS + (size_t)pos[p]*64;
#pragma unroll
            for (int corner = 0; corner < 4; ++corner) {
                const ushort_t* cp = base + ((corner & 1) ? 64 : 0) + ((corner & 2) ? 64*HW_ : 0);
                const float w = (corner==0)?a00[p]:(corner==1)?a01[p]:(corner==2)?a10[p]:a11[p];
                const _Float16 wh = (_Float16)w;
                const half2v w2 = half2v{wh, wh};
                union { uint4 v[8]; half2v h[32]; } q;
#pragma unroll
                for (int k = 0; k < 8; ++k) q.v[k] = reinterpret_cast<const uint4*>(cp)[k];
#pragma unroll
                for (int j = 0; j < 32; ++j)
                    acc[j] += w2 * q.h[j];       // v_pk_fma_f16
            }
        }
    };
    // write packed acc[32] into this lane's A row (m = lane), swizzled
    auto writeA = [&](const half2v* acc) {
#pragma unroll
        for (int c8 = 0; c8 < 8; ++c8) {
            union { half2v h[4]; uint4 v; } pk;
#pragma unroll
            for (int j = 0; j < 4; ++j) pk.h[j] = acc[c8*4 + j];
            *reinterpret_cast<uint4*>(reinterpret_cast<char*>(A) + lane*128 + ((c8*16) ^ ((lane&7)<<4)))
                = pk.v;
        }
    };

    // A-fragment load: lane holds row (lane&15) of tile mi, k = kt*32 + (lane>>4)*8 + j
    auto ldfrag = [&](int mi, int kt) -> half8 {
        int m  = mi*16 + (lane&15);
        int cb = (kt*64 + ((lane>>4)*16)) ^ ((m&7)<<4);
        return *reinterpret_cast<const half8*>(reinterpret_cast<const char*>(A) + m*128 + cb);
    };
    auto ldbfrag = [&](const ushort_t* wrow, int nt, int kt) -> half8 {
        return *reinterpret_cast<const half8*>(wrow + (nt*16 + (lane&15))*64 + kt*32 + (lane>>4)*8);
    };
    auto stH = [&](int m, int n, float v) {
        A[(m*128 + ((n*2) ^ ((m&7)<<4))) >> 1] = f2h(v);
    };

    // one MLP layer; af[8] preload is a CORRECTNESS requirement (R3 lesson).
    auto mlp_layer = [&](const ushort_t* wrow, const float* bias) {
        half8 af[8];
#pragma unroll
        for (int mi = 0; mi < 4; ++mi)
#pragma unroll
            for (int kt = 0; kt < 2; ++kt) af[mi*2+kt] = ldfrag(mi, kt);
#pragma unroll
        for (int nt = 0; nt < 4; ++nt) {
            half8 b0 = ldbfrag(wrow, nt, 0);
            half8 b1 = ldbfrag(wrow, nt, 1);
            floatx4 acc[4];
#pragma unroll
            for (int mi = 0; mi < 4; ++mi) {
                acc[mi] = (floatx4){0.f,0.f,0.f,0.f};
                acc[mi] = __builtin_amdgcn_mfma_f32_16x16x32_f16(af[mi*2+0], b0, acc[mi], 0, 0, 0);
                acc[mi] = __builtin_amdgcn_mfma_f32_16x16x32_f16(af[mi*2+1], b1, acc[mi], 0, 0, 0);
            }
            const int n = nt*16 + (lane&15);
            const float bc = bias[n];
#pragma unroll
            for (int mi = 0; mi < 4; ++mi)
#pragma unroll
                for (int r = 0; r < 4; ++r) {
                    int m = mi*16 + (lane>>4)*4 + r;
                    stH(m, n, sp(acc[mi][r] + bc));
                }
        }
    };

    const ushort_t* whead = wq + 8192;
    floatx4 accH[4];
#pragma unroll
    for (int mi = 0; mi < 4; ++mi) accH[mi] = (floatx4){0.f,0.f,0.f,0.f};

    // ---- phase 1: color gather -> A -> early GEMM (fc+enc)@Wc ----
    {
        half2v accC[32];
        const float* er = enc + (size_t)rid*64;
#pragma unroll
        for (int i = 0; i < 16; ++i) {
            float4 e = *reinterpret_cast<const float4*>(er + i*4);
            accC[2*i+0] = half2v{(_Float16)e.x, (_Float16)e.y};
            accC[2*i+1] = half2v{(_Float16)e.z, (_Float16)e.w};
        }
        gather_regs(3, accC);
        writeA(accC);                    // accC dies here
        half8 b0 = ldbfrag(whead, 0, 0);
        half8 b1 = ldbfrag(whead, 0, 1);
#pragma unroll
        for (int mi = 0; mi < 4; ++mi) {
            accH[mi] = __builtin_amdgcn_mfma_f32_16x16x32_f16(ldfrag(mi,0), b0, accH[mi], 0, 0, 0);
            accH[mi] = __builtin_amdgcn_mfma_f32_16x16x32_f16(ldfrag(mi,1), b1, accH[mi], 0, 0, 0);
        }
    }

    // ---- phase 2: density gather -> A ----
    {
        half2v accD[32];
#pragma unroll
        for (int i = 0; i < 32; ++i) accD[i] = half2v{(_Float16)0.f, (_Float16)0.f};
        gather_regs(0, accD);
        // DS ops are in-order per wave and alias on A: phase-1 frag reads
        // complete before this overwrite.
        writeA(accD);                    // accD dies here
    }

    // ---- MLP (only accH: 16 f32 regs live across) ----
    mlp_layer(wq,        mlp_b);         // layer 1
    mlp_layer(wq + 4096, mlp_b + 64);    // layer 2  (A now holds h)

    // preload h fragments ONCE for both heads (heads only read A)
    half8 af[8];
#pragma unroll
    for (int mi = 0; mi < 4; ++mi)
#pragma unroll
        for (int kt = 0; kt < 2; ++kt) af[mi*2+kt] = ldfrag(mi, kt);

    // sigma head: h @ [w_op | 0...]  (col 16 of head region = w_op)
    {
        half8 b0 = ldbfrag(whead, 1, 0);
        half8 b1 = ldbfrag(whead, 1, 1);
        floatx4 accS[4];
#pragma unroll
        for (int mi = 0; mi < 4; ++mi) {
            accS[mi] = (floatx4){0.f,0.f,0.f,0.f};
            accS[mi] = __builtin_amdgcn_mfma_f32_16x16x32_f16(af[mi*2+0], b0, accS[mi], 0, 0, 0);
            accS[mi] = __builtin_amdgcn_mfma_f32_16x16x32_f16(af[mi*2+1], b1, accS[mi], 0, 0, 0);
        }
        if ((lane & 15) == 0) {
            const float bop = b_op[0];
#pragma unroll
            for (int mi = 0; mi < 4; ++mi)
#pragma unroll
                for (int r = 0; r < 4; ++r) {
                    int m = mi*16 + (lane>>4)*4 + r;
                    sd_lds[wv][m] = sp(accS[mi][r] + bop) * delta;
                }
        }
    }

    // color head part 2: accH += h @ Wc
    {
        half8 b0 = ldbfrag(whead, 0, 0);
        half8 b1 = ldbfrag(whead, 0, 1);
#pragma unroll
        for (int mi = 0; mi < 4; ++mi) {
            accH[mi] = __builtin_amdgcn_mfma_f32_16x16x32_f16(af[mi*2+0], b0, accH[mi], 0, 0, 0);
            accH[mi] = __builtin_amdgcn_mfma_f32_16x16x32_f16(af[mi*2+1], b1, accH[mi], 0, 0, 0);
        }
    }

    // ---- composite: lane = sample ----
    const float sdv = sd_lds[wv][lane];
    float csd = sdv;
#pragma unroll
    for (int off = 1; off < 64; off <<= 1) {
        float nn = __shfl_up(csd, off, 64);
        if (lane >= off) csd += nn;
    }
    const float nlt = __shfl(csd, 63, 64);
    const float Tw  = __expf(sdv - csd) * (1.f - __expf(-sdv));
    const float em  = __expf(-nlt);
    w_lds[wv][lane] = Tw;

    float rl = Tw * t;
#pragma unroll
    for (int off = 32; off > 0; off >>= 1) rl += __shfl_xor(rl, off, 64);

    // feat[k] = sum_m w_m * (color[m][k] + b_col[k]);  k = lane&15
    const float bcn = b_col[lane & 15];
    float pf = 0.f;
#pragma unroll
    for (int mi = 0; mi < 4; ++mi)
#pragma unroll
        for (int r = 0; r < 4; ++r) {
            int m = mi*16 + (lane>>4)*4 + r;
            pf += w_lds[wv][m] * (accH[mi][r] + bcn);
        }
    pf += __shfl_xor(pf, 16, 64);
    pf += __shfl_xor(pf, 32, 64);

    if (lane < 16)
        out[(size_t)rid*16 + lane] = pf + em * bgc[lane];
    if (lane == 0) {
        out[(size_t)NRAYS*16 + rid] = 1.f - em;   // mask
        out[(size_t)NRAYS*17 + rid] = rl;         // ray_len
    }
}

extern "C" void kernel_launch(void* const* d_in, const int* in_sizes, int n_in,
                              void* d_out, int out_size, void* d_ws, size_t ws_size,
                              hipStream_t stream)
{
    const float* rays    = (const float*)d_in[0];
    const float* centers = (const float*)d_in[1];
    const float* enc     = (const float*)d_in[2];
    const float* nearp   = (const float*)d_in[3];
    const float* farp    = (const float*)d_in[4];
    const float* xy      = (const float*)d_in[5];
    const float* yz      = (const float*)d_in[6];
    const float* zx      = (const float*)d_in[7];
    const float* xyc     = (const float*)d_in[8];
    const float* yzc     = (const float*)d_in[9];
    const float* zxc     = (const float*)d_in[10];
    const float* mlp_w   = (const float*)d_in[11];
    const float* mlp_b   = (const float*)d_in[12];
    const float* w_op    = (const float*)d_in[13];
    const float* b_op    = (const float*)d_in[14];
    const float* w_col   = (const float*)d_in[15];
    const float* b_col   = (const float*)d_in[16];
    const float* bg      = (const float*)d_in[17];
    float* out = (float*)d_out;

    char* ws = (char*)d_ws;
    ushort_t* trp  = (ushort_t*)ws;
    ushort_t* wq   = (ushort_t*)(ws + WS_WQ_OFF);
    uint_t*   keys = (uint_t*)(ws + WS_KEYS_OFF);
    uint_t*   perm = (uint_t*)(ws + WS_PERM_OFF);
    uint_t*   hist = (uint_t*)(ws + WS_HIST_OFF);
    uint_t*   offs = (uint_t*)(ws + WS_OFFS_OFF);

    tr_planes<<<6*2*HW_, 256, 0, stream>>>(xy, yz, zx, xyc, yzc, zxc, trp);
    prep_weights<<<(NW_US + 255)/256, 256, 0, stream>>>(mlp_w, w_op, w_col, wq);

    hipMemsetAsync(hist, 0, NBINS*sizeof(uint_t), stream);
    ray_keys<<<NRAYS/256, 256, 0, stream>>>(rays, centers, nearp, farp, keys, hist);
    scan_hist<<<1, NBINS, 0, stream>>>(hist, offs);
    scatter_perm<<<NRAYS/256, 256, 0, stream>>>(keys, offs, perm);

    render<<<NWG, WV*64, 0, stream>>>(
        rays, centers, enc, nearp, farp, mlp_b, b_op, b_col, bg, trp, wq, perm, out);
}

// Round 13
// 383.680 us; speedup vs baseline: 4.0156x; 1.4583x over previous
//
#include <hip/hip_runtime.h>
#include <hip/hip_bf16.h>

typedef unsigned short ushort_t;
typedef unsigned int   uint_t;
typedef __attribute__((ext_vector_type(8))) _Float16 half8;   // MFMA f16 A/B frag
typedef __attribute__((ext_vector_type(2))) _Float16 half2v;  // packed f16 pair
typedef __attribute__((ext_vector_type(4))) float    floatx4; // MFMA acc

#define B_    2
#define R_    8192
#define HW_   256
#define S_    64
#define NRAYS (B_*R_)
#define PLANE_ELEMS ((size_t)64*HW_*HW_)
#define TRP_ELEMS   ((size_t)HW_*HW_*64)
#define WS_PLANES_BYTES (6ull*B_*TRP_ELEMS*2)   /* 100,663,296 */
#define NW_US 10240    /* weight f16s: 8192 mlp + 2048 head */
#define WV 4           /* waves (rays) per block */
#define NWG (NRAYS/WV) /* 4096 render blocks */
#define NBINS 1024

#define WS_WQ_OFF   WS_PLANES_BYTES
#define WS_KEYS_OFF (WS_WQ_OFF + NW_US*2)
#define WS_PERM_OFF (WS_KEYS_OFF + NRAYS*4)
#define WS_HIST_OFF (WS_PERM_OFF + NRAYS*4)
#define WS_OFFS_OFF (WS_HIST_OFF + NBINS*4)

__device__ __forceinline__ float sp(float x){ return fmaxf(x, 0.f) + __logf(1.f + __expf(-fabsf(x))); }
__device__ __forceinline__ ushort_t f2h(float f){
    union{_Float16 h; ushort_t u;} v; v.h = (_Float16)f; return v.u;
}

// ---------------- Kernel A: transpose planes [C,H,W]f32 -> [H,W,C]f16 ----------------
__global__ __launch_bounds__(256) void tr_planes(
    const float* __restrict__ p0, const float* __restrict__ p1, const float* __restrict__ p2,
    const float* __restrict__ p3, const float* __restrict__ p4, const float* __restrict__ p5,
    ushort_t* __restrict__ outp)
{
    const int blk = blockIdx.x;
    const int y = blk & 255, b = (blk >> 8) & 1, p = blk >> 9;
    const float* src = (p==0)?p0:(p==1)?p1:(p==2)?p2:(p==3)?p3:(p==4)?p4:p5;
    src += (size_t)b*PLANE_ELEMS + (size_t)y*HW_ + threadIdx.x;
    ushort_t* dst = outp + (size_t)(p*2+b)*TRP_ELEMS + ((size_t)y*HW_ + threadIdx.x)*64;

    __attribute__((aligned(16))) ushort_t tmp[64];
#pragma unroll
    for (int c = 0; c < 64; ++c)
        tmp[c] = f2h(src[(size_t)c*HW_*HW_]);
#pragma unroll
    for (int k = 0; k < 8; ++k)
        reinterpret_cast<uint4*>(dst)[k] = reinterpret_cast<const uint4*>(tmp)[k];
}

// ---------------- Kernel A2: weights -> f16, transposed for B-fragments ----------------
__global__ __launch_bounds__(256) void prep_weights(
    const float* __restrict__ mlp_w, const float* __restrict__ w_op,
    const float* __restrict__ w_col, ushort_t* __restrict__ dst)
{
    int i = blockIdx.x*256 + threadIdx.x;
    if (i >= NW_US) return;
    float v;
    if (i < 8192) {
        int l = i >> 12, o = (i >> 6) & 63, c = i & 63;
        v = mlp_w[l*4096 + c*64 + o];
    } else {
        int j = i - 8192, n = j >> 6, c = j & 63;
        v = (n < 16) ? w_col[c*16 + n] : (n == 16 ? w_op[c] : 0.f);
    }
    dst[i] = f2h(v);
}

// ---------------- Sort kernels: spatial counting sort of rays (R8) ----------------
__global__ __launch_bounds__(256) void ray_keys(
    const float* __restrict__ rays, const float* __restrict__ centers,
    const float* __restrict__ nearp, const float* __restrict__ farp,
    uint_t* __restrict__ keys, uint_t* __restrict__ hist)
{
    int rid = blockIdx.x*256 + threadIdx.x;
    if (rid >= NRAYS) return;
    const float t = 0.5f*(nearp[rid] + farp[rid]);
    float c[3];
#pragma unroll
    for (int a = 0; a < 3; ++a) {
        float p = centers[rid*3+a] + t*rays[rid*3+a];
        p = fminf(fmaxf(p, -1.f), 1.f);
        int ci = (int)((p + 1.f)*4.f);
        c[a] = (float)(ci > 7 ? 7 : ci);
    }
    uint_t key = (uint_t)(rid >> 13)*512 + (uint_t)c[2]*64 + (uint_t)c[1]*8 + (uint_t)c[0];
    keys[rid] = key;
    atomicAdd(&hist[key], 1u);
}

__global__ __launch_bounds__(NBINS) void scan_hist(
    const uint_t* __restrict__ hist, uint_t* __restrict__ offs)
{
    __shared__ uint_t tmp[NBINS];
    const int tid = threadIdx.x;
    const uint_t own = hist[tid];
    tmp[tid] = own;
    __syncthreads();
#pragma unroll
    for (int off = 1; off < NBINS; off <<= 1) {
        uint_t v = (tid >= off) ? tmp[tid - off] : 0u;
        __syncthreads();
        tmp[tid] += v;
        __syncthreads();
    }
    offs[tid] = tmp[tid] - own;    // exclusive
}

__global__ __launch_bounds__(256) void scatter_perm(
    const uint_t* __restrict__ keys, uint_t* __restrict__ offs, uint_t* __restrict__ perm)
{
    int rid = blockIdx.x*256 + threadIdx.x;
    if (rid >= NRAYS) return;
    uint_t pos = atomicAdd(&offs[keys[rid]], 1u);
    perm[pos] = (uint_t)rid;
}

// ---------------- Kernel B: render (1 wave = 1 ray; MFMA f16 MLP) ----------------
// R12: COOPERATIVE gather addressing. Old scheme: lane=sample owned a whole
// 128B line, read 16B at a time -> each load instr touched 64 distinct lines
// (8 tag-lookups per line). New: lane = sg*8+ch; 8 consecutive lanes read the
// 8 chunks of ONE line (sample j*8+sg). 8x fewer L1 line-transactions; each
// line fetched exactly once. pos/wx/wy reach lanes via __shfl. Phase split
// (one 32-reg acc live at a time, R11) kept for the <=128-VGPR step.
__global__ __launch_bounds__(256) void render(
    const float* __restrict__ rays, const float* __restrict__ centers,
    const float* __restrict__ enc,  const float* __restrict__ nearp, const float* __restrict__ farp,
    const float* __restrict__ mlp_b, const float* __restrict__ b_op,
    const float* __restrict__ b_col, const float* __restrict__ bgc,
    const ushort_t* __restrict__ trp, const ushort_t* __restrict__ wq,
    const uint_t* __restrict__ perm, float* __restrict__ out)
{
    __shared__ ushort_t A_lds[WV][4096];     // 64 rows x 128B (64 f16), XOR-swizzled 16B slots
    __shared__ float    sd_lds[WV][64];
    __shared__ float    w_lds [WV][64];

    const int wv = threadIdx.x >> 6, lane = threadIdx.x & 63;
    const int sg = lane >> 3, ch = lane & 7;       // cooperative gather coords
    const int sb  = (blockIdx.x & 7)*(NWG/8) + (blockIdx.x >> 3);  // XCD-chunk swizzle
    const int rid = (int)perm[sb*WV + wv];
    const int b = rid >> 13;
    ushort_t* A = &A_lds[wv][0];

    const float nr = nearp[rid], fr = farp[rid];
    const float rdx = rays[rid*3+0], rdy = rays[rid*3+1], rdz = rays[rid*3+2];
    const float rox = centers[rid*3+0], roy = centers[rid*3+1], roz = centers[rid*3+2];
    const float delta = (fr - nr) * (1.f/S_);
    const float t  = nr + (fr - nr) * ((lane + 0.5f) * (1.f/S_));
    const float px = rox + t*rdx, py = roy + t*rdy, pz = roz + t*rdz;

    // bilinear prep (lane = sample here); keep pos + fractional parts for shfl
    int pos[3]; float wxp[3], wyp[3];
    {
        float us[3] = {px, py, pz};
        float vs[3] = {py, pz, px};
#pragma unroll
        for (int p = 0; p < 3; ++p) {
            float x = (fminf(fmaxf(us[p],-1.f),1.f) + 1.f) * 127.5f;
            float y = (fminf(fmaxf(vs[p],-1.f),1.f) + 1.f) * 127.5f;
            int x0 = (int)floorf(x); x0 = x0 < 0 ? 0 : (x0 > 254 ? 254 : x0);
            int y0 = (int)floorf(y); y0 = y0 < 0 ? 0 : (y0 > 254 ? 254 : y0);
            pos[p] = y0*HW_ + x0;
            wxp[p] = x - (float)x0;
            wyp[p] = y - (float)y0;
        }
    }

    // cooperative gather: for sample s=j*8+sg this lane accumulates channels
    // ch*8..ch*8+7 (acc[j][0..3] half2). Each 8-lane group loads full lines.
    auto gatherC = [&](int pbase, half2v (&acc)[8][4]) {
#pragma unroll
        for (int p = 0; p < 3; ++p) {
            const ushort_t* plane = trp + (size_t)((pbase+p)*2 + b)*TRP_ELEMS;
#pragma unroll
            for (int j = 0; j < 8; ++j) {
                const int s  = j*8 + sg;
                const int pp = __shfl(pos[p], s, 64);
                const float fx = __shfl(wxp[p], s, 64);
                const float fy = __shfl(wyp[p], s, 64);
                const ushort_t* lb = plane + (size_t)pp*64 + ch*8;
                union { uint4 v; half2v h[4]; } q00, q01, q10, q11;
                q00.v = *reinterpret_cast<const uint4*>(lb);
                q01.v = *reinterpret_cast<const uint4*>(lb + 64);
                q10.v = *reinterpret_cast<const uint4*>(lb + 64*HW_);
                q11.v = *reinterpret_cast<const uint4*>(lb + 64*HW_ + 64);
                const _Float16 h00 = (_Float16)((1.f-fx)*(1.f-fy));
                const _Float16 h01 = (_Float16)(fx*(1.f-fy));
                const _Float16 h10 = (_Float16)((1.f-fx)*fy);
                const _Float16 h11 = (_Float16)(fx*fy);
                const half2v w00 = half2v{h00,h00}, w01 = half2v{h01,h01};
                const half2v w10 = half2v{h10,h10}, w11 = half2v{h11,h11};
#pragma unroll
                for (int k = 0; k < 4; ++k)
                    acc[j][k] += w00*q00.h[k] + w01*q01.h[k]
                               + w10*q10.h[k] + w11*q11.h[k];
            }
        }
    };
    // cooperative write: lane writes chunk ch of rows j*8+sg; swizzle matches
    // ldfrag (byte ^ (row&7)<<4, row&7 == sg). Bijective, conflict-clean.
    auto writeAc = [&](const half2v (&acc)[8][4]) {
#pragma unroll
        for (int j = 0; j < 8; ++j) {
            union { half2v h[4]; uint4 v; } pk;
#pragma unroll
            for (int k = 0; k < 4; ++k) pk.h[k] = acc[j][k];
            const int s = j*8 + sg;
            *reinterpret_cast<uint4*>(reinterpret_cast<char*>(A) + s*128 + ((ch*16) ^ (sg<<4)))
                = pk.v;
        }
    };

    // A-fragment load: lane holds row (lane&15) of tile mi, k = kt*32 + (lane>>4)*8 + j
    auto ldfrag = [&](int mi, int kt) -> half8 {
        int m  = mi*16 + (lane&15);
        int cb = (kt*64 + ((lane>>4)*16)) ^ ((m&7)<<4);
        return *reinterpret_cast<const half8*>(reinterpret_cast<const char*>(A) + m*128 + cb);
    };
    auto ldbfrag = [&](const ushort_t* wrow, int nt, int kt) -> half8 {
        return *reinterpret_cast<const half8*>(wrow + (nt*16 + (lane&15))*64 + kt*32 + (lane>>4)*8);
    };
    auto stH = [&](int m, int n, float v) {
        A[(m*128 + ((n*2) ^ ((m&7)<<4))) >> 1] = f2h(v);
    };

    // one MLP layer; af[8] preload is a CORRECTNESS requirement (R3 lesson).
    auto mlp_layer = [&](const ushort_t* wrow, const float* bias) {
        half8 af[8];
#pragma unroll
        for (int mi = 0; mi < 4; ++mi)
#pragma unroll
            for (int kt = 0; kt < 2; ++kt) af[mi*2+kt] = ldfrag(mi, kt);
#pragma unroll
        for (int nt = 0; nt < 4; ++nt) {
            half8 b0 = ldbfrag(wrow, nt, 0);
            half8 b1 = ldbfrag(wrow, nt, 1);
            floatx4 acc[4];
#pragma unroll
            for (int mi = 0; mi < 4; ++mi) {
                acc[mi] = (floatx4){0.f,0.f,0.f,0.f};
                acc[mi] = __builtin_amdgcn_mfma_f32_16x16x32_f16(af[mi*2+0], b0, acc[mi], 0, 0, 0);
                acc[mi] = __builtin_amdgcn_mfma_f32_16x16x32_f16(af[mi*2+1], b1, acc[mi], 0, 0, 0);
            }
            const int n = nt*16 + (lane&15);
            const float bc = bias[n];
#pragma unroll
            for (int mi = 0; mi < 4; ++mi)
#pragma unroll
                for (int r = 0; r < 4; ++r) {
                    int m = mi*16 + (lane>>4)*4 + r;
                    stH(m, n, sp(acc[mi][r] + bc));
                }
        }
    };

    const ushort_t* whead = wq + 8192;
    floatx4 accH[4];
#pragma unroll
    for (int mi = 0; mi < 4; ++mi) accH[mi] = (floatx4){0.f,0.f,0.f,0.f};

    // ---- phase 1: color gather -> A -> early GEMM (fc+enc)@Wc ----
    {
        half2v accC[8][4];
        // enc is per-ray (sample-independent): this lane's chunk = enc[ch*8..+8]
        const float* er = enc + (size_t)rid*64 + ch*8;
        float4 e0 = *reinterpret_cast<const float4*>(er);
        float4 e1 = *reinterpret_cast<const float4*>(er + 4);
        const half2v i0 = half2v{(_Float16)e0.x, (_Float16)e0.y};
        const half2v i1 = half2v{(_Float16)e0.z, (_Float16)e0.w};
        const half2v i2 = half2v{(_Float16)e1.x, (_Float16)e1.y};
        const half2v i3 = half2v{(_Float16)e1.z, (_Float16)e1.w};
#pragma unroll
        for (int j = 0; j < 8; ++j) {
            accC[j][0] = i0; accC[j][1] = i1; accC[j][2] = i2; accC[j][3] = i3;
        }
        gatherC(3, accC);
        writeAc(accC);                   // accC dies here
        half8 b0 = ldbfrag(whead, 0, 0);
        half8 b1 = ldbfrag(whead, 0, 1);
#pragma unroll
        for (int mi = 0; mi < 4; ++mi) {
            accH[mi] = __builtin_amdgcn_mfma_f32_16x16x32_f16(ldfrag(mi,0), b0, accH[mi], 0, 0, 0);
            accH[mi] = __builtin_amdgcn_mfma_f32_16x16x32_f16(ldfrag(mi,1), b1, accH[mi], 0, 0, 0);
        }
    }

    // ---- phase 2: density gather -> A ----
    {
        half2v accD[8][4];
#pragma unroll
        for (int j = 0; j < 8; ++j)
#pragma unroll
            for (int k = 0; k < 4; ++k) accD[j][k] = half2v{(_Float16)0.f, (_Float16)0.f};
        gatherC(0, accD);
        // DS ops are in-order per wave and alias on A: phase-1 frag reads
        // complete before this overwrite.
        writeAc(accD);                   // accD dies here
    }

    // ---- MLP (only accH: 16 f32 regs live across) ----
    mlp_layer(wq,        mlp_b);         // layer 1
    mlp_layer(wq + 4096, mlp_b + 64);    // layer 2  (A now holds h)

    // preload h fragments ONCE for both heads (heads only read A)
    half8 af[8];
#pragma unroll
    for (int mi = 0; mi < 4; ++mi)
#pragma unroll
        for (int kt = 0; kt < 2; ++kt) af[mi*2+kt] = ldfrag(mi, kt);

    // sigma head: h @ [w_op | 0...]  (col 16 of head region = w_op)
    {
        half8 b0 = ldbfrag(whead, 1, 0);
        half8 b1 = ldbfrag(whead, 1, 1);
        floatx4 accS[4];
#pragma unroll
        for (int mi = 0; mi < 4; ++mi) {
            accS[mi] = (floatx4){0.f,0.f,0.f,0.f};
            accS[mi] = __builtin_amdgcn_mfma_f32_16x16x32_f16(af[mi*2+0], b0, accS[mi], 0, 0, 0);
            accS[mi] = __builtin_amdgcn_mfma_f32_16x16x32_f16(af[mi*2+1], b1, accS[mi], 0, 0, 0);
        }
        if ((lane & 15) == 0) {
            const float bop = b_op[0];
#pragma unroll
            for (int mi = 0; mi < 4; ++mi)
#pragma unroll
                for (int r = 0; r < 4; ++r) {
                    int m = mi*16 + (lane>>4)*4 + r;
                    sd_lds[wv][m] = sp(accS[mi][r] + bop) * delta;
                }
        }
    }

    // color head part 2: accH += h @ Wc
    {
        half8 b0 = ldbfrag(whead, 0, 0);
        half8 b1 = ldbfrag(whead, 0, 1);
#pragma unroll
        for (int mi = 0; mi < 4; ++mi) {
            accH[mi] = __builtin_amdgcn_mfma_f32_16x16x32_f16(af[mi*2+0], b0, accH[mi], 0, 0, 0);
            accH[mi] = __builtin_amdgcn_mfma_f32_16x16x32_f16(af[mi*2+1], b1, accH[mi], 0, 0, 0);
        }
    }

    // ---- composite: lane = sample ----
    const float sdv = sd_lds[wv][lane];
    float csd = sdv;
#pragma unroll
    for (int off = 1; off < 64; off <<= 1) {
        float nn = __shfl_up(csd, off, 64);
        if (lane >= off) csd += nn;
    }
    const float nlt = __shfl(csd, 63, 64);
    const float Tw  = __expf(sdv - csd) * (1.f - __expf(-sdv));
    const float em  = __expf(-nlt);
    w_lds[wv][lane] = Tw;

    float rl = Tw * t;
#pragma unroll
    for (int off = 32; off > 0; off >>= 1) rl += __shfl_xor(rl, off, 64);

    // feat[k] = sum_m w_m * (color[m][k] + b_col[k]);  k = lane&15
    const float bcn = b_col[lane & 15];
    float pf = 0.f;
#pragma unroll
    for (int mi = 0; mi < 4; ++mi)
#pragma unroll
        for (int r = 0; r < 4; ++r) {
            int m = mi*16 + (lane>>4)*4 + r;
            pf += w_lds[wv][m] * (accH[mi][r] + bcn);
        }
    pf += __shfl_xor(pf, 16, 64);
    pf += __shfl_xor(pf, 32, 64);

    if (lane < 16)
        out[(size_t)rid*16 + lane] = pf + em * bgc[lane];
    if (lane == 0) {
        out[(size_t)NRAYS*16 + rid] = 1.f - em;   // mask
        out[(size_t)NRAYS*17 + rid] = rl;         // ray_len
    }
}

extern "C" void kernel_launch(void* const* d_in, const int* in_sizes, int n_in,
                              void* d_out, int out_size, void* d_ws, size_t ws_size,
                              hipStream_t stream)
{
    const float* rays    = (const float*)d_in[0];
    const float* centers = (const float*)d_in[1];
    const float* enc     = (const float*)d_in[2];
    const float* nearp   = (const float*)d_in[3];
    const float* farp    = (const float*)d_in[4];
    const float* xy      = (const float*)d_in[5];
    const float* yz      = (const float*)d_in[6];
    const float* zx      = (const float*)d_in[7];
    const float* xyc     = (const float*)d_in[8];
    const float* yzc     = (const float*)d_in[9];
    const float* zxc     = (const float*)d_in[10];
    const float* mlp_w   = (const float*)d_in[11];
    const float* mlp_b   = (const float*)d_in[12];
    const float* w_op    = (const float*)d_in[13];
    const float* b_op    = (const float*)d_in[14];
    const float* w_col   = (const float*)d_in[15];
    const float* b_col   = (const float*)d_in[16];
    const float* bg      = (const float*)d_in[17];
    float* out = (float*)d_out;

    char* ws = (char*)d_ws;
    ushort_t* trp  = (ushort_t*)ws;
    ushort_t* wq   = (ushort_t*)(ws + WS_WQ_OFF);
    uint_t*   keys = (uint_t*)(ws + WS_KEYS_OFF);
    uint_t*   perm = (uint_t*)(ws + WS_PERM_OFF);
    uint_t*   hist = (uint_t*)(ws + WS_HIST_OFF);
    uint_t*   offs = (uint_t*)(ws + WS_OFFS_OFF);

    tr_planes<<<6*2*HW_, 256, 0, stream>>>(xy, yz, zx, xyc, yzc, zxc, trp);
    prep_weights<<<(NW_US + 255)/256, 256, 0, stream>>>(mlp_w, w_op, w_col, wq);

    hipMemsetAsync(hist, 0, NBINS*sizeof(uint_t), stream);
    ray_keys<<<NRAYS/256, 256, 0, stream>>>(rays, centers, nearp, farp, keys, hist);
    scan_hist<<<1, NBINS, 0, stream>>>(hist, offs);
    scatter_perm<<<NRAYS/256, 256, 0, stream>>>(keys, offs, perm);

    render<<<NWG, WV*64, 0, stream>>>(
        rays, centers, enc, nearp, farp, mlp_b, b_op, b_col, bg, trp, wq, perm, out);
}

// Round 14
// 316.248 us; speedup vs baseline: 4.8719x; 1.2132x over previous
//
#include <hip/hip_runtime.h>
#include <hip/hip_bf16.h>

typedef unsigned short ushort_t;
typedef unsigned int   uint_t;
typedef __attribute__((ext_vector_type(8))) _Float16 half8;   // MFMA f16 A/B frag
typedef __attribute__((ext_vector_type(2))) _Float16 half2v;  // packed f16 pair
typedef __attribute__((ext_vector_type(4))) float    floatx4; // MFMA acc

#define B_    2
#define R_    8192
#define HW_   256
#define S_    64
#define NRAYS (B_*R_)
#define PLANE_ELEMS ((size_t)64*HW_*HW_)
#define NTEX  ((size_t)HW_*HW_)
/* interleaved record: [pair(3)][batch(2)][texel 65536][128ch: D64|C64] f16 */
#define WS_PLANES_BYTES (6ull*B_*NTEX*64*2)     /* 100,663,296 (same total) */
#define NW_US 10240    /* weight f16s: 8192 mlp + 2048 head */
#define WV 4           /* waves (rays) per block */
#define NWG (NRAYS/WV) /* 4096 render blocks */
#define NBINS 1024

#define WS_WQ_OFF   WS_PLANES_BYTES
#define WS_KEYS_OFF (WS_WQ_OFF + NW_US*2)
#define WS_PERM_OFF (WS_KEYS_OFF + NRAYS*4)
#define WS_HIST_OFF (WS_PERM_OFF + NRAYS*4)
#define WS_OFFS_OFF (WS_HIST_OFF + NBINS*4)

__device__ __forceinline__ float sp(float x){ return fmaxf(x, 0.f) + __logf(1.f + __expf(-fabsf(x))); }
__device__ __forceinline__ ushort_t f2h(float f){
    union{_Float16 h; ushort_t u;} v; v.h = (_Float16)f; return v.u;
}

// ---------------- Kernel A: transpose planes [C,H,W]f32 -> interleaved [texel][D|C]f16 ----
// R13: density plane p and color plane p+3 land in the SAME 256B texel record
// (D at +0, C at +64 f16s) so the render gather shares one address stream.
__global__ __launch_bounds__(256) void tr_planes(
    const float* __restrict__ p0, const float* __restrict__ p1, const float* __restrict__ p2,
    const float* __restrict__ p3, const float* __restrict__ p4, const float* __restrict__ p5,
    ushort_t* __restrict__ outp)
{
    const int blk = blockIdx.x;
    const int y = blk & 255, b = (blk >> 8) & 1, p = blk >> 9;
    const int pidx = (p < 3) ? p : p - 3;
    const int half = (p < 3) ? 0 : 1;
    const float* src = (p==0)?p0:(p==1)?p1:(p==2)?p2:(p==3)?p3:(p==4)?p4:p5;
    src += (size_t)b*PLANE_ELEMS + (size_t)y*HW_ + threadIdx.x;
    ushort_t* dst = outp + ((size_t)(pidx*2+b)*NTEX + (size_t)y*HW_ + threadIdx.x)*128 + half*64;

    __attribute__((aligned(16))) ushort_t tmp[64];
#pragma unroll
    for (int c = 0; c < 64; ++c)
        tmp[c] = f2h(src[(size_t)c*HW_*HW_]);
#pragma unroll
    for (int k = 0; k < 8; ++k)
        reinterpret_cast<uint4*>(dst)[k] = reinterpret_cast<const uint4*>(tmp)[k];
}

// ---------------- Kernel A2: weights -> f16, transposed for B-fragments ----------------
__global__ __launch_bounds__(256) void prep_weights(
    const float* __restrict__ mlp_w, const float* __restrict__ w_op,
    const float* __restrict__ w_col, ushort_t* __restrict__ dst)
{
    int i = blockIdx.x*256 + threadIdx.x;
    if (i >= NW_US) return;
    float v;
    if (i < 8192) {
        int l = i >> 12, o = (i >> 6) & 63, c = i & 63;
        v = mlp_w[l*4096 + c*64 + o];
    } else {
        int j = i - 8192, n = j >> 6, c = j & 63;
        v = (n < 16) ? w_col[c*16 + n] : (n == 16 ? w_op[c] : 0.f);
    }
    dst[i] = f2h(v);
}

// ---------------- Sort kernels: spatial counting sort of rays (R8) ----------------
__global__ __launch_bounds__(256) void ray_keys(
    const float* __restrict__ rays, const float* __restrict__ centers,
    const float* __restrict__ nearp, const float* __restrict__ farp,
    uint_t* __restrict__ keys, uint_t* __restrict__ hist)
{
    int rid = blockIdx.x*256 + threadIdx.x;
    if (rid >= NRAYS) return;
    const float t = 0.5f*(nearp[rid] + farp[rid]);
    float c[3];
#pragma unroll
    for (int a = 0; a < 3; ++a) {
        float p = centers[rid*3+a] + t*rays[rid*3+a];
        p = fminf(fmaxf(p, -1.f), 1.f);
        int ci = (int)((p + 1.f)*4.f);
        c[a] = (float)(ci > 7 ? 7 : ci);
    }
    uint_t key = (uint_t)(rid >> 13)*512 + (uint_t)c[2]*64 + (uint_t)c[1]*8 + (uint_t)c[0];
    keys[rid] = key;
    atomicAdd(&hist[key], 1u);
}

__global__ __launch_bounds__(NBINS) void scan_hist(
    const uint_t* __restrict__ hist, uint_t* __restrict__ offs)
{
    __shared__ uint_t tmp[NBINS];
    const int tid = threadIdx.x;
    const uint_t own = hist[tid];
    tmp[tid] = own;
    __syncthreads();
#pragma unroll
    for (int off = 1; off < NBINS; off <<= 1) {
        uint_t v = (tid >= off) ? tmp[tid - off] : 0u;
        __syncthreads();
        tmp[tid] += v;
        __syncthreads();
    }
    offs[tid] = tmp[tid] - own;    // exclusive
}

__global__ __launch_bounds__(256) void scatter_perm(
    const uint_t* __restrict__ keys, uint_t* __restrict__ offs, uint_t* __restrict__ perm)
{
    int rid = blockIdx.x*256 + threadIdx.x;
    if (rid >= NRAYS) return;
    uint_t pos = atomicAdd(&offs[keys[rid]], 1u);
    perm[pos] = (uint_t)rid;
}

// ---------------- Kernel B: render (1 wave = 1 ray; MFMA f16 MLP) ----------------
// R13: ONE merged gather pass over interleaved [D|C] records. Per (j,plane):
// one shfl'd address serves 8 cooperative loads (4 D-chunks + 4 C-chunks).
// accC is 4 regs (written to A per-j); accD[8][4] (32 regs) held across the
// loop. Early (fc+enc)@Wc GEMM, then writeA(D) (in-order DS), then MLP.
// Cooperative lane map (R12): lane = sg*8+ch; 8 lanes share one line.
__global__ __launch_bounds__(256) void render(
    const float* __restrict__ rays, const float* __restrict__ centers,
    const float* __restrict__ enc,  const float* __restrict__ nearp, const float* __restrict__ farp,
    const float* __restrict__ mlp_b, const float* __restrict__ b_op,
    const float* __restrict__ b_col, const float* __restrict__ bgc,
    const ushort_t* __restrict__ trp, const ushort_t* __restrict__ wq,
    const uint_t* __restrict__ perm, float* __restrict__ out)
{
    __shared__ ushort_t A_lds[WV][4096];     // 64 rows x 128B (64 f16), XOR-swizzled 16B slots
    __shared__ float    sd_lds[WV][64];
    __shared__ float    w_lds [WV][64];

    const int wv = threadIdx.x >> 6, lane = threadIdx.x & 63;
    const int sg = lane >> 3, ch = lane & 7;       // cooperative gather coords
    const int sb  = (blockIdx.x & 7)*(NWG/8) + (blockIdx.x >> 3);  // XCD-chunk swizzle
    const int rid = (int)perm[sb*WV + wv];
    const int b = rid >> 13;
    ushort_t* A = &A_lds[wv][0];

    const float nr = nearp[rid], fr = farp[rid];
    const float rdx = rays[rid*3+0], rdy = rays[rid*3+1], rdz = rays[rid*3+2];
    const float rox = centers[rid*3+0], roy = centers[rid*3+1], roz = centers[rid*3+2];
    const float delta = (fr - nr) * (1.f/S_);
    const float t  = nr + (fr - nr) * ((lane + 0.5f) * (1.f/S_));
    const float px = rox + t*rdx, py = roy + t*rdy, pz = roz + t*rdz;

    // bilinear prep (lane = sample here); pos + fractional parts for shfl
    int pos[3]; float wxp[3], wyp[3];
    {
        float us[3] = {px, py, pz};
        float vs[3] = {py, pz, px};
#pragma unroll
        for (int p = 0; p < 3; ++p) {
            float x = (fminf(fmaxf(us[p],-1.f),1.f) + 1.f) * 127.5f;
            float y = (fminf(fmaxf(vs[p],-1.f),1.f) + 1.f) * 127.5f;
            int x0 = (int)floorf(x); x0 = x0 < 0 ? 0 : (x0 > 254 ? 254 : x0);
            int y0 = (int)floorf(y); y0 = y0 < 0 ? 0 : (y0 > 254 ? 254 : y0);
            pos[p] = y0*HW_ + x0;
            wxp[p] = x - (float)x0;
            wyp[p] = y - (float)y0;
        }
    }

    // A-fragment load: lane holds row (lane&15) of tile mi, k = kt*32 + (lane>>4)*8 + j
    auto ldfrag = [&](int mi, int kt) -> half8 {
        int m  = mi*16 + (lane&15);
        int cb = (kt*64 + ((lane>>4)*16)) ^ ((m&7)<<4);
        return *reinterpret_cast<const half8*>(reinterpret_cast<const char*>(A) + m*128 + cb);
    };
    auto ldbfrag = [&](const ushort_t* wrow, int nt, int kt) -> half8 {
        return *reinterpret_cast<const half8*>(wrow + (nt*16 + (lane&15))*64 + kt*32 + (lane>>4)*8);
    };
    auto stH = [&](int m, int n, float v) {
        A[(m*128 + ((n*2) ^ ((m&7)<<4))) >> 1] = f2h(v);
    };

    // one MLP layer; af[8] preload is a CORRECTNESS requirement (R3 lesson).
    auto mlp_layer = [&](const ushort_t* wrow, const float* bias) {
        half8 af[8];
#pragma unroll
        for (int mi = 0; mi < 4; ++mi)
#pragma unroll
            for (int kt = 0; kt < 2; ++kt) af[mi*2+kt] = ldfrag(mi, kt);
#pragma unroll
        for (int nt = 0; nt < 4; ++nt) {
            half8 b0 = ldbfrag(wrow, nt, 0);
            half8 b1 = ldbfrag(wrow, nt, 1);
            floatx4 acc[4];
#pragma unroll
            for (int mi = 0; mi < 4; ++mi) {
                acc[mi] = (floatx4){0.f,0.f,0.f,0.f};
                acc[mi] = __builtin_amdgcn_mfma_f32_16x16x32_f16(af[mi*2+0], b0, acc[mi], 0, 0, 0);
                acc[mi] = __builtin_amdgcn_mfma_f32_16x16x32_f16(af[mi*2+1], b1, acc[mi], 0, 0, 0);
            }
            const int n = nt*16 + (lane&15);
            const float bc = bias[n];
#pragma unroll
            for (int mi = 0; mi < 4; ++mi)
#pragma unroll
                for (int r = 0; r < 4; ++r) {
                    int m = mi*16 + (lane>>4)*4 + r;
                    stH(m, n, sp(acc[mi][r] + bc));
                }
        }
    };

    const ushort_t* whead = wq + 8192;

    // ---- merged gather: D accumulates in regs, C streams through A per-j ----
    half2v accD[8][4];
#pragma unroll
    for (int j = 0; j < 8; ++j)
#pragma unroll
        for (int k = 0; k < 4; ++k) accD[j][k] = half2v{(_Float16)0.f, (_Float16)0.f};
    // enc chunk (per-ray, sample-independent): lane's channels ch*8..+8
    half2v i0, i1, i2, i3;
    {
        const float* er = enc + (size_t)rid*64 + ch*8;
        float4 e0 = *reinterpret_cast<const float4*>(er);
        float4 e1 = *reinterpret_cast<const float4*>(er + 4);
        i0 = half2v{(_Float16)e0.x, (_Float16)e0.y};
        i1 = half2v{(_Float16)e0.z, (_Float16)e0.w};
        i2 = half2v{(_Float16)e1.x, (_Float16)e1.y};
        i3 = half2v{(_Float16)e1.z, (_Float16)e1.w};
    }
#pragma unroll
    for (int j = 0; j < 8; ++j) {
        half2v accC[4] = {i0, i1, i2, i3};
        const int s = j*8 + sg;
#pragma unroll
        for (int p = 0; p < 3; ++p) {
            const int   pp = __shfl(pos[p], s, 64);
            const float fx = __shfl(wxp[p], s, 64);
            const float fy = __shfl(wyp[p], s, 64);
            // record base: [pair p][batch b][texel pp][128ch], lane chunk ch
            const ushort_t* lb = trp + ((size_t)(p*2+b)*NTEX + (size_t)pp)*128 + ch*8;
            union { uint4 v; half2v h[4]; } d00,d01,d10,d11, c00,c01,c10,c11;
            d00.v = *reinterpret_cast<const uint4*>(lb);
            c00.v = *reinterpret_cast<const uint4*>(lb + 64);
            d01.v = *reinterpret_cast<const uint4*>(lb + 128);
            c01.v = *reinterpret_cast<const uint4*>(lb + 192);
            d10.v = *reinterpret_cast<const uint4*>(lb + 128*HW_);
            c10.v = *reinterpret_cast<const uint4*>(lb + 128*HW_ + 64);
            d11.v = *reinterpret_cast<const uint4*>(lb + 128*HW_ + 128);
            c11.v = *reinterpret_cast<const uint4*>(lb + 128*HW_ + 192);
            const _Float16 h00 = (_Float16)((1.f-fx)*(1.f-fy));
            const _Float16 h01 = (_Float16)(fx*(1.f-fy));
            const _Float16 h10 = (_Float16)((1.f-fx)*fy);
            const _Float16 h11 = (_Float16)(fx*fy);
            const half2v w00 = half2v{h00,h00}, w01 = half2v{h01,h01};
            const half2v w10 = half2v{h10,h10}, w11 = half2v{h11,h11};
#pragma unroll
            for (int k = 0; k < 4; ++k) {
                accD[j][k] += w00*d00.h[k] + w01*d01.h[k] + w10*d10.h[k] + w11*d11.h[k];
                accC[k]    += w00*c00.h[k] + w01*c01.h[k] + w10*c10.h[k] + w11*c11.h[k];
            }
        }
        // stream color sample to A (row s, chunk ch, swizzled)
        union { half2v h[4]; uint4 v; } pk;
#pragma unroll
        for (int k = 0; k < 4; ++k) pk.h[k] = accC[k];
        *reinterpret_cast<uint4*>(reinterpret_cast<char*>(A) + s*128 + ((ch*16) ^ (sg<<4))) = pk.v;
    }

    // ---- early color GEMM: accH = (fc + enc) @ Wc ----
    floatx4 accH[4];
#pragma unroll
    for (int mi = 0; mi < 4; ++mi) accH[mi] = (floatx4){0.f,0.f,0.f,0.f};
    {
        half8 b0 = ldbfrag(whead, 0, 0);
        half8 b1 = ldbfrag(whead, 0, 1);
#pragma unroll
        for (int mi = 0; mi < 4; ++mi) {
            accH[mi] = __builtin_amdgcn_mfma_f32_16x16x32_f16(ldfrag(mi,0), b0, accH[mi], 0, 0, 0);
            accH[mi] = __builtin_amdgcn_mfma_f32_16x16x32_f16(ldfrag(mi,1), b1, accH[mi], 0, 0, 0);
        }
    }

    // density -> A (in-order DS: GEMM's frag reads complete before overwrite)
#pragma unroll
    for (int j = 0; j < 8; ++j) {
        union { half2v h[4]; uint4 v; } pk;
#pragma unroll
        for (int k = 0; k < 4; ++k) pk.h[k] = accD[j][k];
        const int s = j*8 + sg;
        *reinterpret_cast<uint4*>(reinterpret_cast<char*>(A) + s*128 + ((ch*16) ^ (sg<<4))) = pk.v;
    }

    // ---- MLP (only accH: 16 f32 regs live across) ----
    mlp_layer(wq,        mlp_b);         // layer 1
    mlp_layer(wq + 4096, mlp_b + 64);    // layer 2  (A now holds h)

    // preload h fragments ONCE for both heads (heads only read A)
    half8 af[8];
#pragma unroll
    for (int mi = 0; mi < 4; ++mi)
#pragma unroll
        for (int kt = 0; kt < 2; ++kt) af[mi*2+kt] = ldfrag(mi, kt);

    // sigma head: h @ [w_op | 0...]  (col 16 of head region = w_op)
    {
        half8 b0 = ldbfrag(whead, 1, 0);
        half8 b1 = ldbfrag(whead, 1, 1);
        floatx4 accS[4];
#pragma unroll
        for (int mi = 0; mi < 4; ++mi) {
            accS[mi] = (floatx4){0.f,0.f,0.f,0.f};
            accS[mi] = __builtin_amdgcn_mfma_f32_16x16x32_f16(af[mi*2+0], b0, accS[mi], 0, 0, 0);
            accS[mi] = __builtin_amdgcn_mfma_f32_16x16x32_f16(af[mi*2+1], b1, accS[mi], 0, 0, 0);
        }
        if ((lane & 15) == 0) {
            const float bop = b_op[0];
#pragma unroll
            for (int mi = 0; mi < 4; ++mi)
#pragma unroll
                for (int r = 0; r < 4; ++r) {
                    int m = mi*16 + (lane>>4)*4 + r;
                    sd_lds[wv][m] = sp(accS[mi][r] + bop) * delta;
                }
        }
    }

    // color head part 2: accH += h @ Wc
    {
        half8 b0 = ldbfrag(whead, 0, 0);
        half8 b1 = ldbfrag(whead, 0, 1);
#pragma unroll
        for (int mi = 0; mi < 4; ++mi) {
            accH[mi] = __builtin_amdgcn_mfma_f32_16x16x32_f16(af[mi*2+0], b0, accH[mi], 0, 0, 0);
            accH[mi] = __builtin_amdgcn_mfma_f32_16x16x32_f16(af[mi*2+1], b1, accH[mi], 0, 0, 0);
        }
    }

    // ---- composite: lane = sample ----
    const float sdv = sd_lds[wv][lane];
    float csd = sdv;
#pragma unroll
    for (int off = 1; off < 64; off <<= 1) {
        float nn = __shfl_up(csd, off, 64);
        if (lane >= off) csd += nn;
    }
    const float nlt = __shfl(csd, 63, 64);
    const float Tw  = __expf(sdv - csd) * (1.f - __expf(-sdv));
    const float em  = __expf(-nlt);
    w_lds[wv][lane] = Tw;

    float rl = Tw * t;
#pragma unroll
    for (int off = 32; off > 0; off >>= 1) rl += __shfl_xor(rl, off, 64);

    // feat[k] = sum_m w_m * (color[m][k] + b_col[k]);  k = lane&15
    const float bcn = b_col[lane & 15];
    float pf = 0.f;
#pragma unroll
    for (int mi = 0; mi < 4; ++mi)
#pragma unroll
        for (int r = 0; r < 4; ++r) {
            int m = mi*16 + (lane>>4)*4 + r;
            pf += w_lds[wv][m] * (accH[mi][r] + bcn);
        }
    pf += __shfl_xor(pf, 16, 64);
    pf += __shfl_xor(pf, 32, 64);

    if (lane < 16)
        out[(size_t)rid*16 + lane] = pf + em * bgc[lane];
    if (lane == 0) {
        out[(size_t)NRAYS*16 + rid] = 1.f - em;   // mask
        out[(size_t)NRAYS*17 + rid] = rl;         // ray_len
    }
}

extern "C" void kernel_launch(void* const* d_in, const int* in_sizes, int n_in,
                              void* d_out, int out_size, void* d_ws, size_t ws_size,
                              hipStream_t stream)
{
    const float* rays    = (const float*)d_in[0];
    const float* centers = (const float*)d_in[1];
    const float* enc     = (const float*)d_in[2];
    const float* nearp   = (const float*)d_in[3];
    const float* farp    = (const float*)d_in[4];
    const float* xy      = (const float*)d_in[5];
    const float* yz      = (const float*)d_in[6];
    const float* zx      = (const float*)d_in[7];
    const float* xyc     = (const float*)d_in[8];
    const float* yzc     = (const float*)d_in[9];
    const float* zxc     = (const float*)d_in[10];
    const float* mlp_w   = (const float*)d_in[11];
    const float* mlp_b   = (const float*)d_in[12];
    const float* w_op    = (const float*)d_in[13];
    const float* b_op    = (const float*)d_in[14];
    const float* w_col   = (const float*)d_in[15];
    const float* b_col   = (const float*)d_in[16];
    const float* bg      = (const float*)d_in[17];
    float* out = (float*)d_out;

    char* ws = (char*)d_ws;
    ushort_t* trp  = (ushort_t*)ws;
    ushort_t* wq   = (ushort_t*)(ws + WS_WQ_OFF);
    uint_t*   keys = (uint_t*)(ws + WS_KEYS_OFF);
    uint_t*   perm = (uint_t*)(ws + WS_PERM_OFF);
    uint_t*   hist = (uint_t*)(ws + WS_HIST_OFF);
    uint_t*   offs = (uint_t*)(ws + WS_OFFS_OFF);

    tr_planes<<<6*2*HW_, 256, 0, stream>>>(xy, yz, zx, xyc, yzc, zxc, trp);
    prep_weights<<<(NW_US + 255)/256, 256, 0, stream>>>(mlp_w, w_op, w_col, wq);

    hipMemsetAsync(hist, 0, NBINS*sizeof(uint_t), stream);
    ray_keys<<<NRAYS/256, 256, 0, stream>>>(rays, centers, nearp, farp, keys, hist);
    scan_hist<<<1, NBINS, 0, stream>>>(hist, offs);
    scatter_perm<<<NRAYS/256, 256, 0, stream>>>(keys, offs, perm);

    render<<<NWG, WV*64, 0, stream>>>(
        rays, centers, enc, nearp, farp, mlp_b, b_op, b_col, bg, trp, wq, perm, out);
}

// Round 15
// 301.407 us; speedup vs baseline: 5.1117x; 1.0492x over previous
//
#include <hip/hip_runtime.h>
#include <hip/hip_bf16.h>

typedef unsigned short ushort_t;
typedef unsigned int   uint_t;
typedef __attribute__((ext_vector_type(8))) _Float16 half8;   // MFMA f16 A/B frag
typedef __attribute__((ext_vector_type(2))) _Float16 half2v;  // packed f16 pair
typedef __attribute__((ext_vector_type(4))) float    floatx4; // MFMA acc

#define B_    2
#define R_    8192
#define HW_   256
#define S_    64
#define NRAYS (B_*R_)
#define PLANE_ELEMS ((size_t)64*HW_*HW_)
#define NTEX  ((size_t)HW_*HW_)
/* interleaved record: [pair(3)][batch(2)][texel 65536][128ch: D64|C64] f16 */
#define WS_PLANES_BYTES (6ull*B_*NTEX*64*2)     /* 100,663,296 */
#define NW_US 10240    /* weight f16s: 8192 mlp + 2048 head */
#define WV 4           /* waves (rays) per block */
#define NWG (NRAYS/WV) /* 4096 render blocks */
#define NBINS 1024

#define WS_WQ_OFF   WS_PLANES_BYTES
#define WS_KEYS_OFF (WS_WQ_OFF + NW_US*2)
#define WS_PERM_OFF (WS_KEYS_OFF + NRAYS*4)
#define WS_HIST_OFF (WS_PERM_OFF + NRAYS*4)
#define WS_OFFS_OFF (WS_HIST_OFF + NBINS*4)

__device__ __forceinline__ float sp(float x){ return fmaxf(x, 0.f) + __logf(1.f + __expf(-fabsf(x))); }
__device__ __forceinline__ ushort_t f2h(float f){
    union{_Float16 h; ushort_t u;} v; v.h = (_Float16)f; return v.u;
}

// ---------------- Kernel A: planes [C,H,W]f32 -> interleaved [texel][D|C]f16 ----------------
// R14: LDS-staged so HBM writes are full contiguous lines. Old version wrote
// 16B chunks at 256B stride (partial-line writes). Block = (pidx,b,y,xh):
// 128 texels; thread (tid>>1)=texel, (tid&1)=D/C half; padded LDS rows (272B)
// avoid the all-lanes-one-bank write hazard; phase 2 writes 32KB contiguous.
__global__ __launch_bounds__(256) void tr_planes(
    const float* __restrict__ p0, const float* __restrict__ p1, const float* __restrict__ p2,
    const float* __restrict__ p3, const float* __restrict__ p4, const float* __restrict__ p5,
    ushort_t* __restrict__ outp)
{
    __shared__ ushort_t st[128*136];           // 128 rows x 272 B = 34816 B
    const int blk = blockIdx.x;
    const int xh = blk & 1, y = (blk >> 1) & 255, b = (blk >> 9) & 1, pidx = blk >> 10;
    const int tid = threadIdx.x;
    const int xt = tid >> 1;                   // texel within half-row
    const int half = tid & 1;                  // 0 = density plane, 1 = color plane
    const int p = pidx + half*3;
    const float* src = (p==0)?p0:(p==1)?p1:(p==2)?p2:(p==3)?p3:(p==4)?p4:p5;
    src += (size_t)b*PLANE_ELEMS + (size_t)y*HW_ + (size_t)(xh*128 + xt);

    ushort_t* row = &st[xt*136 + half*64];
#pragma unroll
    for (int c = 0; c < 64; ++c)
        row[c] = f2h(src[(size_t)c*HW_*HW_]);
    __syncthreads();

    // cooperative contiguous write: 128 records x 256 B = 2048 uint4
    ushort_t* dst = outp + ((size_t)(pidx*2+b)*NTEX + (size_t)y*HW_ + (size_t)xh*128)*128;
#pragma unroll
    for (int i = 0; i < 8; ++i) {
        const int idx = i*256 + tid;           // output uint4 index
        const int rec = idx >> 4;              // 16 uint4 per record
        const int within = (idx & 15)*16;      // byte within record
        uint4 v = *reinterpret_cast<const uint4*>(
            reinterpret_cast<const char*>(st) + rec*272 + within);
        reinterpret_cast<uint4*>(dst)[idx] = v;
    }
}

// ---------------- Kernel A2: weights -> f16, transposed for B-fragments ----------------
__global__ __launch_bounds__(256) void prep_weights(
    const float* __restrict__ mlp_w, const float* __restrict__ w_op,
    const float* __restrict__ w_col, ushort_t* __restrict__ dst)
{
    int i = blockIdx.x*256 + threadIdx.x;
    if (i >= NW_US) return;
    float v;
    if (i < 8192) {
        int l = i >> 12, o = (i >> 6) & 63, c = i & 63;
        v = mlp_w[l*4096 + c*64 + o];
    } else {
        int j = i - 8192, n = j >> 6, c = j & 63;
        v = (n < 16) ? w_col[c*16 + n] : (n == 16 ? w_op[c] : 0.f);
    }
    dst[i] = f2h(v);
}

// ---------------- Sort kernels: spatial counting sort of rays (R8) ----------------
__global__ __launch_bounds__(256) void ray_keys(
    const float* __restrict__ rays, const float* __restrict__ centers,
    const float* __restrict__ nearp, const float* __restrict__ farp,
    uint_t* __restrict__ keys, uint_t* __restrict__ hist)
{
    int rid = blockIdx.x*256 + threadIdx.x;
    if (rid >= NRAYS) return;
    const float t = 0.5f*(nearp[rid] + farp[rid]);
    float c[3];
#pragma unroll
    for (int a = 0; a < 3; ++a) {
        float p = centers[rid*3+a] + t*rays[rid*3+a];
        p = fminf(fmaxf(p, -1.f), 1.f);
        int ci = (int)((p + 1.f)*4.f);
        c[a] = (float)(ci > 7 ? 7 : ci);
    }
    uint_t key = (uint_t)(rid >> 13)*512 + (uint_t)c[2]*64 + (uint_t)c[1]*8 + (uint_t)c[0];
    keys[rid] = key;
    atomicAdd(&hist[key], 1u);
}

__global__ __launch_bounds__(NBINS) void scan_hist(
    const uint_t* __restrict__ hist, uint_t* __restrict__ offs)
{
    __shared__ uint_t tmp[NBINS];
    const int tid = threadIdx.x;
    const uint_t own = hist[tid];
    tmp[tid] = own;
    __syncthreads();
#pragma unroll
    for (int off = 1; off < NBINS; off <<= 1) {
        uint_t v = (tid >= off) ? tmp[tid - off] : 0u;
        __syncthreads();
        tmp[tid] += v;
        __syncthreads();
    }
    offs[tid] = tmp[tid] - own;    // exclusive
}

__global__ __launch_bounds__(256) void scatter_perm(
    const uint_t* __restrict__ keys, uint_t* __restrict__ offs, uint_t* __restrict__ perm)
{
    int rid = blockIdx.x*256 + threadIdx.x;
    if (rid >= NRAYS) return;
    uint_t pos = atomicAdd(&offs[keys[rid]], 1u);
    perm[pos] = (uint_t)rid;
}

// ---------------- Kernel B: render (1 wave = 1 ray; MFMA f16 MLP) ----------------
// R14: gather weights pre-packed per sample as 4 SPLAT half2 dwords
// (v_cvt_pkrtz(w,w)); the loop shfls packed dwords instead of recomputing
// 4 weights + converts per (j,p) (~290 VALU/thread saved). Pre-commit:
// VGPR must stay <=128 (the 64/128/256 HW allocation step).
__global__ __launch_bounds__(256) void render(
    const float* __restrict__ rays, const float* __restrict__ centers,
    const float* __restrict__ enc,  const float* __restrict__ nearp, const float* __restrict__ farp,
    const float* __restrict__ mlp_b, const float* __restrict__ b_op,
    const float* __restrict__ b_col, const float* __restrict__ bgc,
    const ushort_t* __restrict__ trp, const ushort_t* __restrict__ wq,
    const uint_t* __restrict__ perm, float* __restrict__ out)
{
    __shared__ ushort_t A_lds[WV][4096];     // 64 rows x 128B (64 f16), XOR-swizzled 16B slots
    __shared__ float    sd_lds[WV][64];
    __shared__ float    w_lds [WV][64];

    const int wv = threadIdx.x >> 6, lane = threadIdx.x & 63;
    const int sg = lane >> 3, ch = lane & 7;       // cooperative gather coords
    const int sb  = (blockIdx.x & 7)*(NWG/8) + (blockIdx.x >> 3);  // XCD-chunk swizzle
    const int rid = (int)perm[sb*WV + wv];
    const int b = rid >> 13;
    ushort_t* A = &A_lds[wv][0];

    const float nr = nearp[rid], fr = farp[rid];
    const float rdx = rays[rid*3+0], rdy = rays[rid*3+1], rdz = rays[rid*3+2];
    const float rox = centers[rid*3+0], roy = centers[rid*3+1], roz = centers[rid*3+2];
    const float delta = (fr - nr) * (1.f/S_);
    const float t  = nr + (fr - nr) * ((lane + 0.5f) * (1.f/S_));
    const float px = rox + t*rdx, py = roy + t*rdy, pz = roz + t*rdz;

    // bilinear prep (lane = sample): pos + 4 splat-packed f16 weights per plane
    int pos[3]; uint_t wpk[3][4];
    {
        float us[3] = {px, py, pz};
        float vs[3] = {py, pz, px};
#pragma unroll
        for (int p = 0; p < 3; ++p) {
            float x = (fminf(fmaxf(us[p],-1.f),1.f) + 1.f) * 127.5f;
            float y = (fminf(fmaxf(vs[p],-1.f),1.f) + 1.f) * 127.5f;
            int x0 = (int)floorf(x); x0 = x0 < 0 ? 0 : (x0 > 254 ? 254 : x0);
            int y0 = (int)floorf(y); y0 = y0 < 0 ? 0 : (y0 > 254 ? 254 : y0);
            pos[p] = y0*HW_ + x0;
            const float fx = x - (float)x0, fy = y - (float)y0;
            const float w00 = (1.f-fx)*(1.f-fy), w01 = fx*(1.f-fy);
            const float w10 = (1.f-fx)*fy,       w11 = fx*fy;
            wpk[p][0] = __builtin_bit_cast(uint_t, __builtin_amdgcn_cvt_pkrtz(w00, w00));
            wpk[p][1] = __builtin_bit_cast(uint_t, __builtin_amdgcn_cvt_pkrtz(w01, w01));
            wpk[p][2] = __builtin_bit_cast(uint_t, __builtin_amdgcn_cvt_pkrtz(w10, w10));
            wpk[p][3] = __builtin_bit_cast(uint_t, __builtin_amdgcn_cvt_pkrtz(w11, w11));
        }
    }

    // A-fragment load: lane holds row (lane&15) of tile mi, k = kt*32 + (lane>>4)*8 + j
    auto ldfrag = [&](int mi, int kt) -> half8 {
        int m  = mi*16 + (lane&15);
        int cb = (kt*64 + ((lane>>4)*16)) ^ ((m&7)<<4);
        return *reinterpret_cast<const half8*>(reinterpret_cast<const char*>(A) + m*128 + cb);
    };
    auto ldbfrag = [&](const ushort_t* wrow, int nt, int kt) -> half8 {
        return *reinterpret_cast<const half8*>(wrow + (nt*16 + (lane&15))*64 + kt*32 + (lane>>4)*8);
    };
    auto stH = [&](int m, int n, float v) {
        A[(m*128 + ((n*2) ^ ((m&7)<<4))) >> 1] = f2h(v);
    };

    // one MLP layer; af[8] preload is a CORRECTNESS requirement (R3 lesson).
    auto mlp_layer = [&](const ushort_t* wrow, const float* bias) {
        half8 af[8];
#pragma unroll
        for (int mi = 0; mi < 4; ++mi)
#pragma unroll
            for (int kt = 0; kt < 2; ++kt) af[mi*2+kt] = ldfrag(mi, kt);
#pragma unroll
        for (int nt = 0; nt < 4; ++nt) {
            half8 b0 = ldbfrag(wrow, nt, 0);
            half8 b1 = ldbfrag(wrow, nt, 1);
            floatx4 acc[4];
#pragma unroll
            for (int mi = 0; mi < 4; ++mi) {
                acc[mi] = (floatx4){0.f,0.f,0.f,0.f};
                acc[mi] = __builtin_amdgcn_mfma_f32_16x16x32_f16(af[mi*2+0], b0, acc[mi], 0, 0, 0);
                acc[mi] = __builtin_amdgcn_mfma_f32_16x16x32_f16(af[mi*2+1], b1, acc[mi], 0, 0, 0);
            }
            const int n = nt*16 + (lane&15);
            const float bc = bias[n];
#pragma unroll
            for (int mi = 0; mi < 4; ++mi)
#pragma unroll
                for (int r = 0; r < 4; ++r) {
                    int m = mi*16 + (lane>>4)*4 + r;
                    stH(m, n, sp(acc[mi][r] + bc));
                }
        }
    };

    const ushort_t* whead = wq + 8192;

    // ---- merged gather: D accumulates in regs, C streams through A per-j ----
    half2v accD[8][4];
#pragma unroll
    for (int j = 0; j < 8; ++j)
#pragma unroll
        for (int k = 0; k < 4; ++k) accD[j][k] = half2v{(_Float16)0.f, (_Float16)0.f};
    // enc chunk (per-ray, sample-independent): lane's channels ch*8..+8
    half2v i0, i1, i2, i3;
    {
        const float* er = enc + (size_t)rid*64 + ch*8;
        float4 e0 = *reinterpret_cast<const float4*>(er);
        float4 e1 = *reinterpret_cast<const float4*>(er + 4);
        i0 = half2v{(_Float16)e0.x, (_Float16)e0.y};
        i1 = half2v{(_Float16)e0.z, (_Float16)e0.w};
        i2 = half2v{(_Float16)e1.x, (_Float16)e1.y};
        i3 = half2v{(_Float16)e1.z, (_Float16)e1.w};
    }
#pragma unroll
    for (int j = 0; j < 8; ++j) {
        half2v accC[4] = {i0, i1, i2, i3};
        const int s = j*8 + sg;
#pragma unroll
        for (int p = 0; p < 3; ++p) {
            const int pp = __shfl(pos[p], s, 64);
            const half2v w00 = __builtin_bit_cast(half2v, (uint_t)__shfl((int)wpk[p][0], s, 64));
            const half2v w01 = __builtin_bit_cast(half2v, (uint_t)__shfl((int)wpk[p][1], s, 64));
            const half2v w10 = __builtin_bit_cast(half2v, (uint_t)__shfl((int)wpk[p][2], s, 64));
            const half2v w11 = __builtin_bit_cast(half2v, (uint_t)__shfl((int)wpk[p][3], s, 64));
            // record base: [pair p][batch b][texel pp][128ch], lane chunk ch
            const ushort_t* lb = trp + ((size_t)(p*2+b)*NTEX + (size_t)pp)*128 + ch*8;
            union { uint4 v; half2v h[4]; } d00,d01,d10,d11, c00,c01,c10,c11;
            d00.v = *reinterpret_cast<const uint4*>(lb);
            c00.v = *reinterpret_cast<const uint4*>(lb + 64);
            d01.v = *reinterpret_cast<const uint4*>(lb + 128);
            c01.v = *reinterpret_cast<const uint4*>(lb + 192);
            d10.v = *reinterpret_cast<const uint4*>(lb + 128*HW_);
            c10.v = *reinterpret_cast<const uint4*>(lb + 128*HW_ + 64);
            d11.v = *reinterpret_cast<const uint4*>(lb + 128*HW_ + 128);
            c11.v = *reinterpret_cast<const uint4*>(lb + 128*HW_ + 192);
#pragma unroll
            for (int k = 0; k < 4; ++k) {
                accD[j][k] += w00*d00.h[k] + w01*d01.h[k] + w10*d10.h[k] + w11*d11.h[k];
                accC[k]    += w00*c00.h[k] + w01*c01.h[k] + w10*c10.h[k] + w11*c11.h[k];
            }
        }
        // stream color sample to A (row s, chunk ch, swizzled)
        union { half2v h[4]; uint4 v; } pk;
#pragma unroll
        for (int k = 0; k < 4; ++k) pk.h[k] = accC[k];
        *reinterpret_cast<uint4*>(reinterpret_cast<char*>(A) + s*128 + ((ch*16) ^ (sg<<4))) = pk.v;
    }

    // ---- early color GEMM: accH = (fc + enc) @ Wc ----
    floatx4 accH[4];
#pragma unroll
    for (int mi = 0; mi < 4; ++mi) accH[mi] = (floatx4){0.f,0.f,0.f,0.f};
    {
        half8 b0 = ldbfrag(whead, 0, 0);
        half8 b1 = ldbfrag(whead, 0, 1);
#pragma unroll
        for (int mi = 0; mi < 4; ++mi) {
            accH[mi] = __builtin_amdgcn_mfma_f32_16x16x32_f16(ldfrag(mi,0), b0, accH[mi], 0, 0, 0);
            accH[mi] = __builtin_amdgcn_mfma_f32_16x16x32_f16(ldfrag(mi,1), b1, accH[mi], 0, 0, 0);
        }
    }

    // density -> A (in-order DS: GEMM's frag reads complete before overwrite)
#pragma unroll
    for (int j = 0; j < 8; ++j) {
        union { half2v h[4]; uint4 v; } pk;
#pragma unroll
        for (int k = 0; k < 4; ++k) pk.h[k] = accD[j][k];
        const int s = j*8 + sg;
        *reinterpret_cast<uint4*>(reinterpret_cast<char*>(A) + s*128 + ((ch*16) ^ (sg<<4))) = pk.v;
    }

    // ---- MLP (only accH: 16 f32 regs live across) ----
    mlp_layer(wq,        mlp_b);         // layer 1
    mlp_layer(wq + 4096, mlp_b + 64);    // layer 2  (A now holds h)

    // preload h fragments ONCE for both heads (heads only read A)
    half8 af[8];
#pragma unroll
    for (int mi = 0; mi < 4; ++mi)
#pragma unroll
        for (int kt = 0; kt < 2; ++kt) af[mi*2+kt] = ldfrag(mi, kt);

    // sigma head: h @ [w_op | 0...]  (col 16 of head region = w_op)
    {
        half8 b0 = ldbfrag(whead, 1, 0);
        half8 b1 = ldbfrag(whead, 1, 1);
        floatx4 accS[4];
#pragma unroll
        for (int mi = 0; mi < 4; ++mi) {
            accS[mi] = (floatx4){0.f,0.f,0.f,0.f};
            accS[mi] = __builtin_amdgcn_mfma_f32_16x16x32_f16(af[mi*2+0], b0, accS[mi], 0, 0, 0);
            accS[mi] = __builtin_amdgcn_mfma_f32_16x16x32_f16(af[mi*2+1], b1, accS[mi], 0, 0, 0);
        }
        if ((lane & 15) == 0) {
            const float bop = b_op[0];
#pragma unroll
            for (int mi = 0; mi < 4; ++mi)
#pragma unroll
                for (int r = 0; r < 4; ++r) {
                    int m = mi*16 + (lane>>4)*4 + r;
                    sd_lds[wv][m] = sp(accS[mi][r] + bop) * delta;
                }
        }
    }

    // color head part 2: accH += h @ Wc
    {
        half8 b0 = ldbfrag(whead, 0, 0);
        half8 b1 = ldbfrag(whead, 0, 1);
#pragma unroll
        for (int mi = 0; mi < 4; ++mi) {
            accH[mi] = __builtin_amdgcn_mfma_f32_16x16x32_f16(af[mi*2+0], b0, accH[mi], 0, 0, 0);
            accH[mi] = __builtin_amdgcn_mfma_f32_16x16x32_f16(af[mi*2+1], b1, accH[mi], 0, 0, 0);
        }
    }

    // ---- composite: lane = sample ----
    const float sdv = sd_lds[wv][lane];
    float csd = sdv;
#pragma unroll
    for (int off = 1; off < 64; off <<= 1) {
        float nn = __shfl_up(csd, off, 64);
        if (lane >= off) csd += nn;
    }
    const float nlt = __shfl(csd, 63, 64);
    const float Tw  = __expf(sdv - csd) * (1.f - __expf(-sdv));
    const float em  = __expf(-nlt);
    w_lds[wv][lane] = Tw;

    float rl = Tw * t;
#pragma unroll
    for (int off = 32; off > 0; off >>= 1) rl += __shfl_xor(rl, off, 64);

    // feat[k] = sum_m w_m * (color[m][k] + b_col[k]);  k = lane&15
    const float bcn = b_col[lane & 15];
    float pf = 0.f;
#pragma unroll
    for (int mi = 0; mi < 4; ++mi)
#pragma unroll
        for (int r = 0; r < 4; ++r) {
            int m = mi*16 + (lane>>4)*4 + r;
            pf += w_lds[wv][m] * (accH[mi][r] + bcn);
        }
    pf += __shfl_xor(pf, 16, 64);
    pf += __shfl_xor(pf, 32, 64);

    if (lane < 16)
        out[(size_t)rid*16 + lane] = pf + em * bgc[lane];
    if (lane == 0) {
        out[(size_t)NRAYS*16 + rid] = 1.f - em;   // mask
        out[(size_t)NRAYS*17 + rid] = rl;         // ray_len
    }
}

extern "C" void kernel_launch(void* const* d_in, const int* in_sizes, int n_in,
                              void* d_out, int out_size, void* d_ws, size_t ws_size,
                              hipStream_t stream)
{
    const float* rays    = (const float*)d_in[0];
    const float* centers = (const float*)d_in[1];
    const float* enc     = (const float*)d_in[2];
    const float* nearp   = (const float*)d_in[3];
    const float* farp    = (const float*)d_in[4];
    const float* xy      = (const float*)d_in[5];
    const float* yz      = (const float*)d_in[6];
    const float* zx      = (const float*)d_in[7];
    const float* xyc     = (const float*)d_in[8];
    const float* yzc     = (const float*)d_in[9];
    const float* zxc     = (const float*)d_in[10];
    const float* mlp_w   = (const float*)d_in[11];
    const float* mlp_b   = (const float*)d_in[12];
    const float* w_op    = (const float*)d_in[13];
    const float* b_op    = (const float*)d_in[14];
    const float* w_col   = (const float*)d_in[15];
    const float* b_col   = (const float*)d_in[16];
    const float* bg      = (const float*)d_in[17];
    float* out = (float*)d_out;

    char* ws = (char*)d_ws;
    ushort_t* trp  = (ushort_t*)ws;
    ushort_t* wq   = (ushort_t*)(ws + WS_WQ_OFF);
    uint_t*   keys = (uint_t*)(ws + WS_KEYS_OFF);
    uint_t*   perm = (uint_t*)(ws + WS_PERM_OFF);
    uint_t*   hist = (uint_t*)(ws + WS_HIST_OFF);
    uint_t*   offs = (uint_t*)(ws + WS_OFFS_OFF);

    tr_planes<<<3*2*HW_*2, 256, 0, stream>>>(xy, yz, zx, xyc, yzc, zxc, trp);
    prep_weights<<<(NW_US + 255)/256, 256, 0, stream>>>(mlp_w, w_op, w_col, wq);

    hipMemsetAsync(hist, 0, NBINS*sizeof(uint_t), stream);
    ray_keys<<<NRAYS/256, 256, 0, stream>>>(rays, centers, nearp, farp, keys, hist);
    scan_hist<<<1, NBINS, 0, stream>>>(hist, offs);
    scatter_perm<<<NRAYS/256, 256, 0, stream>>>(keys, offs, perm);

    render<<<NWG, WV*64, 0, stream>>>(
        rays, centers, enc, nearp, farp, mlp_b, b_op, b_col, bg, trp, wq, perm, out);
}

// Round 16
// 270.429 us; speedup vs baseline: 5.6973x; 1.1146x over previous
//
#include <hip/hip_runtime.h>
#include <hip/hip_bf16.h>

typedef unsigned short ushort_t;
typedef unsigned int   uint_t;
typedef __attribute__((ext_vector_type(8))) _Float16 half8;   // MFMA f16 A/B frag
typedef __attribute__((ext_vector_type(2))) _Float16 half2v;  // packed f16 pair
typedef __attribute__((ext_vector_type(4))) float    floatx4; // MFMA acc

#define B_    2
#define R_    8192
#define HW_   256
#define S_    64
#define NRAYS (B_*R_)
#define PLANE_ELEMS ((size_t)64*HW_*HW_)
#define NTEX  ((size_t)HW_*HW_)
/* interleaved record: [pair(3)][batch(2)][texel 65536][128ch: D64|C64] f16 */
#define WS_PLANES_BYTES (6ull*B_*NTEX*64*2)     /* 100,663,296 */
#define NW_US 10240    /* weight f16s: 8192 mlp + 2048 head */
#define WV 4           /* waves (rays) per block */
#define NWG (NRAYS/WV) /* 4096 render blocks */
#define NBINS 1024

#define WS_WQ_OFF   WS_PLANES_BYTES
#define WS_KEYS_OFF (WS_WQ_OFF + NW_US*2)
#define WS_PERM_OFF (WS_KEYS_OFF + NRAYS*4)
#define WS_HIST_OFF (WS_PERM_OFF + NRAYS*4)
#define WS_OFFS_OFF (WS_HIST_OFF + NBINS*4)

__device__ __forceinline__ float sp(float x){ return fmaxf(x, 0.f) + __logf(1.f + __expf(-fabsf(x))); }
__device__ __forceinline__ ushort_t f2h(float f){
    union{_Float16 h; ushort_t u;} v; v.h = (_Float16)f; return v.u;
}
__device__ __forceinline__ half2v splat_h2(float w){
    return __builtin_bit_cast(half2v, __builtin_amdgcn_cvt_pkrtz(w, w));
}

// ---------------- Kernel A: planes [C,H,W]f32 -> interleaved [texel][D|C]f16 ----------------
// R14: LDS-staged so HBM writes are full contiguous lines.
__global__ __launch_bounds__(256) void tr_planes(
    const float* __restrict__ p0, const float* __restrict__ p1, const float* __restrict__ p2,
    const float* __restrict__ p3, const float* __restrict__ p4, const float* __restrict__ p5,
    ushort_t* __restrict__ outp)
{
    __shared__ ushort_t st[128*136];           // 128 rows x 272 B = 34816 B
    const int blk = blockIdx.x;
    const int xh = blk & 1, y = (blk >> 1) & 255, b = (blk >> 9) & 1, pidx = blk >> 10;
    const int tid = threadIdx.x;
    const int xt = tid >> 1;                   // texel within half-row
    const int half = tid & 1;                  // 0 = density plane, 1 = color plane
    const int p = pidx + half*3;
    const float* src = (p==0)?p0:(p==1)?p1:(p==2)?p2:(p==3)?p3:(p==4)?p4:p5;
    src += (size_t)b*PLANE_ELEMS + (size_t)y*HW_ + (size_t)(xh*128 + xt);

    ushort_t* row = &st[xt*136 + half*64];
#pragma unroll
    for (int c = 0; c < 64; ++c)
        row[c] = f2h(src[(size_t)c*HW_*HW_]);
    __syncthreads();

    // cooperative contiguous write: 128 records x 256 B = 2048 uint4
    ushort_t* dst = outp + ((size_t)(pidx*2+b)*NTEX + (size_t)y*HW_ + (size_t)xh*128)*128;
#pragma unroll
    for (int i = 0; i < 8; ++i) {
        const int idx = i*256 + tid;           // output uint4 index
        const int rec = idx >> 4;              // 16 uint4 per record
        const int within = (idx & 15)*16;      // byte within record
        uint4 v = *reinterpret_cast<const uint4*>(
            reinterpret_cast<const char*>(st) + rec*272 + within);
        reinterpret_cast<uint4*>(dst)[idx] = v;
    }
}

// ---------------- Kernel A2: weights -> f16, transposed for B-fragments ----------------
__global__ __launch_bounds__(256) void prep_weights(
    const float* __restrict__ mlp_w, const float* __restrict__ w_op,
    const float* __restrict__ w_col, ushort_t* __restrict__ dst)
{
    int i = blockIdx.x*256 + threadIdx.x;
    if (i >= NW_US) return;
    float v;
    if (i < 8192) {
        int l = i >> 12, o = (i >> 6) & 63, c = i & 63;
        v = mlp_w[l*4096 + c*64 + o];
    } else {
        int j = i - 8192, n = j >> 6, c = j & 63;
        v = (n < 16) ? w_col[c*16 + n] : (n == 16 ? w_op[c] : 0.f);
    }
    dst[i] = f2h(v);
}

// ---------------- Sort kernels: spatial counting sort of rays (R8) ----------------
__global__ __launch_bounds__(256) void ray_keys(
    const float* __restrict__ rays, const float* __restrict__ centers,
    const float* __restrict__ nearp, const float* __restrict__ farp,
    uint_t* __restrict__ keys, uint_t* __restrict__ hist)
{
    int rid = blockIdx.x*256 + threadIdx.x;
    if (rid >= NRAYS) return;
    const float t = 0.5f*(nearp[rid] + farp[rid]);
    float c[3];
#pragma unroll
    for (int a = 0; a < 3; ++a) {
        float p = centers[rid*3+a] + t*rays[rid*3+a];
        p = fminf(fmaxf(p, -1.f), 1.f);
        int ci = (int)((p + 1.f)*4.f);
        c[a] = (float)(ci > 7 ? 7 : ci);
    }
    uint_t key = (uint_t)(rid >> 13)*512 + (uint_t)c[2]*64 + (uint_t)c[1]*8 + (uint_t)c[0];
    keys[rid] = key;
    atomicAdd(&hist[key], 1u);
}

__global__ __launch_bounds__(NBINS) void scan_hist(
    const uint_t* __restrict__ hist, uint_t* __restrict__ offs)
{
    __shared__ uint_t tmp[NBINS];
    const int tid = threadIdx.x;
    const uint_t own = hist[tid];
    tmp[tid] = own;
    __syncthreads();
#pragma unroll
    for (int off = 1; off < NBINS; off <<= 1) {
        uint_t v = (tid >= off) ? tmp[tid - off] : 0u;
        __syncthreads();
        tmp[tid] += v;
        __syncthreads();
    }
    offs[tid] = tmp[tid] - own;    // exclusive
}

__global__ __launch_bounds__(256) void scatter_perm(
    const uint_t* __restrict__ keys, uint_t* __restrict__ offs, uint_t* __restrict__ perm)
{
    int rid = blockIdx.x*256 + threadIdx.x;
    if (rid >= NRAYS) return;
    uint_t pos = atomicAdd(&offs[keys[rid]], 1u);
    perm[pos] = (uint_t)rid;
}

// ---------------- Kernel B: render (1 wave = 1 ray; MFMA f16 MLP) ----------------
// R15: ZERO-shuffle gather. Ray state (nr/fr/ro/rd) is WAVE-UNIFORM, so the
// serving lane computes sample s=j*8+sg's pos + bilinear weights directly
// inside the loop (~45 VALU/j) instead of shfl'ing from lane==sample
// (R13: 9 bpermutes/j; R14's 15/j regressed -> shfl latency is the gather
// critical path). Weights packed as splat half2 via cvt_pkrtz.
__global__ __launch_bounds__(256) void render(
    const float* __restrict__ rays, const float* __restrict__ centers,
    const float* __restrict__ enc,  const float* __restrict__ nearp, const float* __restrict__ farp,
    const float* __restrict__ mlp_b, const float* __restrict__ b_op,
    const float* __restrict__ b_col, const float* __restrict__ bgc,
    const ushort_t* __restrict__ trp, const ushort_t* __restrict__ wq,
    const uint_t* __restrict__ perm, float* __restrict__ out)
{
    __shared__ ushort_t A_lds[WV][4096];     // 64 rows x 128B (64 f16), XOR-swizzled 16B slots
    __shared__ float    sd_lds[WV][64];
    __shared__ float    w_lds [WV][64];

    const int wv = threadIdx.x >> 6, lane = threadIdx.x & 63;
    const int sg = lane >> 3, ch = lane & 7;       // cooperative gather coords
    const int sb  = (blockIdx.x & 7)*(NWG/8) + (blockIdx.x >> 3);  // XCD-chunk swizzle
    const int rid = (int)perm[sb*WV + wv];
    const int b = rid >> 13;
    ushort_t* A = &A_lds[wv][0];

    const float nr = nearp[rid], fr = farp[rid];
    const float rdx = rays[rid*3+0], rdy = rays[rid*3+1], rdz = rays[rid*3+2];
    const float rox = centers[rid*3+0], roy = centers[rid*3+1], roz = centers[rid*3+2];
    const float delta = (fr - nr) * (1.f/S_);
    const float t  = nr + (fr - nr) * ((lane + 0.5f) * (1.f/S_));  // lane = sample (composite)

    // A-fragment load: lane holds row (lane&15) of tile mi, k = kt*32 + (lane>>4)*8 + j
    auto ldfrag = [&](int mi, int kt) -> half8 {
        int m  = mi*16 + (lane&15);
        int cb = (kt*64 + ((lane>>4)*16)) ^ ((m&7)<<4);
        return *reinterpret_cast<const half8*>(reinterpret_cast<const char*>(A) + m*128 + cb);
    };
    auto ldbfrag = [&](const ushort_t* wrow, int nt, int kt) -> half8 {
        return *reinterpret_cast<const half8*>(wrow + (nt*16 + (lane&15))*64 + kt*32 + (lane>>4)*8);
    };
    auto stH = [&](int m, int n, float v) {
        A[(m*128 + ((n*2) ^ ((m&7)<<4))) >> 1] = f2h(v);
    };

    // one MLP layer; af[8] preload is a CORRECTNESS requirement (R3 lesson).
    auto mlp_layer = [&](const ushort_t* wrow, const float* bias) {
        half8 af[8];
#pragma unroll
        for (int mi = 0; mi < 4; ++mi)
#pragma unroll
            for (int kt = 0; kt < 2; ++kt) af[mi*2+kt] = ldfrag(mi, kt);
#pragma unroll
        for (int nt = 0; nt < 4; ++nt) {
            half8 b0 = ldbfrag(wrow, nt, 0);
            half8 b1 = ldbfrag(wrow, nt, 1);
            floatx4 acc[4];
#pragma unroll
            for (int mi = 0; mi < 4; ++mi) {
                acc[mi] = (floatx4){0.f,0.f,0.f,0.f};
                acc[mi] = __builtin_amdgcn_mfma_f32_16x16x32_f16(af[mi*2+0], b0, acc[mi], 0, 0, 0);
                acc[mi] = __builtin_amdgcn_mfma_f32_16x16x32_f16(af[mi*2+1], b1, acc[mi], 0, 0, 0);
            }
            const int n = nt*16 + (lane&15);
            const float bc = bias[n];
#pragma unroll
            for (int mi = 0; mi < 4; ++mi)
#pragma unroll
                for (int r = 0; r < 4; ++r) {
                    int m = mi*16 + (lane>>4)*4 + r;
                    stH(m, n, sp(acc[mi][r] + bc));
                }
        }
    };

    const ushort_t* whead = wq + 8192;

    // ---- merged gather: D accumulates in regs, C streams through A per-j ----
    half2v accD[8][4];
#pragma unroll
    for (int j = 0; j < 8; ++j)
#pragma unroll
        for (int k = 0; k < 4; ++k) accD[j][k] = half2v{(_Float16)0.f, (_Float16)0.f};
    // enc chunk (per-ray, sample-independent): lane's channels ch*8..+8
    half2v i0, i1, i2, i3;
    {
        const float* er = enc + (size_t)rid*64 + ch*8;
        float4 e0 = *reinterpret_cast<const float4*>(er);
        float4 e1 = *reinterpret_cast<const float4*>(er + 4);
        i0 = half2v{(_Float16)e0.x, (_Float16)e0.y};
        i1 = half2v{(_Float16)e0.z, (_Float16)e0.w};
        i2 = half2v{(_Float16)e1.x, (_Float16)e1.y};
        i3 = half2v{(_Float16)e1.z, (_Float16)e1.w};
    }
#pragma unroll
    for (int j = 0; j < 8; ++j) {
        half2v accC[4] = {i0, i1, i2, i3};
        const int s = j*8 + sg;                        // sample this lane serves
        // direct per-serving-lane sample math (wave-uniform ray state)
        const float ts = nr + (fr - nr) * ((s + 0.5f) * (1.f/S_));
        const float qx = rox + ts*rdx, qy = roy + ts*rdy, qz = roz + ts*rdz;
        const float uu[3] = {qx, qy, qz};
        const float vv[3] = {qy, qz, qx};
#pragma unroll
        for (int p = 0; p < 3; ++p) {
            float x = (fminf(fmaxf(uu[p],-1.f),1.f) + 1.f) * 127.5f;
            float y = (fminf(fmaxf(vv[p],-1.f),1.f) + 1.f) * 127.5f;
            int x0 = (int)floorf(x); x0 = x0 < 0 ? 0 : (x0 > 254 ? 254 : x0);
            int y0 = (int)floorf(y); y0 = y0 < 0 ? 0 : (y0 > 254 ? 254 : y0);
            const int pp = y0*HW_ + x0;
            const float fx = x - (float)x0, fy = y - (float)y0;
            const half2v w00 = splat_h2((1.f-fx)*(1.f-fy));
            const half2v w01 = splat_h2(fx*(1.f-fy));
            const half2v w10 = splat_h2((1.f-fx)*fy);
            const half2v w11 = splat_h2(fx*fy);
            // record base: [pair p][batch b][texel pp][128ch], lane chunk ch
            const ushort_t* lb = trp + ((size_t)(p*2+b)*NTEX + (size_t)pp)*128 + ch*8;
            union { uint4 v; half2v h[4]; } d00,d01,d10,d11, c00,c01,c10,c11;
            d00.v = *reinterpret_cast<const uint4*>(lb);
            c00.v = *reinterpret_cast<const uint4*>(lb + 64);
            d01.v = *reinterpret_cast<const uint4*>(lb + 128);
            c01.v = *reinterpret_cast<const uint4*>(lb + 192);
            d10.v = *reinterpret_cast<const uint4*>(lb + 128*HW_);
            c10.v = *reinterpret_cast<const uint4*>(lb + 128*HW_ + 64);
            d11.v = *reinterpret_cast<const uint4*>(lb + 128*HW_ + 128);
            c11.v = *reinterpret_cast<const uint4*>(lb + 128*HW_ + 192);
#pragma unroll
            for (int k = 0; k < 4; ++k) {
                accD[j][k] += w00*d00.h[k] + w01*d01.h[k] + w10*d10.h[k] + w11*d11.h[k];
                accC[k]    += w00*c00.h[k] + w01*c01.h[k] + w10*c10.h[k] + w11*c11.h[k];
            }
        }
        // stream color sample to A (row s, chunk ch, swizzled)
        union { half2v h[4]; uint4 v; } pk;
#pragma unroll
        for (int k = 0; k < 4; ++k) pk.h[k] = accC[k];
        *reinterpret_cast<uint4*>(reinterpret_cast<char*>(A) + s*128 + ((ch*16) ^ (sg<<4))) = pk.v;
    }

    // ---- early color GEMM: accH = (fc + enc) @ Wc ----
    floatx4 accH[4];
#pragma unroll
    for (int mi = 0; mi < 4; ++mi) accH[mi] = (floatx4){0.f,0.f,0.f,0.f};
    {
        half8 b0 = ldbfrag(whead, 0, 0);
        half8 b1 = ldbfrag(whead, 0, 1);
#pragma unroll
        for (int mi = 0; mi < 4; ++mi) {
            accH[mi] = __builtin_amdgcn_mfma_f32_16x16x32_f16(ldfrag(mi,0), b0, accH[mi], 0, 0, 0);
            accH[mi] = __builtin_amdgcn_mfma_f32_16x16x32_f16(ldfrag(mi,1), b1, accH[mi], 0, 0, 0);
        }
    }

    // density -> A (in-order DS: GEMM's frag reads complete before overwrite)
#pragma unroll
    for (int j = 0; j < 8; ++j) {
        union { half2v h[4]; uint4 v; } pk;
#pragma unroll
        for (int k = 0; k < 4; ++k) pk.h[k] = accD[j][k];
        const int s = j*8 + sg;
        *reinterpret_cast<uint4*>(reinterpret_cast<char*>(A) + s*128 + ((ch*16) ^ (sg<<4))) = pk.v;
    }

    // ---- MLP (only accH: 16 f32 regs live across) ----
    mlp_layer(wq,        mlp_b);         // layer 1
    mlp_layer(wq + 4096, mlp_b + 64);    // layer 2  (A now holds h)

    // preload h fragments ONCE for both heads (heads only read A)
    half8 af[8];
#pragma unroll
    for (int mi = 0; mi < 4; ++mi)
#pragma unroll
        for (int kt = 0; kt < 2; ++kt) af[mi*2+kt] = ldfrag(mi, kt);

    // sigma head: h @ [w_op | 0...]  (col 16 of head region = w_op)
    {
        half8 b0 = ldbfrag(whead, 1, 0);
        half8 b1 = ldbfrag(whead, 1, 1);
        floatx4 accS[4];
#pragma unroll
        for (int mi = 0; mi < 4; ++mi) {
            accS[mi] = (floatx4){0.f,0.f,0.f,0.f};
            accS[mi] = __builtin_amdgcn_mfma_f32_16x16x32_f16(af[mi*2+0], b0, accS[mi], 0, 0, 0);
            accS[mi] = __builtin_amdgcn_mfma_f32_16x16x32_f16(af[mi*2+1], b1, accS[mi], 0, 0, 0);
        }
        if ((lane & 15) == 0) {
            const float bop = b_op[0];
#pragma unroll
            for (int mi = 0; mi < 4; ++mi)
#pragma unroll
                for (int r = 0; r < 4; ++r) {
                    int m = mi*16 + (lane>>4)*4 + r;
                    sd_lds[wv][m] = sp(accS[mi][r] + bop) * delta;
                }
        }
    }

    // color head part 2: accH += h @ Wc
    {
        half8 b0 = ldbfrag(whead, 0, 0);
        half8 b1 = ldbfrag(whead, 0, 1);
#pragma unroll
        for (int mi = 0; mi < 4; ++mi) {
            accH[mi] = __builtin_amdgcn_mfma_f32_16x16x32_f16(af[mi*2+0], b0, accH[mi], 0, 0, 0);
            accH[mi] = __builtin_amdgcn_mfma_f32_16x16x32_f16(af[mi*2+1], b1, accH[mi], 0, 0, 0);
        }
    }

    // ---- composite: lane = sample ----
    const float sdv = sd_lds[wv][lane];
    float csd = sdv;
#pragma unroll
    for (int off = 1; off < 64; off <<= 1) {
        float nn = __shfl_up(csd, off, 64);
        if (lane >= off) csd += nn;
    }
    const float nlt = __shfl(csd, 63, 64);
    const float Tw  = __expf(sdv - csd) * (1.f - __expf(-sdv));
    const float em  = __expf(-nlt);
    w_lds[wv][lane] = Tw;

    float rl = Tw * t;
#pragma unroll
    for (int off = 32; off > 0; off >>= 1) rl += __shfl_xor(rl, off, 64);

    // feat[k] = sum_m w_m * (color[m][k] + b_col[k]);  k = lane&15
    const float bcn = b_col[lane & 15];
    float pf = 0.f;
#pragma unroll
    for (int mi = 0; mi < 4; ++mi)
#pragma unroll
        for (int r = 0; r < 4; ++r) {
            int m = mi*16 + (lane>>4)*4 + r;
            pf += w_lds[wv][m] * (accH[mi][r] + bcn);
        }
    pf += __shfl_xor(pf, 16, 64);
    pf += __shfl_xor(pf, 32, 64);

    if (lane < 16)
        out[(size_t)rid*16 + lane] = pf + em * bgc[lane];
    if (lane == 0) {
        out[(size_t)NRAYS*16 + rid] = 1.f - em;   // mask
        out[(size_t)NRAYS*17 + rid] = rl;         // ray_len
    }
}

extern "C" void kernel_launch(void* const* d_in, const int* in_sizes, int n_in,
                              void* d_out, int out_size, void* d_ws, size_t ws_size,
                              hipStream_t stream)
{
    const float* rays    = (const float*)d_in[0];
    const float* centers = (const float*)d_in[1];
    const float* enc     = (const float*)d_in[2];
    const float* nearp   = (const float*)d_in[3];
    const float* farp    = (const float*)d_in[4];
    const float* xy      = (const float*)d_in[5];
    const float* yz      = (const float*)d_in[6];
    const float* zx      = (const float*)d_in[7];
    const float* xyc     = (const float*)d_in[8];
    const float* yzc     = (const float*)d_in[9];
    const float* zxc     = (const float*)d_in[10];
    const float* mlp_w   = (const float*)d_in[11];
    const float* mlp_b   = (const float*)d_in[12];
    const float* w_op    = (const float*)d_in[13];
    const float* b_op    = (const float*)d_in[14];
    const float* w_col   = (const float*)d_in[15];
    const float* b_col   = (const float*)d_in[16];
    const float* bg      = (const float*)d_in[17];
    float* out = (float*)d_out;

    char* ws = (char*)d_ws;
    ushort_t* trp  = (ushort_t*)ws;
    ushort_t* wq   = (ushort_t*)(ws + WS_WQ_OFF);
    uint_t*   keys = (uint_t*)(ws + WS_KEYS_OFF);
    uint_t*   perm = (uint_t*)(ws + WS_PERM_OFF);
    uint_t*   hist = (uint_t*)(ws + WS_HIST_OFF);
    uint_t*   offs = (uint_t*)(ws + WS_OFFS_OFF);

    tr_planes<<<3*2*HW_*2, 256, 0, stream>>>(xy, yz, zx, xyc, yzc, zxc, trp);
    prep_weights<<<(NW_US + 255)/256, 256, 0, stream>>>(mlp_w, w_op, w_col, wq);

    hipMemsetAsync(hist, 0, NBINS*sizeof(uint_t), stream);
    ray_keys<<<NRAYS/256, 256, 0, stream>>>(rays, centers, nearp, farp, keys, hist);
    scan_hist<<<1, NBINS, 0, stream>>>(hist, offs);
    scatter_perm<<<NRAYS/256, 256, 0, stream>>>(keys, offs, perm);

    render<<<NWG, WV*64, 0, stream>>>(
        rays, centers, enc, nearp, farp, mlp_b, b_op, b_col, bg, trp, wq, perm, out);
}

// Round 17
// 258.111 us; speedup vs baseline: 5.9692x; 1.0477x over previous
//
#include <hip/hip_runtime.h>
#include <hip/hip_bf16.h>

typedef unsigned short ushort_t;
typedef unsigned int   uint_t;
typedef __attribute__((ext_vector_type(8))) _Float16 half8;   // MFMA f16 A/B frag
typedef __attribute__((ext_vector_type(2))) _Float16 half2v;  // packed f16 pair
typedef __attribute__((ext_vector_type(4))) float    floatx4; // MFMA acc

#define B_    2
#define R_    8192
#define HW_   256
#define S_    64
#define NRAYS (B_*R_)
#define PLANE_ELEMS ((size_t)64*HW_*HW_)
#define NTEX  ((size_t)HW_*HW_)
/* interleaved record: [pair(3)][batch(2)][texel 65536][128ch: D64|C64] f16 */
#define WS_PLANES_BYTES (6ull*B_*NTEX*64*2)     /* 100,663,296 */
#define NW_US 10240    /* weight f16s: 8192 mlp + 2048 head */
#define WV 2           /* waves (rays) per block: 17KB LDS -> more blocks/CU */
#define NWG (NRAYS/WV) /* 8192 render blocks */
#define NBINS 1024

#define WS_WQ_OFF   WS_PLANES_BYTES
#define WS_KEYS_OFF (WS_WQ_OFF + NW_US*2)
#define WS_PERM_OFF (WS_KEYS_OFF + NRAYS*4)
#define WS_HIST_OFF (WS_PERM_OFF + NRAYS*4)
#define WS_OFFS_OFF (WS_HIST_OFF + NBINS*4)

__device__ __forceinline__ float sp(float x){ return fmaxf(x, 0.f) + __logf(1.f + __expf(-fabsf(x))); }
__device__ __forceinline__ ushort_t f2h(float f){
    union{_Float16 h; ushort_t u;} v; v.h = (_Float16)f; return v.u;
}
__device__ __forceinline__ half2v splat_h2(float w){
    return __builtin_bit_cast(half2v, __builtin_amdgcn_cvt_pkrtz(w, w));
}

// ---------------- Kernel A: planes [C,H,W]f32 -> interleaved [texel][D|C]f16 ----------------
__global__ __launch_bounds__(256) void tr_planes(
    const float* __restrict__ p0, const float* __restrict__ p1, const float* __restrict__ p2,
    const float* __restrict__ p3, const float* __restrict__ p4, const float* __restrict__ p5,
    ushort_t* __restrict__ outp)
{
    __shared__ ushort_t st[128*136];           // 128 rows x 272 B = 34816 B
    const int blk = blockIdx.x;
    const int xh = blk & 1, y = (blk >> 1) & 255, b = (blk >> 9) & 1, pidx = blk >> 10;
    const int tid = threadIdx.x;
    const int xt = tid >> 1;                   // texel within half-row
    const int half = tid & 1;                  // 0 = density plane, 1 = color plane
    const int p = pidx + half*3;
    const float* src = (p==0)?p0:(p==1)?p1:(p==2)?p2:(p==3)?p3:(p==4)?p4:p5;
    src += (size_t)b*PLANE_ELEMS + (size_t)y*HW_ + (size_t)(xh*128 + xt);

    ushort_t* row = &st[xt*136 + half*64];
#pragma unroll
    for (int c = 0; c < 64; ++c)
        row[c] = f2h(src[(size_t)c*HW_*HW_]);
    __syncthreads();

    // cooperative contiguous write: 128 records x 256 B = 2048 uint4
    ushort_t* dst = outp + ((size_t)(pidx*2+b)*NTEX + (size_t)y*HW_ + (size_t)xh*128)*128;
#pragma unroll
    for (int i = 0; i < 8; ++i) {
        const int idx = i*256 + tid;           // output uint4 index
        const int rec = idx >> 4;              // 16 uint4 per record
        const int within = (idx & 15)*16;      // byte within record
        uint4 v = *reinterpret_cast<const uint4*>(
            reinterpret_cast<const char*>(st) + rec*272 + within);
        reinterpret_cast<uint4*>(dst)[idx] = v;
    }
}

// ---------------- Kernel A2: weights -> f16, transposed for fragments ----------------
__global__ __launch_bounds__(256) void prep_weights(
    const float* __restrict__ mlp_w, const float* __restrict__ w_op,
    const float* __restrict__ w_col, ushort_t* __restrict__ dst)
{
    int i = blockIdx.x*256 + threadIdx.x;
    if (i >= NW_US) return;
    float v;
    if (i < 8192) {
        int l = i >> 12, o = (i >> 6) & 63, c = i & 63;
        v = mlp_w[l*4096 + c*64 + o];
    } else {
        int j = i - 8192, n = j >> 6, c = j & 63;
        v = (n < 16) ? w_col[c*16 + n] : (n == 16 ? w_op[c] : 0.f);
    }
    dst[i] = f2h(v);
}

// ---------------- Sort kernels: spatial counting sort of rays (R8) ----------------
__global__ __launch_bounds__(256) void ray_keys(
    const float* __restrict__ rays, const float* __restrict__ centers,
    const float* __restrict__ nearp, const float* __restrict__ farp,
    uint_t* __restrict__ keys, uint_t* __restrict__ hist)
{
    int rid = blockIdx.x*256 + threadIdx.x;
    if (rid >= NRAYS) return;
    const float t = 0.5f*(nearp[rid] + farp[rid]);
    float c[3];
#pragma unroll
    for (int a = 0; a < 3; ++a) {
        float p = centers[rid*3+a] + t*rays[rid*3+a];
        p = fminf(fmaxf(p, -1.f), 1.f);
        int ci = (int)((p + 1.f)*4.f);
        c[a] = (float)(ci > 7 ? 7 : ci);
    }
    uint_t key = (uint_t)(rid >> 13)*512 + (uint_t)c[2]*64 + (uint_t)c[1]*8 + (uint_t)c[0];
    keys[rid] = key;
    atomicAdd(&hist[key], 1u);
}

__global__ __launch_bounds__(NBINS) void scan_hist(
    const uint_t* __restrict__ hist, uint_t* __restrict__ offs)
{
    __shared__ uint_t tmp[NBINS];
    const int tid = threadIdx.x;
    const uint_t own = hist[tid];
    tmp[tid] = own;
    __syncthreads();
#pragma unroll
    for (int off = 1; off < NBINS; off <<= 1) {
        uint_t v = (tid >= off) ? tmp[tid - off] : 0u;
        __syncthreads();
        tmp[tid] += v;
        __syncthreads();
    }
    offs[tid] = tmp[tid] - own;    // exclusive
}

__global__ __launch_bounds__(256) void scatter_perm(
    const uint_t* __restrict__ keys, uint_t* __restrict__ offs, uint_t* __restrict__ perm)
{
    int rid = blockIdx.x*256 + threadIdx.x;
    if (rid >= NRAYS) return;
    uint_t pos = atomicAdd(&offs[keys[rid]], 1u);
    perm[pos] = (uint_t)rid;
}

// ---------------- Kernel B: render (1 wave = 1 ray; transposed MFMA MLP) ----------------
// R16: MLP computed as h_next^T = W . h^T  (W = MFMA A-operand, h = B-operand;
// both use the SAME frag address patterns as before). D-layout col=lane&15=s,
// row=o block -> each lane writes 4 consecutive o as ONE ds_write_b64 (16
// writes/layer vs 64 scalar b16 + 64 f2h). Heads transposed likewise; bcol
// folded via sum_s w = mask; w_lds dropped (shfl). WV=2 -> 17KB LDS blocks.
__global__ __launch_bounds__(WV*64) void render(
    const float* __restrict__ rays, const float* __restrict__ centers,
    const float* __restrict__ enc,  const float* __restrict__ nearp, const float* __restrict__ farp,
    const float* __restrict__ mlp_b, const float* __restrict__ b_op,
    const float* __restrict__ b_col, const float* __restrict__ bgc,
    const ushort_t* __restrict__ trp, const ushort_t* __restrict__ wq,
    const uint_t* __restrict__ perm, float* __restrict__ out)
{
    __shared__ ushort_t A_lds[WV][4096];     // 64 rows x 128B (64 f16), XOR-swizzled 16B slots
    __shared__ float    sd_lds[WV][64];

    const int wv = threadIdx.x >> 6, lane = threadIdx.x & 63;
    const int sg = lane >> 3, ch = lane & 7;       // cooperative gather coords
    const int sb  = (blockIdx.x & 7)*(NWG/8) + (blockIdx.x >> 3);  // XCD-chunk swizzle
    const int rid = (int)perm[sb*WV + wv];
    const int b = rid >> 13;
    ushort_t* A = &A_lds[wv][0];

    const float nr = nearp[rid], fr = farp[rid];
    const float rdx = rays[rid*3+0], rdy = rays[rid*3+1], rdz = rays[rid*3+2];
    const float rox = centers[rid*3+0], roy = centers[rid*3+1], roz = centers[rid*3+2];
    const float delta = (fr - nr) * (1.f/S_);
    const float t  = nr + (fr - nr) * ((lane + 0.5f) * (1.f/S_));  // lane = sample (composite)

    // B-frag (features) read: lane holds col s=(lane&15) of s-tile `stile`,
    // k = kt*32 + (lane>>4)*8 + j  -> row stile*16+(lane&15) of A, swizzled
    auto ldfrag = [&](int stile, int kt) -> half8 {
        int s  = stile*16 + (lane&15);
        int cb = (kt*64 + ((lane>>4)*16)) ^ ((s&7)<<4);
        return *reinterpret_cast<const half8*>(reinterpret_cast<const char*>(A) + s*128 + cb);
    };
    // A-frag (weights): lane holds row nt*16+(lane&15) of W, same k pattern
    auto ldwfrag = [&](const ushort_t* wrow, int nt, int kt) -> half8 {
        return *reinterpret_cast<const half8*>(wrow + (nt*16 + (lane&15))*64 + kt*32 + (lane>>4)*8);
    };

    // one MLP layer (transposed): preload ALL h B-frags (R3 read-before-write
    // rule), then per (otile,stile): 2 MFMA -> softplus -> packed b64 write.
    auto mlp_layerT = [&](const ushort_t* wrow, const float* bias) {
        half8 bf[8];
#pragma unroll
        for (int stile = 0; stile < 4; ++stile)
#pragma unroll
            for (int kt = 0; kt < 2; ++kt) bf[stile*2+kt] = ldfrag(stile, kt);
#pragma unroll
        for (int otile = 0; otile < 4; ++otile) {
            half8 a0 = ldwfrag(wrow, otile, 0);
            half8 a1 = ldwfrag(wrow, otile, 1);
            float4 bb = *reinterpret_cast<const float4*>(bias + otile*16 + (lane>>4)*4);
#pragma unroll
            for (int stile = 0; stile < 4; ++stile) {
                floatx4 acc = (floatx4){0.f,0.f,0.f,0.f};
                acc = __builtin_amdgcn_mfma_f32_16x16x32_f16(a0, bf[stile*2+0], acc, 0, 0, 0);
                acc = __builtin_amdgcn_mfma_f32_16x16x32_f16(a1, bf[stile*2+1], acc, 0, 0, 0);
                const uint_t lo = __builtin_bit_cast(uint_t,
                    __builtin_amdgcn_cvt_pkrtz(sp(acc[0]+bb.x), sp(acc[1]+bb.y)));
                const uint_t hi = __builtin_bit_cast(uint_t,
                    __builtin_amdgcn_cvt_pkrtz(sp(acc[2]+bb.z), sp(acc[3]+bb.w)));
                const int s = stile*16 + (lane&15);
                const int off = (otile*32 + ((lane>>4)*8)) ^ ((s&7)<<4);
                *reinterpret_cast<uint2*>(reinterpret_cast<char*>(A) + s*128 + off)
                    = make_uint2(lo, hi);
            }
        }
    };

    const ushort_t* whead = wq + 8192;

    // ---- merged gather: D accumulates in regs, C streams through A per-j ----
    half2v accD[8][4];
#pragma unroll
    for (int j = 0; j < 8; ++j)
#pragma unroll
        for (int k = 0; k < 4; ++k) accD[j][k] = half2v{(_Float16)0.f, (_Float16)0.f};
    half2v i0, i1, i2, i3;
    {
        const float* er = enc + (size_t)rid*64 + ch*8;
        float4 e0 = *reinterpret_cast<const float4*>(er);
        float4 e1 = *reinterpret_cast<const float4*>(er + 4);
        i0 = half2v{(_Float16)e0.x, (_Float16)e0.y};
        i1 = half2v{(_Float16)e0.z, (_Float16)e0.w};
        i2 = half2v{(_Float16)e1.x, (_Float16)e1.y};
        i3 = half2v{(_Float16)e1.z, (_Float16)e1.w};
    }
#pragma unroll
    for (int j = 0; j < 8; ++j) {
        half2v accC[4] = {i0, i1, i2, i3};
        const int s = j*8 + sg;                        // sample this lane serves
        const float ts = nr + (fr - nr) * ((s + 0.5f) * (1.f/S_));
        const float qx = rox + ts*rdx, qy = roy + ts*rdy, qz = roz + ts*rdz;
        const float uu[3] = {qx, qy, qz};
        const float vv[3] = {qy, qz, qx};
#pragma unroll
        for (int p = 0; p < 3; ++p) {
            float x = (fminf(fmaxf(uu[p],-1.f),1.f) + 1.f) * 127.5f;
            float y = (fminf(fmaxf(vv[p],-1.f),1.f) + 1.f) * 127.5f;
            int x0 = (int)floorf(x); x0 = x0 < 0 ? 0 : (x0 > 254 ? 254 : x0);
            int y0 = (int)floorf(y); y0 = y0 < 0 ? 0 : (y0 > 254 ? 254 : y0);
            const int pp = y0*HW_ + x0;
            const float fx = x - (float)x0, fy = y - (float)y0;
            const half2v w00 = splat_h2((1.f-fx)*(1.f-fy));
            const half2v w01 = splat_h2(fx*(1.f-fy));
            const half2v w10 = splat_h2((1.f-fx)*fy);
            const half2v w11 = splat_h2(fx*fy);
            const ushort_t* lb = trp + ((size_t)(p*2+b)*NTEX + (size_t)pp)*128 + ch*8;
            union { uint4 v; half2v h[4]; } d00,d01,d10,d11, c00,c01,c10,c11;
            d00.v = *reinterpret_cast<const uint4*>(lb);
            c00.v = *reinterpret_cast<const uint4*>(lb + 64);
            d01.v = *reinterpret_cast<const uint4*>(lb + 128);
            c01.v = *reinterpret_cast<const uint4*>(lb + 192);
            d10.v = *reinterpret_cast<const uint4*>(lb + 128*HW_);
            c10.v = *reinterpret_cast<const uint4*>(lb + 128*HW_ + 64);
            d11.v = *reinterpret_cast<const uint4*>(lb + 128*HW_ + 128);
            c11.v = *reinterpret_cast<const uint4*>(lb + 128*HW_ + 192);
#pragma unroll
            for (int k = 0; k < 4; ++k) {
                accD[j][k] += w00*d00.h[k] + w01*d01.h[k] + w10*d10.h[k] + w11*d11.h[k];
                accC[k]    += w00*c00.h[k] + w01*c01.h[k] + w10*c10.h[k] + w11*c11.h[k];
            }
        }
        union { half2v h[4]; uint4 v; } pk;
#pragma unroll
        for (int k = 0; k < 4; ++k) pk.h[k] = accC[k];
        *reinterpret_cast<uint4*>(reinterpret_cast<char*>(A) + s*128 + ((ch*16) ^ (sg<<4))) = pk.v;
    }

    // ---- early color GEMM (transposed): accH[stile] = Wc . (fc+enc)^T ----
    floatx4 accH[4];
    {
        half8 c0 = ldwfrag(whead, 0, 0);
        half8 c1 = ldwfrag(whead, 0, 1);
#pragma unroll
        for (int stile = 0; stile < 4; ++stile) {
            floatx4 acc = (floatx4){0.f,0.f,0.f,0.f};
            acc = __builtin_amdgcn_mfma_f32_16x16x32_f16(c0, ldfrag(stile,0), acc, 0, 0, 0);
            acc = __builtin_amdgcn_mfma_f32_16x16x32_f16(c1, ldfrag(stile,1), acc, 0, 0, 0);
            accH[stile] = acc;
        }
    }

    // density -> A (in-order DS: GEMM's frag reads complete before overwrite)
#pragma unroll
    for (int j = 0; j < 8; ++j) {
        union { half2v h[4]; uint4 v; } pk;
#pragma unroll
        for (int k = 0; k < 4; ++k) pk.h[k] = accD[j][k];
        const int s = j*8 + sg;
        *reinterpret_cast<uint4*>(reinterpret_cast<char*>(A) + s*128 + ((ch*16) ^ (sg<<4))) = pk.v;
    }

    // ---- MLP (only accH: 16 f32 regs live across) ----
    mlp_layerT(wq,        mlp_b);         // layer 1
    mlp_layerT(wq + 4096, mlp_b + 64);    // layer 2  (A now holds h[s][o])

    // preload h B-frags ONCE for both heads (heads only read A)
    half8 af[8];
#pragma unroll
    for (int stile = 0; stile < 4; ++stile)
#pragma unroll
        for (int kt = 0; kt < 2; ++kt) af[stile*2+kt] = ldfrag(stile, kt);

    // sigma head (transposed): rows 16..31 of head = [w_op row | zeros];
    // D row 0 (o=16) lands in lanes 0..15 reg[0], col s = stile*16+lane.
    {
        half8 a0 = ldwfrag(whead, 1, 0);
        half8 a1 = ldwfrag(whead, 1, 1);
        const float bop = b_op[0];
#pragma unroll
        for (int stile = 0; stile < 4; ++stile) {
            floatx4 acc = (floatx4){0.f,0.f,0.f,0.f};
            acc = __builtin_amdgcn_mfma_f32_16x16x32_f16(a0, af[stile*2+0], acc, 0, 0, 0);
            acc = __builtin_amdgcn_mfma_f32_16x16x32_f16(a1, af[stile*2+1], acc, 0, 0, 0);
            if (lane < 16)
                sd_lds[wv][stile*16 + lane] = sp(acc[0] + bop) * delta;
        }
    }

    // color head part 2: accH[stile] += Wc . h^T
    {
        half8 c0 = ldwfrag(whead, 0, 0);
        half8 c1 = ldwfrag(whead, 0, 1);
#pragma unroll
        for (int stile = 0; stile < 4; ++stile) {
            accH[stile] = __builtin_amdgcn_mfma_f32_16x16x32_f16(c0, af[stile*2+0], accH[stile], 0, 0, 0);
            accH[stile] = __builtin_amdgcn_mfma_f32_16x16x32_f16(c1, af[stile*2+1], accH[stile], 0, 0, 0);
        }
    }

    // ---- composite: lane = sample ----
    const float sdv = sd_lds[wv][lane];
    float csd = sdv;
#pragma unroll
    for (int off = 1; off < 64; off <<= 1) {
        float nn = __shfl_up(csd, off, 64);
        if (lane >= off) csd += nn;
    }
    const float nlt = __shfl(csd, 63, 64);
    const float Tw  = __expf(sdv - csd) * (1.f - __expf(-sdv));
    const float em  = __expf(-nlt);                 // wave-uniform
    const float mask = 1.f - em;

    float rl = Tw * t;
#pragma unroll
    for (int off = 32; off > 0; off >>= 1) rl += __shfl_xor(rl, off, 64);

    // feat[o] = sum_s w[s]*c[s][o] + bcol[o]*mask + em*bg[o]
    // lane holds c[s=stile*16+(lane&15)][o=(lane>>4)*4+r] in accH[stile][r]
    float pf[4] = {0.f, 0.f, 0.f, 0.f};
#pragma unroll
    for (int stile = 0; stile < 4; ++stile) {
        const float wS = __shfl(Tw, stile*16 + (lane & 15), 64);
#pragma unroll
        for (int r = 0; r < 4; ++r) pf[r] += wS * accH[stile][r];
    }
#pragma unroll
    for (int m = 1; m <= 8; m <<= 1)
#pragma unroll
        for (int r = 0; r < 4; ++r) pf[r] += __shfl_xor(pf[r], m, 64);

    if ((lane & 15) == 0) {
        const int o0 = (lane >> 4)*4;
        float4 bc = *reinterpret_cast<const float4*>(b_col + o0);
        float4 bg = *reinterpret_cast<const float4*>(bgc + o0);
        float4 r;
        r.x = pf[0] + bc.x*mask + em*bg.x;
        r.y = pf[1] + bc.y*mask + em*bg.y;
        r.z = pf[2] + bc.z*mask + em*bg.z;
        r.w = pf[3] + bc.w*mask + em*bg.w;
        *reinterpret_cast<float4*>(out + (size_t)rid*16 + o0) = r;
    }
    if (lane == 0) {
        out[(size_t)NRAYS*16 + rid] = mask;        // mask
        out[(size_t)NRAYS*17 + rid] = rl;          // ray_len
    }
}

extern "C" void kernel_launch(void* const* d_in, const int* in_sizes, int n_in,
                              void* d_out, int out_size, void* d_ws, size_t ws_size,
                              hipStream_t stream)
{
    const float* rays    = (const float*)d_in[0];
    const float* centers = (const float*)d_in[1];
    const float* enc     = (const float*)d_in[2];
    const float* nearp   = (const float*)d_in[3];
    const float* farp    = (const float*)d_in[4];
    const float* xy      = (const float*)d_in[5];
    const float* yz      = (const float*)d_in[6];
    const float* zx      = (const float*)d_in[7];
    const float* xyc     = (const float*)d_in[8];
    const float* yzc     = (const float*)d_in[9];
    const float* zxc     = (const float*)d_in[10];
    const float* mlp_w   = (const float*)d_in[11];
    const float* mlp_b   = (const float*)d_in[12];
    const float* w_op    = (const float*)d_in[13];
    const float* b_op    = (const float*)d_in[14];
    const float* w_col   = (const float*)d_in[15];
    const float* b_col   = (const float*)d_in[16];
    const float* bg      = (const float*)d_in[17];
    float* out = (float*)d_out;

    char* ws = (char*)d_ws;
    ushort_t* trp  = (ushort_t*)ws;
    ushort_t* wq   = (ushort_t*)(ws + WS_WQ_OFF);
    uint_t*   keys = (uint_t*)(ws + WS_KEYS_OFF);
    uint_t*   perm = (uint_t*)(ws + WS_PERM_OFF);
    uint_t*   hist = (uint_t*)(ws + WS_HIST_OFF);
    uint_t*   offs = (uint_t*)(ws + WS_OFFS_OFF);

    tr_planes<<<3*2*HW_*2, 256, 0, stream>>>(xy, yz, zx, xyc, yzc, zxc, trp);
    prep_weights<<<(NW_US + 255)/256, 256, 0, stream>>>(mlp_w, w_op, w_col, wq);

    hipMemsetAsync(hist, 0, NBINS*sizeof(uint_t), stream);
    ray_keys<<<NRAYS/256, 256, 0, stream>>>(rays, centers, nearp, farp, keys, hist);
    scan_hist<<<1, NBINS, 0, stream>>>(hist, offs);
    scatter_perm<<<NRAYS/256, 256, 0, stream>>>(keys, offs, perm);

    render<<<NWG, WV*64, 0, stream>>>(
        rays, centers, enc, nearp, farp, mlp_b, b_op, b_col, bg, trp, wq, perm, out);
}

// Round 18
// 250.072 us; speedup vs baseline: 6.1611x; 1.0321x over previous
//
#include <hip/hip_runtime.h>
#include <hip/hip_bf16.h>

typedef unsigned short ushort_t;
typedef unsigned int   uint_t;
typedef __attribute__((ext_vector_type(8))) _Float16 half8;   // MFMA f16 A/B frag
typedef __attribute__((ext_vector_type(2))) _Float16 half2v;  // packed f16 pair
typedef __attribute__((ext_vector_type(4))) float    floatx4; // MFMA acc

#define B_    2
#define R_    8192
#define HW_   256
#define S_    64
#define NRAYS (B_*R_)
#define PLANE_ELEMS ((size_t)64*HW_*HW_)
#define NTEX  ((size_t)HW_*HW_)
/* interleaved record: [pair(3)][batch(2)][texel 65536][128ch: D64|C64] f16 */
#define WS_PLANES_BYTES (6ull*B_*NTEX*64*2)     /* 100,663,296 */
#define NW_US 10240    /* weight f16s: 8192 mlp + 2048 head */
#define WV 2           /* waves (rays) per block */
#define NWG (NRAYS/WV) /* 8192 render blocks */
#define NBINS 1024

#define WS_WQ_OFF   WS_PLANES_BYTES
#define WS_KEYS_OFF (WS_WQ_OFF + NW_US*2)
#define WS_PERM_OFF (WS_KEYS_OFF + NRAYS*4)
#define WS_HIST_OFF (WS_PERM_OFF + NRAYS*4)
#define WS_OFFS_OFF (WS_HIST_OFF + NBINS*4)

__device__ __forceinline__ float sp(float x){ return fmaxf(x, 0.f) + __logf(1.f + __expf(-fabsf(x))); }
__device__ __forceinline__ ushort_t f2h(float f){
    union{_Float16 h; ushort_t u;} v; v.h = (_Float16)f; return v.u;
}
__device__ __forceinline__ half2v splat_h2(float w){
    return __builtin_bit_cast(half2v, __builtin_amdgcn_cvt_pkrtz(w, w));
}

// ---------------- Kernel A: planes [C,H,W]f32 -> interleaved [texel][D|C]f16 ----------------
__global__ __launch_bounds__(256) void tr_planes(
    const float* __restrict__ p0, const float* __restrict__ p1, const float* __restrict__ p2,
    const float* __restrict__ p3, const float* __restrict__ p4, const float* __restrict__ p5,
    ushort_t* __restrict__ outp)
{
    __shared__ ushort_t st[128*136];           // 128 rows x 272 B = 34816 B
    const int blk = blockIdx.x;
    const int xh = blk & 1, y = (blk >> 1) & 255, b = (blk >> 9) & 1, pidx = blk >> 10;
    const int tid = threadIdx.x;
    const int xt = tid >> 1;                   // texel within half-row
    const int half = tid & 1;                  // 0 = density plane, 1 = color plane
    const int p = pidx + half*3;
    const float* src = (p==0)?p0:(p==1)?p1:(p==2)?p2:(p==3)?p3:(p==4)?p4:p5;
    src += (size_t)b*PLANE_ELEMS + (size_t)y*HW_ + (size_t)(xh*128 + xt);

    ushort_t* row = &st[xt*136 + half*64];
#pragma unroll
    for (int c = 0; c < 64; ++c)
        row[c] = f2h(src[(size_t)c*HW_*HW_]);
    __syncthreads();

    // cooperative contiguous write: 128 records x 256 B = 2048 uint4
    ushort_t* dst = outp + ((size_t)(pidx*2+b)*NTEX + (size_t)y*HW_ + (size_t)xh*128)*128;
#pragma unroll
    for (int i = 0; i < 8; ++i) {
        const int idx = i*256 + tid;           // output uint4 index
        const int rec = idx >> 4;              // 16 uint4 per record
        const int within = (idx & 15)*16;      // byte within record
        uint4 v = *reinterpret_cast<const uint4*>(
            reinterpret_cast<const char*>(st) + rec*272 + within);
        reinterpret_cast<uint4*>(dst)[idx] = v;
    }
}

// ---------------- Kernel A2: weights -> f16, transposed for fragments ----------------
__global__ __launch_bounds__(256) void prep_weights(
    const float* __restrict__ mlp_w, const float* __restrict__ w_op,
    const float* __restrict__ w_col, ushort_t* __restrict__ dst)
{
    int i = blockIdx.x*256 + threadIdx.x;
    if (i >= NW_US) return;
    float v;
    if (i < 8192) {
        int l = i >> 12, o = (i >> 6) & 63, c = i & 63;
        v = mlp_w[l*4096 + c*64 + o];
    } else {
        int j = i - 8192, n = j >> 6, c = j & 63;
        v = (n < 16) ? w_col[c*16 + n] : (n == 16 ? w_op[c] : 0.f);
    }
    dst[i] = f2h(v);
}

// ---------------- Sort kernels: spatial counting sort of rays (R8) ----------------
__global__ __launch_bounds__(256) void ray_keys(
    const float* __restrict__ rays, const float* __restrict__ centers,
    const float* __restrict__ nearp, const float* __restrict__ farp,
    uint_t* __restrict__ keys, uint_t* __restrict__ hist)
{
    int rid = blockIdx.x*256 + threadIdx.x;
    if (rid >= NRAYS) return;
    const float t = 0.5f*(nearp[rid] + farp[rid]);
    float c[3];
#pragma unroll
    for (int a = 0; a < 3; ++a) {
        float p = centers[rid*3+a] + t*rays[rid*3+a];
        p = fminf(fmaxf(p, -1.f), 1.f);
        int ci = (int)((p + 1.f)*4.f);
        c[a] = (float)(ci > 7 ? 7 : ci);
    }
    uint_t key = (uint_t)(rid >> 13)*512 + (uint_t)c[2]*64 + (uint_t)c[1]*8 + (uint_t)c[0];
    keys[rid] = key;
    atomicAdd(&hist[key], 1u);
}

__global__ __launch_bounds__(NBINS) void scan_hist(
    const uint_t* __restrict__ hist, uint_t* __restrict__ offs)
{
    __shared__ uint_t tmp[NBINS];
    const int tid = threadIdx.x;
    const uint_t own = hist[tid];
    tmp[tid] = own;
    __syncthreads();
#pragma unroll
    for (int off = 1; off < NBINS; off <<= 1) {
        uint_t v = (tid >= off) ? tmp[tid - off] : 0u;
        __syncthreads();
        tmp[tid] += v;
        __syncthreads();
    }
    offs[tid] = tmp[tid] - own;    // exclusive
}

__global__ __launch_bounds__(256) void scatter_perm(
    const uint_t* __restrict__ keys, uint_t* __restrict__ offs, uint_t* __restrict__ perm)
{
    int rid = blockIdx.x*256 + threadIdx.x;
    if (rid >= NRAYS) return;
    uint_t pos = atomicAdd(&offs[keys[rid]], 1u);
    perm[pos] = (uint_t)rid;
}

// ---------------- Kernel B: render (1 wave = 1 ray; transposed MFMA MLP) ----------------
// R17: depth-1/2 SOFTWARE-PIPELINED gather. Flat 24-iteration loop with two
// statically-indexed load buffers (qa/qb): consume it while it+1/it+2 loads
// are in flight (hipcc emits counted vmcnt per register). R16 had load->wait->
// FMA serialization = ~26% stall. Pre-commit: VGPR must stay <=128.
__global__ __launch_bounds__(WV*64) void render(
    const float* __restrict__ rays, const float* __restrict__ centers,
    const float* __restrict__ enc,  const float* __restrict__ nearp, const float* __restrict__ farp,
    const float* __restrict__ mlp_b, const float* __restrict__ b_op,
    const float* __restrict__ b_col, const float* __restrict__ bgc,
    const ushort_t* __restrict__ trp, const ushort_t* __restrict__ wq,
    const uint_t* __restrict__ perm, float* __restrict__ out)
{
    __shared__ ushort_t A_lds[WV][4096];     // 64 rows x 128B (64 f16), XOR-swizzled 16B slots
    __shared__ float    sd_lds[WV][64];

    const int wv = threadIdx.x >> 6, lane = threadIdx.x & 63;
    const int sg = lane >> 3, ch = lane & 7;       // cooperative gather coords
    const int sb  = (blockIdx.x & 7)*(NWG/8) + (blockIdx.x >> 3);  // XCD-chunk swizzle
    const int rid = (int)perm[sb*WV + wv];
    const int b = rid >> 13;
    ushort_t* A = &A_lds[wv][0];

    const float nr = nearp[rid], fr = farp[rid];
    const float rdx = rays[rid*3+0], rdy = rays[rid*3+1], rdz = rays[rid*3+2];
    const float rox = centers[rid*3+0], roy = centers[rid*3+1], roz = centers[rid*3+2];
    const float delta = (fr - nr) * (1.f/S_);
    const float t  = nr + (fr - nr) * ((lane + 0.5f) * (1.f/S_));  // lane = sample (composite)

    // B-frag (features): lane holds col s=(lane&15) of s-tile, k = kt*32+(lane>>4)*8+j
    auto ldfrag = [&](int stile, int kt) -> half8 {
        int s  = stile*16 + (lane&15);
        int cb = (kt*64 + ((lane>>4)*16)) ^ ((s&7)<<4);
        return *reinterpret_cast<const half8*>(reinterpret_cast<const char*>(A) + s*128 + cb);
    };
    // A-frag (weights): lane holds row nt*16+(lane&15) of W, same k pattern
    auto ldwfrag = [&](const ushort_t* wrow, int nt, int kt) -> half8 {
        return *reinterpret_cast<const half8*>(wrow + (nt*16 + (lane&15))*64 + kt*32 + (lane>>4)*8);
    };

    // one MLP layer (transposed): preload ALL h B-frags (R3 read-before-write
    // rule), then per (otile,stile): 2 MFMA -> softplus -> packed b64 write.
    auto mlp_layerT = [&](const ushort_t* wrow, const float* bias) {
        half8 bf[8];
#pragma unroll
        for (int stile = 0; stile < 4; ++stile)
#pragma unroll
            for (int kt = 0; kt < 2; ++kt) bf[stile*2+kt] = ldfrag(stile, kt);
#pragma unroll
        for (int otile = 0; otile < 4; ++otile) {
            half8 a0 = ldwfrag(wrow, otile, 0);
            half8 a1 = ldwfrag(wrow, otile, 1);
            float4 bb = *reinterpret_cast<const float4*>(bias + otile*16 + (lane>>4)*4);
#pragma unroll
            for (int stile = 0; stile < 4; ++stile) {
                floatx4 acc = (floatx4){0.f,0.f,0.f,0.f};
                acc = __builtin_amdgcn_mfma_f32_16x16x32_f16(a0, bf[stile*2+0], acc, 0, 0, 0);
                acc = __builtin_amdgcn_mfma_f32_16x16x32_f16(a1, bf[stile*2+1], acc, 0, 0, 0);
                const uint_t lo = __builtin_bit_cast(uint_t,
                    __builtin_amdgcn_cvt_pkrtz(sp(acc[0]+bb.x), sp(acc[1]+bb.y)));
                const uint_t hi = __builtin_bit_cast(uint_t,
                    __builtin_amdgcn_cvt_pkrtz(sp(acc[2]+bb.z), sp(acc[3]+bb.w)));
                const int s = stile*16 + (lane&15);
                const int off = (otile*32 + ((lane>>4)*8)) ^ ((s&7)<<4);
                *reinterpret_cast<uint2*>(reinterpret_cast<char*>(A) + s*128 + off)
                    = make_uint2(lo, hi);
            }
        }
    };

    const ushort_t* whead = wq + 8192;

    // ---- merged gather: depth-1/2 pipeline; D in regs, C streams to A per-j ----
    half2v accD[8][4];
#pragma unroll
    for (int j = 0; j < 8; ++j)
#pragma unroll
        for (int k = 0; k < 4; ++k) accD[j][k] = half2v{(_Float16)0.f, (_Float16)0.f};
    half2v i0, i1, i2, i3;
    {
        const float* er = enc + (size_t)rid*64 + ch*8;
        float4 e0 = *reinterpret_cast<const float4*>(er);
        float4 e1 = *reinterpret_cast<const float4*>(er + 4);
        i0 = half2v{(_Float16)e0.x, (_Float16)e0.y};
        i1 = half2v{(_Float16)e0.z, (_Float16)e0.w};
        i2 = half2v{(_Float16)e1.x, (_Float16)e1.y};
        i3 = half2v{(_Float16)e1.z, (_Float16)e1.w};
    }
    half2v curC[4];

    auto prep = [&](int it, const ushort_t*& lb, float& fx, float& fy) {
        const int j = it/3, p = it - j*3;
        const int s = j*8 + sg;
        const float ts = nr + (fr - nr) * ((s + 0.5f) * (1.f/S_));
        const float qx = rox + ts*rdx, qy = roy + ts*rdy, qz = roz + ts*rdz;
        const float u = (p==0)?qx:(p==1)?qy:qz;
        const float v = (p==0)?qy:(p==1)?qz:qx;
        float x = (fminf(fmaxf(u,-1.f),1.f) + 1.f) * 127.5f;
        float y = (fminf(fmaxf(v,-1.f),1.f) + 1.f) * 127.5f;
        int x0 = (int)floorf(x); x0 = x0 < 0 ? 0 : (x0 > 254 ? 254 : x0);
        int y0 = (int)floorf(y); y0 = y0 < 0 ? 0 : (y0 > 254 ? 254 : y0);
        fx = x - (float)x0; fy = y - (float)y0;
        lb = trp + ((size_t)(p*2+b)*NTEX + (size_t)(y0*HW_ + x0))*128 + ch*8;
    };
    auto issue = [&](const ushort_t* lb, uint4* q) {
        q[0] = *reinterpret_cast<const uint4*>(lb);
        q[1] = *reinterpret_cast<const uint4*>(lb + 64);
        q[2] = *reinterpret_cast<const uint4*>(lb + 128);
        q[3] = *reinterpret_cast<const uint4*>(lb + 192);
        q[4] = *reinterpret_cast<const uint4*>(lb + 128*HW_);
        q[5] = *reinterpret_cast<const uint4*>(lb + 128*HW_ + 64);
        q[6] = *reinterpret_cast<const uint4*>(lb + 128*HW_ + 128);
        q[7] = *reinterpret_cast<const uint4*>(lb + 128*HW_ + 192);
    };
    auto consume = [&](int it, const uint4* q, float fx, float fy) {
        const int j = it/3, p = it - j*3;
        if (p == 0) { curC[0]=i0; curC[1]=i1; curC[2]=i2; curC[3]=i3; }
        const half2v w00 = splat_h2((1.f-fx)*(1.f-fy));
        const half2v w01 = splat_h2(fx*(1.f-fy));
        const half2v w10 = splat_h2((1.f-fx)*fy);
        const half2v w11 = splat_h2(fx*fy);
        const half2v* h = reinterpret_cast<const half2v*>(q);  // 32 half2v: D00 C00 D01 C01 D10 C10 D11 C11
#pragma unroll
        for (int k = 0; k < 4; ++k) {
            accD[j][k] += w00*h[k]    + w01*h[8+k]  + w10*h[16+k] + w11*h[24+k];
            curC[k]    += w00*h[4+k]  + w01*h[12+k] + w10*h[20+k] + w11*h[28+k];
        }
        if (p == 2) {
            union { half2v hh[4]; uint4 v; } pk;
#pragma unroll
            for (int k = 0; k < 4; ++k) pk.hh[k] = curC[k];
            const int s = j*8 + sg;
            *reinterpret_cast<uint4*>(reinterpret_cast<char*>(A) + s*128 + ((ch*16) ^ (sg<<4))) = pk.v;
        }
    };

    {
        const ushort_t *lb0, *lb1; float fx0, fy0, fx1, fy1;
        uint4 qa[8], qb[8];
        prep(0, lb0, fx0, fy0); issue(lb0, qa);
        prep(1, lb1, fx1, fy1); issue(lb1, qb);
#pragma unroll
        for (int it = 0; it < 24; it += 2) {
            consume(it, qa, fx0, fy0);
            if (it + 2 < 24) { prep(it+2, lb0, fx0, fy0); issue(lb0, qa); }
            consume(it+1, qb, fx1, fy1);
            if (it + 3 < 24) { prep(it+3, lb1, fx1, fy1); issue(lb1, qb); }
        }
    }

    // ---- early color GEMM (transposed): accH[stile] = Wc . (fc+enc)^T ----
    floatx4 accH[4];
    {
        half8 c0 = ldwfrag(whead, 0, 0);
        half8 c1 = ldwfrag(whead, 0, 1);
#pragma unroll
        for (int stile = 0; stile < 4; ++stile) {
            floatx4 acc = (floatx4){0.f,0.f,0.f,0.f};
            acc = __builtin_amdgcn_mfma_f32_16x16x32_f16(c0, ldfrag(stile,0), acc, 0, 0, 0);
            acc = __builtin_amdgcn_mfma_f32_16x16x32_f16(c1, ldfrag(stile,1), acc, 0, 0, 0);
            accH[stile] = acc;
        }
    }

    // density -> A (in-order DS: GEMM's frag reads complete before overwrite)
#pragma unroll
    for (int j = 0; j < 8; ++j) {
        union { half2v h[4]; uint4 v; } pk;
#pragma unroll
        for (int k = 0; k < 4; ++k) pk.h[k] = accD[j][k];
        const int s = j*8 + sg;
        *reinterpret_cast<uint4*>(reinterpret_cast<char*>(A) + s*128 + ((ch*16) ^ (sg<<4))) = pk.v;
    }

    // ---- MLP (only accH: 16 f32 regs live across) ----
    mlp_layerT(wq,        mlp_b);         // layer 1
    mlp_layerT(wq + 4096, mlp_b + 64);    // layer 2  (A now holds h[s][o])

    // preload h B-frags ONCE for both heads (heads only read A)
    half8 af[8];
#pragma unroll
    for (int stile = 0; stile < 4; ++stile)
#pragma unroll
        for (int kt = 0; kt < 2; ++kt) af[stile*2+kt] = ldfrag(stile, kt);

    // sigma head (transposed): rows 16..31 of head = [w_op row | zeros]
    {
        half8 a0 = ldwfrag(whead, 1, 0);
        half8 a1 = ldwfrag(whead, 1, 1);
        const float bop = b_op[0];
#pragma unroll
        for (int stile = 0; stile < 4; ++stile) {
            floatx4 acc = (floatx4){0.f,0.f,0.f,0.f};
            acc = __builtin_amdgcn_mfma_f32_16x16x32_f16(a0, af[stile*2+0], acc, 0, 0, 0);
            acc = __builtin_amdgcn_mfma_f32_16x16x32_f16(a1, af[stile*2+1], acc, 0, 0, 0);
            if (lane < 16)
                sd_lds[wv][stile*16 + lane] = sp(acc[0] + bop) * delta;
        }
    }

    // color head part 2: accH[stile] += Wc . h^T
    {
        half8 c0 = ldwfrag(whead, 0, 0);
        half8 c1 = ldwfrag(whead, 0, 1);
#pragma unroll
        for (int stile = 0; stile < 4; ++stile) {
            accH[stile] = __builtin_amdgcn_mfma_f32_16x16x32_f16(c0, af[stile*2+0], accH[stile], 0, 0, 0);
            accH[stile] = __builtin_amdgcn_mfma_f32_16x16x32_f16(c1, af[stile*2+1], accH[stile], 0, 0, 0);
        }
    }

    // ---- composite: lane = sample ----
    const float sdv = sd_lds[wv][lane];
    float csd = sdv;
#pragma unroll
    for (int off = 1; off < 64; off <<= 1) {
        float nn = __shfl_up(csd, off, 64);
        if (lane >= off) csd += nn;
    }
    const float nlt = __shfl(csd, 63, 64);
    const float Tw  = __expf(sdv - csd) * (1.f - __expf(-sdv));
    const float em  = __expf(-nlt);                 // wave-uniform
    const float mask = 1.f - em;

    float rl = Tw * t;
#pragma unroll
    for (int off = 32; off > 0; off >>= 1) rl += __shfl_xor(rl, off, 64);

    // feat[o] = sum_s w[s]*c[s][o] + bcol[o]*mask + em*bg[o]
    float pf[4] = {0.f, 0.f, 0.f, 0.f};
#pragma unroll
    for (int stile = 0; stile < 4; ++stile) {
        const float wS = __shfl(Tw, stile*16 + (lane & 15), 64);
#pragma unroll
        for (int r = 0; r < 4; ++r) pf[r] += wS * accH[stile][r];
    }
#pragma unroll
    for (int m = 1; m <= 8; m <<= 1)
#pragma unroll
        for (int r = 0; r < 4; ++r) pf[r] += __shfl_xor(pf[r], m, 64);

    if ((lane & 15) == 0) {
        const int o0 = (lane >> 4)*4;
        float4 bc = *reinterpret_cast<const float4*>(b_col + o0);
        float4 bg = *reinterpret_cast<const float4*>(bgc + o0);
        float4 r;
        r.x = pf[0] + bc.x*mask + em*bg.x;
        r.y = pf[1] + bc.y*mask + em*bg.y;
        r.z = pf[2] + bc.z*mask + em*bg.z;
        r.w = pf[3] + bc.w*mask + em*bg.w;
        *reinterpret_cast<float4*>(out + (size_t)rid*16 + o0) = r;
    }
    if (lane == 0) {
        out[(size_t)NRAYS*16 + rid] = mask;        // mask
        out[(size_t)NRAYS*17 + rid] = rl;          // ray_len
    }
}

extern "C" void kernel_launch(void* const* d_in, const int* in_sizes, int n_in,
                              void* d_out, int out_size, void* d_ws, size_t ws_size,
                              hipStream_t stream)
{
    const float* rays    = (const float*)d_in[0];
    const float* centers = (const float*)d_in[1];
    const float* enc     = (const float*)d_in[2];
    const float* nearp   = (const float*)d_in[3];
    const float* farp    = (const float*)d_in[4];
    const float* xy      = (const float*)d_in[5];
    const float* yz      = (const float*)d_in[6];
    const float* zx      = (const float*)d_in[7];
    const float* xyc     = (const float*)d_in[8];
    const float* yzc     = (const float*)d_in[9];
    const float* zxc     = (const float*)d_in[10];
    const float* mlp_w   = (const float*)d_in[11];
    const float* mlp_b   = (const float*)d_in[12];
    const float* w_op    = (const float*)d_in[13];
    const float* b_op    = (const float*)d_in[14];
    const float* w_col   = (const float*)d_in[15];
    const float* b_col   = (const float*)d_in[16];
    const float* bg      = (const float*)d_in[17];
    float* out = (float*)d_out;

    char* ws = (char*)d_ws;
    ushort_t* trp  = (ushort_t*)ws;
    ushort_t* wq   = (ushort_t*)(ws + WS_WQ_OFF);
    uint_t*   keys = (uint_t*)(ws + WS_KEYS_OFF);
    uint_t*   perm = (uint_t*)(ws + WS_PERM_OFF);
    uint_t*   hist = (uint_t*)(ws + WS_HIST_OFF);
    uint_t*   offs = (uint_t*)(ws + WS_OFFS_OFF);

    tr_planes<<<3*2*HW_*2, 256, 0, stream>>>(xy, yz, zx, xyc, yzc, zxc, trp);
    prep_weights<<<(NW_US + 255)/256, 256, 0, stream>>>(mlp_w, w_op, w_col, wq);

    hipMemsetAsync(hist, 0, NBINS*sizeof(uint_t), stream);
    ray_keys<<<NRAYS/256, 256, 0, stream>>>(rays, centers, nearp, farp, keys, hist);
    scan_hist<<<1, NBINS, 0, stream>>>(hist, offs);
    scatter_perm<<<NRAYS/256, 256, 0, stream>>>(keys, offs, perm);

    render<<<NWG, WV*64, 0, stream>>>(
        rays, centers, enc, nearp, farp, mlp_b, b_op, b_col, bg, trp, wq, perm, out);
}